// Round 21
// baseline (407.120 us; speedup 1.0000x reference)
//
#include <hip/hip_runtime.h>
#include <math.h>

#define LQ 2048
#define SCALING 0.14433756729740643f   // 48^-0.5
#define FEPS 1.1920928955078125e-07f   // np.finfo(float32).eps

typedef unsigned short u16;
typedef __attribute__((ext_vector_type(8))) short bf16x8;
typedef __attribute__((ext_vector_type(4))) float f32x4;

#define MFMA16(a, b, c) __builtin_amdgcn_mfma_f32_16x16x32_bf16((a), (b), (c), 0, 0, 0)

__device__ __forceinline__ u16 f2b(float x) {
  union { float f; unsigned u; } v; v.f = x;
  return (u16)((v.u + 0x7FFFu + ((v.u >> 16) & 1u)) >> 16);
}
__device__ __forceinline__ float b2f(u16 b) {
  union { unsigned u; float f; } v; v.u = ((unsigned)b) << 16;
  return v.f;
}

// ---------------- weight fp32 [K][N] -> bf16 [N][K] (single) ----------------
__global__ void transpose_to_bf16(const float* __restrict__ W, u16* __restrict__ Wt,
                                  int K, int N) {
  __shared__ float tile[32][33];
  int n0 = blockIdx.x * 32, k0 = blockIdx.y * 32;
  int tx = threadIdx.x, ty = threadIdx.y;  // 32 x 8
  for (int i = ty; i < 32; i += 8) {
    int k = k0 + i, n = n0 + tx;
    tile[i][tx] = (k < K && n < N) ? W[(size_t)k * N + n] : 0.f;
  }
  __syncthreads();
  for (int i = ty; i < 32; i += 8) {
    int n = n0 + i, k = k0 + tx;
    if (n < N && k < K) Wt[(size_t)n * K + k] = f2b(tile[tx][i]);
  }
}

// ---------------- weight fp32 [K][N] -> hi/lo bf16 [N][K] ----------------
__global__ void transpose_split(const float* __restrict__ W, u16* __restrict__ Whi,
                                u16* __restrict__ Wlo, int K, int N) {
  __shared__ float tile[32][33];
  int n0 = blockIdx.x * 32, k0 = blockIdx.y * 32;
  int tx = threadIdx.x, ty = threadIdx.y;  // 32 x 8
  for (int i = ty; i < 32; i += 8) {
    int k = k0 + i, n = n0 + tx;
    tile[i][tx] = (k < K && n < N) ? W[(size_t)k * N + n] : 0.f;
  }
  __syncthreads();
  for (int i = ty; i < 32; i += 8) {
    int n = n0 + i, k = k0 + tx;
    if (n < N && k < K) {
      float x = tile[tx][i];
      u16 hi = f2b(x);
      float lo = x - b2f(hi);
      Whi[(size_t)n * K + k] = hi;
      Wlo[(size_t)n * K + k] = f2b(lo);
    }
  }
}

// ---------------- rmsnorm fp32 in (strided) -> fp32 or bf16 out ----------------
template <int BF16OUT>
__global__ __launch_bounds__(256) void rmsnorm_kernel(
    const float* __restrict__ x, const float* __restrict__ w, void* __restrict__ outv,
    int cols, int in_stride, float eps) {
  const int row = blockIdx.x;
  const float* xr = x + (size_t)row * in_stride;
  float ss = 0.f;
  for (int c = threadIdx.x; c < cols; c += 256) { float v = xr[c]; ss = fmaf(v, v, ss); }
#pragma unroll
  for (int off = 32; off > 0; off >>= 1) ss += __shfl_xor(ss, off);
  __shared__ float red[4];
  if ((threadIdx.x & 63) == 0) red[threadIdx.x >> 6] = ss;
  __syncthreads();
  float tot = red[0] + red[1] + red[2] + red[3];
  float sc = 1.f / sqrtf(tot / (float)cols + eps);
  for (int c = threadIdx.x; c < cols; c += 256) {
    float v = xr[c] * sc * w[c];
    if (BF16OUT) ((u16*)outv)[(size_t)row * cols + c] = f2b(v);
    else ((float*)outv)[(size_t)row * cols + c] = v;
  }
}

// ---- rmsnorm fp32 in (strided) -> hi/lo bf16 out (split once, reused by gemm) ----
__global__ __launch_bounds__(256) void rmsnorm_split_kernel(
    const float* __restrict__ x, const float* __restrict__ w,
    u16* __restrict__ hi_out, u16* __restrict__ lo_out,
    int cols, int in_stride, float eps) {
  const int row = blockIdx.x;
  const float* xr = x + (size_t)row * in_stride;
  float ss = 0.f;
  for (int c = threadIdx.x; c < cols; c += 256) { float v = xr[c]; ss = fmaf(v, v, ss); }
#pragma unroll
  for (int off = 32; off > 0; off >>= 1) ss += __shfl_xor(ss, off);
  __shared__ float red[4];
  if ((threadIdx.x & 63) == 0) red[threadIdx.x >> 6] = ss;
  __syncthreads();
  float tot = red[0] + red[1] + red[2] + red[3];
  float sc = 1.f / sqrtf(tot / (float)cols + eps);
  for (int c = threadIdx.x; c < cols; c += 256) {
    float v = xr[c] * sc * w[c];
    u16 hi = f2b(v);
    hi_out[(size_t)row * cols + c] = hi;
    lo_out[(size_t)row * cols + c] = f2b(v - b2f(hi));
  }
}

// ---- split-precision GEMM (3-term), all-bf16 staging ----
__global__ __launch_bounds__(256) void gemm_split(
    const u16* __restrict__ Ahi, const u16* __restrict__ Alo,
    const u16* __restrict__ Bhi, const u16* __restrict__ Blo,
    float* __restrict__ C, int M, int N, int K) {
  __shared__ u16 Ah[64][72];
  __shared__ u16 Al[64][72];
  __shared__ u16 Bh[64][72];
  __shared__ u16 Bl[64][72];

  const int t = threadIdx.x;
  const int lane = t & 63;
  const int wv = t >> 6;
  const int wr = (wv >> 1) * 32;
  const int wc = (wv & 1) * 32;
  const int bm = blockIdx.y * 64;
  const int bn = blockIdx.x * 64;
  const int lr = t >> 2;
  const int lc = (t & 3) * 16;
  const int rsel = lane & 15;
  const int ksel = 8 * (lane >> 4);

  const u16* Ahrow = Ahi + (size_t)(bm + lr) * K + lc;
  const u16* Alrow = Alo + (size_t)(bm + lr) * K + lc;
  const bool bval = (bn + lr) < N;
  const u16* Bhrow = Bhi + (size_t)(bn + lr) * K + lc;
  const u16* Blrow = Blo + (size_t)(bn + lr) * K + lc;

  f32x4 acc[2][2] = {};

  for (int kt = 0; kt < K; kt += 64) {
    uint4 ah0 = *(const uint4*)(Ahrow + kt);
    uint4 ah1 = *(const uint4*)(Ahrow + kt + 8);
    uint4 al0 = *(const uint4*)(Alrow + kt);
    uint4 al1 = *(const uint4*)(Alrow + kt + 8);
    uint4 bh0 = {0, 0, 0, 0}, bh1 = {0, 0, 0, 0}, bl0 = {0, 0, 0, 0}, bl1 = {0, 0, 0, 0};
    if (bval) {
      bh0 = *(const uint4*)(Bhrow + kt); bh1 = *(const uint4*)(Bhrow + kt + 8);
      bl0 = *(const uint4*)(Blrow + kt); bl1 = *(const uint4*)(Blrow + kt + 8);
    }
    __syncthreads();
    *(uint4*)&Ah[lr][lc] = ah0; *(uint4*)&Ah[lr][lc + 8] = ah1;
    *(uint4*)&Al[lr][lc] = al0; *(uint4*)&Al[lr][lc + 8] = al1;
    *(uint4*)&Bh[lr][lc] = bh0; *(uint4*)&Bh[lr][lc + 8] = bh1;
    *(uint4*)&Bl[lr][lc] = bl0; *(uint4*)&Bl[lr][lc + 8] = bl1;
    __syncthreads();
#pragma unroll
    for (int ks = 0; ks < 2; ++ks) {
      const int ko = ks * 32 + ksel;
      bf16x8 a0h = *(const bf16x8*)&Ah[wr + rsel][ko];
      bf16x8 a1h = *(const bf16x8*)&Ah[wr + 16 + rsel][ko];
      bf16x8 a0l = *(const bf16x8*)&Al[wr + rsel][ko];
      bf16x8 a1l = *(const bf16x8*)&Al[wr + 16 + rsel][ko];
      bf16x8 b0h = *(const bf16x8*)&Bh[wc + rsel][ko];
      bf16x8 b1h = *(const bf16x8*)&Bh[wc + 16 + rsel][ko];
      bf16x8 b0l = *(const bf16x8*)&Bl[wc + rsel][ko];
      bf16x8 b1l = *(const bf16x8*)&Bl[wc + 16 + rsel][ko];
      acc[0][0] = MFMA16(a0h, b0h, acc[0][0]);
      acc[0][0] = MFMA16(a0h, b0l, acc[0][0]);
      acc[0][0] = MFMA16(a0l, b0h, acc[0][0]);
      acc[0][1] = MFMA16(a0h, b1h, acc[0][1]);
      acc[0][1] = MFMA16(a0h, b1l, acc[0][1]);
      acc[0][1] = MFMA16(a0l, b1h, acc[0][1]);
      acc[1][0] = MFMA16(a1h, b0h, acc[1][0]);
      acc[1][0] = MFMA16(a1h, b0l, acc[1][0]);
      acc[1][0] = MFMA16(a1l, b0h, acc[1][0]);
      acc[1][1] = MFMA16(a1h, b1h, acc[1][1]);
      acc[1][1] = MFMA16(a1h, b1l, acc[1][1]);
      acc[1][1] = MFMA16(a1l, b1h, acc[1][1]);
    }
  }
  const int r0 = (lane >> 4) * 4;
#pragma unroll
  for (int fm = 0; fm < 2; ++fm)
#pragma unroll
    for (int fn = 0; fn < 2; ++fn)
#pragma unroll
      for (int j = 0; j < 4; ++j) {
        int row = bm + wr + fm * 16 + r0 + j;
        int col = bn + wc + fn * 16 + rsel;
        if (col < N) C[(size_t)row * N + col] = acc[fm][fn][j];
      }
}

// ---- plain bf16 GEMM (o_w / FFN): 128(M)x64(N) tile, reg-staged.
//      A-tile staged once per 128 rows (halves inter-block A re-reads vs 64-row
//      tiles). 4 waves, each owns 32 rows x 64 cols. ADDX fuses residual add. ----
template <int GATED, int ADDX>
__global__ __launch_bounds__(256) void gemm_kernel(
    const u16* __restrict__ A, const u16* __restrict__ Bt, const float* __restrict__ X,
    float* __restrict__ C, u16* __restrict__ Cg, int M, int N, int K) {
  __shared__ u16 As[128][72];
  __shared__ u16 Bs[64][72];
  __shared__ u16 Bs2[GATED ? 64 : 1][72];

  const int t = threadIdx.x;
  const int lane = t & 63;
  const int wv = t >> 6;
  const int wr = wv * 32;             // wave row base within 128-row tile
  const int bm = blockIdx.y * 128;
  const int bn = blockIdx.x * 64;
  const int lr = t >> 2;              // staging row 0..63
  const int lc = (t & 3) * 16;        // staging col
  const int rsel = lane & 15;
  const int ksel = 8 * (lane >> 4);

  const u16* Arow0 = A + (size_t)(bm + lr) * K + lc;
  const u16* Arow1 = A + (size_t)(bm + 64 + lr) * K + lc;
  const u16* Brow = Bt + (size_t)(bn + lr) * K + lc;
  const u16* Brow2 = Bt + (size_t)(4096 + bn + lr) * K + lc;

  f32x4 acc[2][4] = {};
  f32x4 accg[2][4] = {};

  for (int kt = 0; kt < K; kt += 64) {
    uint4 a00 = *(const uint4*)(Arow0 + kt);
    uint4 a01 = *(const uint4*)(Arow0 + kt + 8);
    uint4 a10 = *(const uint4*)(Arow1 + kt);
    uint4 a11 = *(const uint4*)(Arow1 + kt + 8);
    uint4 b0 = *(const uint4*)(Brow + kt);
    uint4 b1 = *(const uint4*)(Brow + kt + 8);
    uint4 c0 = {0, 0, 0, 0}, c1 = {0, 0, 0, 0};
    if (GATED) { c0 = *(const uint4*)(Brow2 + kt); c1 = *(const uint4*)(Brow2 + kt + 8); }
    __syncthreads();
    *(uint4*)&As[lr][lc] = a00; *(uint4*)&As[lr][lc + 8] = a01;
    *(uint4*)&As[64 + lr][lc] = a10; *(uint4*)&As[64 + lr][lc + 8] = a11;
    *(uint4*)&Bs[lr][lc] = b0; *(uint4*)&Bs[lr][lc + 8] = b1;
    if (GATED) { *(uint4*)&Bs2[lr][lc] = c0; *(uint4*)&Bs2[lr][lc + 8] = c1; }
    __syncthreads();
#pragma unroll
    for (int ks = 0; ks < 2; ++ks) {
      const int ko = ks * 32 + ksel;
      bf16x8 af0 = *(const bf16x8*)&As[wr + rsel][ko];
      bf16x8 af1 = *(const bf16x8*)&As[wr + 16 + rsel][ko];
      bf16x8 bf[4];
#pragma unroll
      for (int fn = 0; fn < 4; ++fn)
        bf[fn] = *(const bf16x8*)&Bs[fn * 16 + rsel][ko];
#pragma unroll
      for (int fn = 0; fn < 4; ++fn) {
        acc[0][fn] = MFMA16(af0, bf[fn], acc[0][fn]);
        acc[1][fn] = MFMA16(af1, bf[fn], acc[1][fn]);
      }
      if (GATED) {
        bf16x8 cf[4];
#pragma unroll
        for (int fn = 0; fn < 4; ++fn)
          cf[fn] = *(const bf16x8*)&Bs2[fn * 16 + rsel][ko];
#pragma unroll
        for (int fn = 0; fn < 4; ++fn) {
          accg[0][fn] = MFMA16(af0, cf[fn], accg[0][fn]);
          accg[1][fn] = MFMA16(af1, cf[fn], accg[1][fn]);
        }
      }
    }
  }
  const int r0 = (lane >> 4) * 4;
#pragma unroll
  for (int fm = 0; fm < 2; ++fm)
#pragma unroll
    for (int fn = 0; fn < 4; ++fn)
#pragma unroll
      for (int j = 0; j < 4; ++j) {
        int row = bm + wr + fm * 16 + r0 + j;
        int col = bn + fn * 16 + rsel;
        size_t o = (size_t)row * N + col;
        if (!GATED) {
          float v = acc[fm][fn][j];
          if (ADDX) v += X[o];
          C[o] = v;
        } else {
          float u = acc[fm][fn][j], g = accg[fm][fn][j];
          float sv = g / (1.f + __expf(-g));
          Cg[o] = f2b(u * sv);
        }
      }
}

// ---------------- build qh / kh (RoPE applied, padded 48->64, hi/lo split) ----------------
__global__ void build_qh_kernel(const float* __restrict__ qfull, const float* __restrict__ fr,
                                const float* __restrict__ fi, u16* __restrict__ qhi,
                                u16* __restrict__ qlo) {
  const int q = blockIdx.x;
  const int h2 = blockIdx.y * 4 + (threadIdx.x >> 6);
  const int d = threadIdx.x & 63;
  const int hh = h2 >> 1, s = h2 & 1;
  const float* row = qfull + (size_t)q * 1536 + hh * 96;
  float val;
  if (d < 32) {
    val = row[s * 32 + d];
  } else if (d < 48) {
    int r = d - 32;
    int pos = q & 511;
    const float* rp = row + 64 + s * 16;
    if (pos == 0) val = rp[r];
    else {
      int j = r >> 1;
      float cr = fr[(pos - 1) * 8 + j], ci = fi[(pos - 1) * 8 + j];
      float a = rp[2 * j], b = rp[2 * j + 1];
      val = (r & 1) ? (a * ci + b * cr) : (a * cr - b * ci);
    }
  } else val = 0.f;
  u16 hi = f2b(val);
  qhi[((size_t)h2 * LQ + q) * 64 + d] = hi;
  qlo[((size_t)h2 * LQ + q) * 64 + d] = f2b(val - b2f(hi));
}

__global__ void build_kh_kernel(const float* __restrict__ kv, const float* __restrict__ ckv,
                                const float* __restrict__ fr, const float* __restrict__ fi,
                                u16* __restrict__ khi, u16* __restrict__ klo) {
  const int kp = blockIdx.x;
  const int h2 = blockIdx.y * 4 + (threadIdx.x >> 6);
  const int d = threadIdx.x & 63;
  const int hh = h2 >> 1, s = h2 & 1;
  float val;
  if (d < 32) {
    val = kv[(size_t)kp * 2048 + hh * 128 + s * 32 + d];
  } else if (d < 48) {
    int r = d - 32;
    int pos = kp & 511;
    const float* rp = ckv + (size_t)kp * 544 + 512 + s * 16;
    if (pos == 0) val = rp[r];
    else {
      int j = r >> 1;
      float cr = fr[(pos - 1) * 8 + j], ci = fi[(pos - 1) * 8 + j];
      float a = rp[2 * j], b = rp[2 * j + 1];
      val = (r & 1) ? (a * ci + b * cr) : (a * cr - b * ci);
    }
  } else val = 0.f;
  u16 hi = f2b(val);
  khi[((size_t)h2 * LQ + kp) * 64 + d] = hi;
  klo[((size_t)h2 * LQ + kp) * 64 + d] = f2b(val - b2f(hi));
}

// vt[h][d][k] = bf16(kv[k][h*128+64+d])  (transposed V for PV B-fragments)
__global__ __launch_bounds__(256) void build_vt_kernel(const float* __restrict__ kv,
                                                       u16* __restrict__ vt) {
  __shared__ u16 tile[64][65];
  int h = blockIdx.y, k0 = blockIdx.x * 64;
  int t = threadIdx.x;
  int d = t & 63, kr = t >> 6;
#pragma unroll
  for (int i = 0; i < 16; ++i) {
    int k = kr + i * 4;
    tile[k][d] = f2b(kv[(size_t)(k0 + k) * 2048 + h * 128 + 64 + d]);
  }
  __syncthreads();
  int kk = t & 63, dr = t >> 6;
#pragma unroll
  for (int i = 0; i < 16; ++i) {
    int d2 = dr + i * 4;
    vt[((size_t)h * 64 + d2) * LQ + k0 + kk] = tile[kk][d2];
  }
}

// lam = exp(sum(lk1*lq1)) - exp(sum(lk2*lq2)) + 0.2
__global__ void lam_kernel(const float* lq1, const float* lk1, const float* lq2,
                           const float* lk2, float* lamp) {
  int t = threadIdx.x;  // 32
  float a = lq1[t] * lk1[t], b = lq2[t] * lk2[t];
#pragma unroll
  for (int off = 1; off < 32; off <<= 1) { a += __shfl_xor(a, off); b += __shfl_xor(b, off); }
  if (t == 0) lamp[0] = expf(a) - expf(b) + 0.2f;
}

// 6-MFMA split-precision 16x16 score tile
#define SCORE6(z, a0h, a1h, a0l, a1l, ph, pl)                         \
  {                                                                   \
    bf16x8 bh0 = *(const bf16x8*)(ph), bh1 = *(const bf16x8*)((ph) + 32); \
    bf16x8 bl0 = *(const bf16x8*)(pl), bl1 = *(const bf16x8*)((pl) + 32); \
    z = MFMA16(a0h, bh0, z); z = MFMA16(a1h, bh1, z);                 \
    z = MFMA16(a0h, bl0, z); z = MFMA16(a1h, bl1, z);                 \
    z = MFMA16(a0l, bh0, z); z = MFMA16(a1l, bh1, z);                 \
  }

// ---- attention Z: zp[s][h2][q] = sum over k-segment s of exp|a| (s = 0..3) ----
// K tiles COOPERATIVELY staged in dbuf LDS (dedup across 4 waves).
__global__ __launch_bounds__(256) void attn_z_kernel(
    const u16* __restrict__ qhi, const u16* __restrict__ khi,
    float* __restrict__ zp) {
  __shared__ u16 Kh[2][64][72];

  const int bid = blockIdx.x;
  const int c = 7 - (bid >> 9);                 // heavy-first
  const int r = bid & 511;
  const int h2 = r & 31;
  const int qtIdx = (r >> 5) & 3;
  const int s = r >> 7;                         // 0..3
  const int qt = qtIdx * 8 + c;
  const int qb = qt * 64;
  const int t = threadIdx.x;
  const int lane = t & 63, wv = t >> 6;
  const int rsel = lane & 15, grp = lane >> 4, ksel = 8 * grp;
  const int qrow = qb + wv * 16;

  const size_t qoff = ((size_t)h2 * LQ + qrow + rsel) * 64 + ksel;
  bf16x8 aq0h = *(const bf16x8*)(qhi + qoff), aq1h = *(const bf16x8*)(qhi + qoff + 32);
  const u16* kh = khi + (size_t)h2 * LQ * 64;

  const int srow = t >> 2;
  const int scol = (t & 3) * 16;

  int qm[4];
  float Z[4] = {0.f, 0.f, 0.f, 0.f};
#pragma unroll
  for (int j = 0; j < 4; ++j) qm[j] = (qrow + grp * 4 + j) & 511;

  const int kbeg = s * 512;
  int buf = 0;
  for (int jt = 0; jt <= c; ++jt) {             // computed tiles only
    const int kt = kbeg + jt * 64;
    const size_t kb = (size_t)(kt + srow) * 64 + scol;
    uint4 r0 = *(const uint4*)(kh + kb);
    uint4 r1 = *(const uint4*)(kh + kb + 8);
    *(uint4*)&Kh[buf][srow][scol] = r0;
    *(uint4*)&Kh[buf][srow][scol + 8] = r1;
    __syncthreads();   // K tile ready (dbuf protects against next-tile WAR)
#pragma unroll
    for (int fk = 0; fk < 4; ++fk) {
      const int krow = fk * 16 + rsel;
      const int k = kt + krow;
      bf16x8 b0 = *(const bf16x8*)&Kh[buf][krow][ksel];
      bf16x8 b1 = *(const bf16x8*)&Kh[buf][krow][ksel + 32];
      f32x4 z = {};
      z = MFMA16(aq0h, b0, z);
      z = MFMA16(aq1h, b1, z);
#pragma unroll
      for (int j = 0; j < 4; ++j)
        if ((k & 511) <= qm[j]) Z[j] += __expf(fabsf(z[j] * SCALING));
    }
    buf ^= 1;
  }
#pragma unroll
  for (int j = 0; j < 4; ++j) {
#pragma unroll
    for (int off = 1; off < 16; off <<= 1) Z[j] += __shfl_xor(Z[j], off);
    if (rsel == 0) {
      int q = qrow + grp * 4 + j;
      zp[((size_t)(s * 32 + h2) << 11) + q] = Z[j];
    }
  }
}

// ---- attention PV: 1D grid 2048 heavy-first, one 512-segment per block ----
// K AND V tiles COOPERATIVELY staged in LDS once per block (dedup across
// waves); pcLDS intra-wave; csLDS dbuf + barrier for colsum.
__global__ __launch_bounds__(256) void attn_pv_kernel(
    const u16* __restrict__ qhi, const u16* __restrict__ qlo,
    const u16* __restrict__ khi, const u16* __restrict__ klo,
    const u16* __restrict__ vt, const float* __restrict__ zp,
    const float* __restrict__ lamp,
    float* __restrict__ O0, float* __restrict__ O123, float* __restrict__ colsum) {
  __shared__ u16 KhA[64][72], KlA[64][72], KhB[64][72], KlB[64][72];
  __shared__ u16 Vs[64][72];
  __shared__ u16 pcLDS[4][16][72];
  __shared__ float csLDS[2][4][64];

  const int bid = blockIdx.x;
  const int c = 7 - (bid >> 8);                 // heavy-first
  const int r = bid & 255;
  const int h = r & 15;
  const int qtIdx = (r >> 4) & 3;
  const int s = r >> 6;                         // 0..3
  const int qt = qtIdx * 8 + c;
  const int qb = qt * 64;
  const int t = threadIdx.x;
  const int lane = t & 63, wv = t >> 6;
  const int rsel = lane & 15, grp = lane >> 4, ksel = 8 * grp;
  const int qrow = qb + wv * 16;
  const float lam = lamp[0];

  const int h2a = 2 * h, h2b = 2 * h + 1;
  const size_t qoffa = ((size_t)h2a * LQ + qrow + rsel) * 64 + ksel;
  const size_t qoffb = ((size_t)h2b * LQ + qrow + rsel) * 64 + ksel;
  bf16x8 aqa0h = *(const bf16x8*)(qhi + qoffa), aqa1h = *(const bf16x8*)(qhi + qoffa + 32);
  bf16x8 aqa0l = *(const bf16x8*)(qlo + qoffa), aqa1l = *(const bf16x8*)(qlo + qoffa + 32);
  bf16x8 aqb0h = *(const bf16x8*)(qhi + qoffb), aqb1h = *(const bf16x8*)(qhi + qoffb + 32);
  bf16x8 aqb0l = *(const bf16x8*)(qlo + qoffb), aqb1l = *(const bf16x8*)(qlo + qoffb + 32);
  const u16* kha = khi + (size_t)h2a * LQ * 64;
  const u16* kla = klo + (size_t)h2a * LQ * 64;
  const u16* khb = khi + (size_t)h2b * LQ * 64;
  const u16* klb = klo + (size_t)h2b * LQ * 64;
  const u16* vb = vt + (size_t)h * 64 * LQ;

  // cooperative staging coords: thread t covers row t>>2, 16 cols at (t&3)*16
  const int srow = t >> 2;
  const int scol = (t & 3) * 16;

  int qm[4];
  float iz1[4], iz2[4];
#pragma unroll
  for (int j = 0; j < 4; ++j) {
    int q = qrow + grp * 4 + j;
    qm[j] = q & 511;
    float z1 = 0.f, z2 = 0.f;
#pragma unroll
    for (int ss = 0; ss < 4; ++ss) {
      z1 += zp[((size_t)(ss * 32 + h2a) << 11) + q];
      z2 += zp[((size_t)(ss * 32 + h2b) << 11) + q];
    }
    iz1[j] = 1.f / z1;
    iz2[j] = 1.f / z2;
  }

  f32x4 accO[4] = {};
  const int kbeg = s * 512;
  int buf = 0;

  // zero colsum for skipped (fully-masked) tiles of this segment
  for (int jt = c + 1; jt < 8; ++jt) {
    if (t < 64) colsum[((size_t)h * 32 + qt) * LQ + kbeg + jt * 64 + t] = 0.f;
  }

  for (int jt = 0; jt <= c; ++jt) {
    const int kt = kbeg + jt * 64;

    // ---- cooperative K + V global loads (dedup across waves) ----
    const size_t kb = (size_t)(kt + srow) * 64 + scol;
    uint4 rha0 = *(const uint4*)(kha + kb);
    uint4 rha1 = *(const uint4*)(kha + kb + 8);
    uint4 rla0 = *(const uint4*)(kla + kb);
    uint4 rla1 = *(const uint4*)(kla + kb + 8);
    uint4 rhb0 = *(const uint4*)(khb + kb);
    uint4 rhb1 = *(const uint4*)(khb + kb + 8);
    uint4 rlb0 = *(const uint4*)(klb + kb);
    uint4 rlb1 = *(const uint4*)(klb + kb + 8);
    // V: row = d (srow), cols = kt + scol..  (vt layout [h][d][k])
    const u16* vsrc = vb + (size_t)srow * LQ + kt + scol;
    uint4 rv0 = *(const uint4*)(vsrc);
    uint4 rv1 = *(const uint4*)(vsrc + 8);

    // prev tile's K/V-LDS reads are fenced by the csLDS barrier of tile jt-1
    *(uint4*)&KhA[srow][scol] = rha0; *(uint4*)&KhA[srow][scol + 8] = rha1;
    *(uint4*)&KlA[srow][scol] = rla0; *(uint4*)&KlA[srow][scol + 8] = rla1;
    *(uint4*)&KhB[srow][scol] = rhb0; *(uint4*)&KhB[srow][scol + 8] = rhb1;
    *(uint4*)&KlB[srow][scol] = rlb0; *(uint4*)&KlB[srow][scol + 8] = rlb1;
    *(uint4*)&Vs[srow][scol] = rv0;  *(uint4*)&Vs[srow][scol + 8] = rv1;
    __syncthreads();   // K/V tile ready

    __builtin_amdgcn_s_setprio(1);
    float pc[4][4], cs[4];
#pragma unroll
    for (int fk = 0; fk < 4; ++fk) {
      const int krow = fk * 16 + rsel;
      const int k = kt + krow;
      f32x4 z = {};
      SCORE6(z, aqa0h, aqa1h, aqa0l, aqa1l, &KhA[krow][ksel], &KlA[krow][ksel]);
      f32x4 w = {};
      SCORE6(w, aqb0h, aqb1h, aqb0l, aqb1l, &KhB[krow][ksel], &KlB[krow][ksel]);
      float csj = 0.f;
#pragma unroll
      for (int j = 0; j < 4; ++j) {
        bool msk = ((k & 511) > qm[j]);
        float sa = z[j] * SCALING;
        float pa = __builtin_copysignf(__expf(fabsf(sa)) * iz1[j], sa);
        pa = msk ? 0.f : pa;
        csj += pa;
        float sb = w[j] * SCALING;
        float pb = __builtin_copysignf(__expf(fabsf(sb)) * iz2[j], sb);
        pc[fk][j] = pa - (msk ? 0.f : lam * pb);
      }
      cs[fk] = csj;
    }
    // pc relayout through OWN pcLDS slice (intra-wave, lgkmcnt-ordered)
#pragma unroll
    for (int fk = 0; fk < 4; ++fk)
#pragma unroll
      for (int j = 0; j < 4; ++j)
        pcLDS[wv][grp * 4 + j][fk * 16 + rsel] = f2b(pc[fk][j]);
    // PV (intra-wave; V read from LDS)
#pragma unroll
    for (int kc = 0; kc < 2; ++kc) {
      bf16x8 ap = *(const bf16x8*)&pcLDS[wv][rsel][kc * 32 + ksel];
#pragma unroll
      for (int fn = 0; fn < 4; ++fn) {
        bf16x8 bv = *(const bf16x8*)&Vs[fn * 16 + rsel][kc * 32 + ksel];
        accO[fn] = MFMA16(ap, bv, accO[fn]);
      }
    }
    __builtin_amdgcn_s_setprio(0);
    // cross-wave colsum (csLDS dbuf + barrier; barrier also fences K/V reads
    // of this tile before next tile's ds_writes)
#pragma unroll
    for (int fk = 0; fk < 4; ++fk) {
      float cc = cs[fk];
      cc += __shfl_xor(cc, 16);
      cc += __shfl_xor(cc, 32);
      if (grp == 0) csLDS[buf][wv][fk * 16 + rsel] = cc;
    }
    __syncthreads();
    if (t < 64) {
      float tot = csLDS[buf][0][t] + csLDS[buf][1][t] + csLDS[buf][2][t] + csLDS[buf][3][t];
      colsum[((size_t)h * 32 + qt) * LQ + kt + t] = tot;
    }
    buf ^= 1;
  }
  float* Op = (s == 0) ? O0 : (O123 + (size_t)(s - 1) * 16 * LQ * 64);
#pragma unroll
  for (int fn = 0; fn < 4; ++fn)
#pragma unroll
    for (int j = 0; j < 4; ++j) {
      int q = qrow + grp * 4 + j;
      int d = fn * 16 + rsel;
      Op[((size_t)h * LQ + q) * 64 + d] = accO[fn][j];
    }
}

// g[h][k] = sum_qt colsum[h][qt][k] / 2048
__global__ void g_reduce_kernel(const float* __restrict__ colsum, float* __restrict__ g) {
  int idx = blockIdx.x * 256 + threadIdx.x;
  if (idx >= 16 * LQ) return;
  int h = idx >> 11, k = idx & 2047;
  float s = 0.f;
#pragma unroll
  for (int qt = 0; qt < 32; ++qt) s += colsum[((size_t)h * 32 + qt) * LQ + k];
  g[idx] = s * (1.f / 2048.f);
}

// Gv[h][r][d] = sum_seg g[h][seg*512+r] * vt[h][d][seg*512+r]
__global__ void gv_kernel(const float* __restrict__ g, const u16* __restrict__ vt,
                          float* __restrict__ Gv) {
  int idx = blockIdx.x * 256 + threadIdx.x;
  if (idx >= 16 * 512 * 64) return;
  int d = idx & 63, r = (idx >> 6) & 511, h = idx >> 15;
  float s = 0.f;
#pragma unroll
  for (int seg = 0; seg < 4; ++seg) {
    int k = seg * 512 + r;
    s += g[h * 2048 + k] * b2f(vt[((size_t)h * 64 + d) * LQ + k]);
  }
  Gv[idx] = s;
}

// W[h][r][d] = inclusive prefix over r of Gv[h][r][d]
__global__ __launch_bounds__(512) void wscan_kernel(const float* __restrict__ Gv,
                                                    float* __restrict__ W) {
  __shared__ float s[512];
  int h = blockIdx.x >> 6, d = blockIdx.x & 63;
  int t = threadIdx.x;
  s[t] = Gv[((size_t)h * 512 + t) * 64 + d];
  __syncthreads();
  for (int off = 1; off < 512; off <<= 1) {
    float add = (t >= off) ? s[t - off] : 0.f;
    __syncthreads();
    s[t] += add;
    __syncthreads();
  }
  W[((size_t)h * 512 + t) * 64 + d] = s[t];
}

// out_pre = O0 + O1 + O2 + O3 + lam*W[q%512]; head rmsnorm -> bf16 [q][h*64+d]
__global__ __launch_bounds__(256) void combine_norm_kernel(
    const float* __restrict__ O0, const float* __restrict__ O123,
    const float* __restrict__ W, const float* __restrict__ hw,
    const float* __restrict__ lamp, u16* __restrict__ out) {
  const int q = blockIdx.x;
  const int h = blockIdx.y * 4 + (threadIdx.x >> 6);
  const int d = threadIdx.x & 63;
  const float lam = lamp[0];
  const size_t S = (size_t)16 * LQ * 64;
  const size_t idx = ((size_t)h * LQ + q) * 64 + d;
  float v = O0[idx] + O123[idx] + O123[idx + S] + O123[idx + 2 * S] +
            lam * W[((size_t)h * 512 + (q & 511)) * 64 + d];
  float ss = v * v;
#pragma unroll
  for (int off = 1; off < 64; off <<= 1) ss += __shfl_xor(ss, off);
  float sc = 1.f / sqrtf(ss * (1.f / 64.f) + 1e-5f);
  out[(size_t)q * 1024 + h * 64 + d] = f2b(v * sc * hw[d]);
}

// ============================== launch ==============================
extern "C" void kernel_launch(void* const* d_in, const int* in_sizes, int n_in,
                              void* d_out, int out_size, void* d_ws, size_t ws_size,
                              hipStream_t stream) {
  const float* x = (const float*)d_in[0];
  const float* freqs_r = (const float*)d_in[1];
  const float* freqs_i = (const float*)d_in[2];
  // d_in[3] = mask (recomputed analytically)
  const float* kv_down_w = (const float*)d_in[4];
  const float* q_down_w = (const float*)d_in[5];
  const float* kv_up_w = (const float*)d_in[6];
  const float* q_up_w = (const float*)d_in[7];
  const float* kv_norm_w = (const float*)d_in[8];
  const float* q_norm_w = (const float*)d_in[9];
  const float* o_w = (const float*)d_in[10];
  const float* lambda_q1 = (const float*)d_in[11];
  const float* lambda_k1 = (const float*)d_in[12];
  const float* lambda_q2 = (const float*)d_in[13];
  const float* lambda_k2 = (const float*)d_in[14];
  const float* head_norm_w = (const float*)d_in[15];
  const float* norm1_w = (const float*)d_in[16];
  const float* norm2_w = (const float*)d_in[17];
  const float* ff_in_w = (const float*)d_in[18];
  const float* ff_out_w = (const float*)d_in[19];
  float* out = (float*)d_out;
  char* ws = (char*)d_ws;

  // ---- weights region (persistent except down/up: dead after projections) ----
  const size_t WT_KVD_H = 0;                                  // 544x1024 bf16
  const size_t WT_KVD_L = WT_KVD_H + (size_t)544 * 1024 * 2;
  const size_t WT_QD_H  = WT_KVD_L + (size_t)544 * 1024 * 2;  // 512x1024
  const size_t WT_QD_L  = WT_QD_H + (size_t)512 * 1024 * 2;
  const size_t WT_KVU_H = WT_QD_L + (size_t)512 * 1024 * 2;   // 2048x512
  const size_t WT_KVU_L = WT_KVU_H + (size_t)2048 * 512 * 2;
  const size_t WT_QU_H  = WT_KVU_L + (size_t)2048 * 512 * 2;  // 1536x512
  const size_t WT_QU_L  = WT_QU_H + (size_t)1536 * 512 * 2;
  const size_t WT_OW    = WT_QU_L + (size_t)1536 * 512 * 2;   // = 11,714,560
  const size_t WT_FFI   = WT_OW + (size_t)1024 * 1024 * 2;
  const size_t WT_FFO   = WT_FFI + (size_t)8192 * 1024 * 2;
  const size_t A0 = WT_FFO + (size_t)1024 * 4096 * 2;         // = 38,928,384

  // ---- activations (lifetime-aliased) ----
  const size_t H     = A0;                  // h hi/lo bf16 (2x 4,194,304); dead after down-GEMMs
  const size_t CKV   = A0 + 8388608;        // f32 2048x544;  dead after build_kh
  const size_t CKVN  = A0 + 12845056;       // ckvn hi/lo bf16 (2x 2,097,152); dead after kv_up
  const size_t KVB   = A0 + 17039360;       // f32 2048x2048; dead after build_vt
  const size_t CQ    = A0 + 33816576;       // f32 2048x512;  dead after rmsnorm
  const size_t CQN   = A0 + 38010880;       // cqn hi/lo bf16 (2x 2,097,152); dead after q_up
  const size_t QFULL = A0 + 42205184;       // f32 2048x1536; dead after build_qh
  // mid buffers (aliases):
  const size_t QHI = H;                     // bf16 32x2048x64 over dead H
  const size_t KHI = QFULL;                 // bf16 32x2048x64 over dead QFULL[0:8.39M]
  const size_t KLO = A0 + 50593792;         // bf16 32x2048x64 over dead QFULL[8.39M:]+
  const size_t QLO = A0 + 58982400;         // bf16 32x2048x64
  const size_t VT  = CKVN;                  // bf16 16x64x2048 over dead CKVN
  // O partials (4 x 8,388,608 f32):
  const size_t OP0   = 0;                   // over dead down/up weights [0, 8.39M) < WT_OW
  const size_t OP123 = KVB;                 // 3 contiguous partials over dead KVB+CQ+CQN
  const size_t CS  = CKV;                   // f32 16x32x2048 over dead CKV
  const size_t GB  = A0 + 67371008;         // f32 16x2048 (131,072)
  const size_t GV  = A0 + 67502080;         // f32 16x512x64 (2,097,152)
  const size_t WB  = A0 + 69599232;         // f32 16x512x64 (2,097,152)
  const size_t LAM = A0 + 71696384;         // scalar
  const size_t ZP  = A0 + 71696640;         // f32 4x32x2048 (1,048,576)
  const size_t WS_END = A0 + 72745216;      // ~111.7 MB (known-safe)
  // late aliases:
  const size_t ATTN  = CKV;                 // bf16 2048x1024 (over consumed CS)
  const size_t X1    = KVB + 8388608;       // f32 2048x1024 (partials consumed by combine)
  const size_t H2N   = H;                   // bf16 2048x1024 over dead QHI
  const size_t FFACT = QFULL;               // bf16 2048x4096 over dead KHI+KLO

  if (ws_size < WS_END) return;

  u16* wt_kvd_h = (u16*)(ws + WT_KVD_H); u16* wt_kvd_l = (u16*)(ws + WT_KVD_L);
  u16* wt_qd_h  = (u16*)(ws + WT_QD_H);  u16* wt_qd_l  = (u16*)(ws + WT_QD_L);
  u16* wt_kvu_h = (u16*)(ws + WT_KVU_H); u16* wt_kvu_l = (u16*)(ws + WT_KVU_L);
  u16* wt_qu_h  = (u16*)(ws + WT_QU_H);  u16* wt_qu_l  = (u16*)(ws + WT_QU_L);
  u16* wt_ow  = (u16*)(ws + WT_OW);
  u16* wt_ffi = (u16*)(ws + WT_FFI);
  u16* wt_ffo = (u16*)(ws + WT_FFO);
  u16* h_hi   = (u16*)(ws + H);
  u16* h_lo   = (u16*)(ws + H + 4194304);
  float* ckv  = (float*)(ws + CKV);
  u16* ckvn_hi = (u16*)(ws + CKVN);
  u16* ckvn_lo = (u16*)(ws + CKVN + 2097152);
  float* kvb  = (float*)(ws + KVB);
  float* cq   = (float*)(ws + CQ);
  u16* cqn_hi = (u16*)(ws + CQN);
  u16* cqn_lo = (u16*)(ws + CQN + 2097152);
  float* qfull = (float*)(ws + QFULL);
  u16* qhib = (u16*)(ws + QHI); u16* qlob = (u16*)(ws + QLO);
  u16* khib = (u16*)(ws + KHI); u16* klob = (u16*)(ws + KLO);
  u16* vtb  = (u16*)(ws + VT);
  float* zpb = (float*)(ws + ZP);
  float* Op0 = (float*)(ws + OP0);
  float* Op123 = (float*)(ws + OP123);
  float* csb = (float*)(ws + CS);
  float* gb  = (float*)(ws + GB);
  float* gvb = (float*)(ws + GV);
  float* wbb = (float*)(ws + WB);
  float* lamp = (float*)(ws + LAM);
  u16* attn_n = (u16*)(ws + ATTN);
  float* x1 = (float*)(ws + X1);
  u16* h2n = (u16*)(ws + H2N);
  u16* ffact = (u16*)(ws + FFACT);

  dim3 tb(32, 8);
  transpose_split<<<dim3(17, 32), tb, 0, stream>>>(kv_down_w, wt_kvd_h, wt_kvd_l, 1024, 544);
  transpose_split<<<dim3(16, 32), tb, 0, stream>>>(q_down_w, wt_qd_h, wt_qd_l, 1024, 512);
  transpose_split<<<dim3(64, 16), tb, 0, stream>>>(kv_up_w, wt_kvu_h, wt_kvu_l, 512, 2048);
  transpose_split<<<dim3(48, 16), tb, 0, stream>>>(q_up_w, wt_qu_h, wt_qu_l, 512, 1536);
  transpose_to_bf16<<<dim3(32, 32), tb, 0, stream>>>(o_w, wt_ow, 1024, 1024);
  transpose_to_bf16<<<dim3(256, 32), tb, 0, stream>>>(ff_in_w, wt_ffi, 1024, 8192);
  transpose_to_bf16<<<dim3(32, 128), tb, 0, stream>>>(ff_out_w, wt_ffo, 4096, 1024);

  rmsnorm_split_kernel<<<2048, 256, 0, stream>>>(x, norm1_w, h_hi, h_lo, 1024, 1024, FEPS);
  gemm_split<<<dim3(9, 32), 256, 0, stream>>>(h_hi, h_lo, wt_kvd_h, wt_kvd_l, ckv,
                                              2048, 544, 1024);
  rmsnorm_split_kernel<<<2048, 256, 0, stream>>>(ckv, kv_norm_w, ckvn_hi, ckvn_lo,
                                                 512, 544, FEPS);
  gemm_split<<<dim3(32, 32), 256, 0, stream>>>(ckvn_hi, ckvn_lo, wt_kvu_h, wt_kvu_l, kvb,
                                               2048, 2048, 512);
  gemm_split<<<dim3(8, 32), 256, 0, stream>>>(h_hi, h_lo, wt_qd_h, wt_qd_l, cq,
                                              2048, 512, 1024);
  rmsnorm_split_kernel<<<2048, 256, 0, stream>>>(cq, q_norm_w, cqn_hi, cqn_lo,
                                                 512, 512, FEPS);
  gemm_split<<<dim3(24, 32), 256, 0, stream>>>(cqn_hi, cqn_lo, wt_qu_h, wt_qu_l, qfull,
                                               2048, 1536, 512);

  build_qh_kernel<<<dim3(2048, 8), 256, 0, stream>>>(qfull, freqs_r, freqs_i, qhib, qlob);
  build_kh_kernel<<<dim3(2048, 8), 256, 0, stream>>>(kvb, ckv, freqs_r, freqs_i, khib, klob);
  build_vt_kernel<<<dim3(32, 16), 256, 0, stream>>>(kvb, vtb);

  lam_kernel<<<1, 32, 0, stream>>>(lambda_q1, lambda_k1, lambda_q2, lambda_k2, lamp);
  attn_z_kernel<<<4096, 256, 0, stream>>>(qhib, khib, zpb);
  attn_pv_kernel<<<2048, 256, 0, stream>>>(qhib, qlob, khib, klob, vtb, zpb,
                                           lamp, Op0, Op123, csb);

  g_reduce_kernel<<<128, 256, 0, stream>>>(csb, gb);
  gv_kernel<<<2048, 256, 0, stream>>>(gb, vtb, gvb);
  wscan_kernel<<<1024, 512, 0, stream>>>(gvb, wbb);
  combine_norm_kernel<<<dim3(2048, 4), 256, 0, stream>>>(Op0, Op123, wbb, head_norm_w,
                                                         lamp, attn_n);

  // x1 = x + attn_n @ o_w  (residual fused into epilogue); tiles M=128 x N=64
  gemm_kernel<0, 1><<<dim3(16, 16), 256, 0, stream>>>(attn_n, wt_ow, x, x1, nullptr,
                                                      2048, 1024, 1024);
  rmsnorm_kernel<1><<<2048, 256, 0, stream>>>(x1, norm2_w, h2n, 1024, 1024, FEPS);
  gemm_kernel<1, 0><<<dim3(64, 16), 256, 0, stream>>>(h2n, wt_ffi, nullptr, nullptr, ffact,
                                                      2048, 4096, 1024);
  // out = x1 + ffact @ ff_out  (residual fused into epilogue)
  gemm_kernel<0, 1><<<dim3(16, 16), 256, 0, stream>>>(ffact, wt_ffo, x1, out, nullptr,
                                                      2048, 1024, 4096);
}

// Round 22
// 392.174 us; speedup vs baseline: 1.0381x; 1.0381x over previous
//
#include <hip/hip_runtime.h>
#include <math.h>

#define LQ 2048
#define SCALING 0.14433756729740643f   // 48^-0.5
#define FEPS 1.1920928955078125e-07f   // np.finfo(float32).eps

typedef unsigned short u16;
typedef __attribute__((ext_vector_type(8))) short bf16x8;
typedef __attribute__((ext_vector_type(4))) float f32x4;

#define MFMA16(a, b, c) __builtin_amdgcn_mfma_f32_16x16x32_bf16((a), (b), (c), 0, 0, 0)

__device__ __forceinline__ u16 f2b(float x) {
  union { float f; unsigned u; } v; v.f = x;
  return (u16)((v.u + 0x7FFFu + ((v.u >> 16) & 1u)) >> 16);
}
__device__ __forceinline__ float b2f(u16 b) {
  union { unsigned u; float f; } v; v.u = ((unsigned)b) << 16;
  return v.f;
}

// ---------------- weight fp32 [K][N] -> bf16 [N][K] (single) ----------------
__global__ void transpose_to_bf16(const float* __restrict__ W, u16* __restrict__ Wt,
                                  int K, int N) {
  __shared__ float tile[32][33];
  int n0 = blockIdx.x * 32, k0 = blockIdx.y * 32;
  int tx = threadIdx.x, ty = threadIdx.y;  // 32 x 8
  for (int i = ty; i < 32; i += 8) {
    int k = k0 + i, n = n0 + tx;
    tile[i][tx] = (k < K && n < N) ? W[(size_t)k * N + n] : 0.f;
  }
  __syncthreads();
  for (int i = ty; i < 32; i += 8) {
    int n = n0 + i, k = k0 + tx;
    if (n < N && k < K) Wt[(size_t)n * K + k] = f2b(tile[tx][i]);
  }
}

// ---------------- weight fp32 [K][N] -> hi/lo bf16 [N][K] ----------------
__global__ void transpose_split(const float* __restrict__ W, u16* __restrict__ Whi,
                                u16* __restrict__ Wlo, int K, int N) {
  __shared__ float tile[32][33];
  int n0 = blockIdx.x * 32, k0 = blockIdx.y * 32;
  int tx = threadIdx.x, ty = threadIdx.y;  // 32 x 8
  for (int i = ty; i < 32; i += 8) {
    int k = k0 + i, n = n0 + tx;
    tile[i][tx] = (k < K && n < N) ? W[(size_t)k * N + n] : 0.f;
  }
  __syncthreads();
  for (int i = ty; i < 32; i += 8) {
    int n = n0 + i, k = k0 + tx;
    if (n < N && k < K) {
      float x = tile[tx][i];
      u16 hi = f2b(x);
      float lo = x - b2f(hi);
      Whi[(size_t)n * K + k] = hi;
      Wlo[(size_t)n * K + k] = f2b(lo);
    }
  }
}

// ---------------- rmsnorm fp32 in (strided) -> fp32 or bf16 out ----------------
template <int BF16OUT>
__global__ __launch_bounds__(256) void rmsnorm_kernel(
    const float* __restrict__ x, const float* __restrict__ w, void* __restrict__ outv,
    int cols, int in_stride, float eps) {
  const int row = blockIdx.x;
  const float* xr = x + (size_t)row * in_stride;
  float ss = 0.f;
  for (int c = threadIdx.x; c < cols; c += 256) { float v = xr[c]; ss = fmaf(v, v, ss); }
#pragma unroll
  for (int off = 32; off > 0; off >>= 1) ss += __shfl_xor(ss, off);
  __shared__ float red[4];
  if ((threadIdx.x & 63) == 0) red[threadIdx.x >> 6] = ss;
  __syncthreads();
  float tot = red[0] + red[1] + red[2] + red[3];
  float sc = 1.f / sqrtf(tot / (float)cols + eps);
  for (int c = threadIdx.x; c < cols; c += 256) {
    float v = xr[c] * sc * w[c];
    if (BF16OUT) ((u16*)outv)[(size_t)row * cols + c] = f2b(v);
    else ((float*)outv)[(size_t)row * cols + c] = v;
  }
}

// ---- rmsnorm fp32 in (strided) -> hi/lo bf16 out (split once, reused by gemm) ----
__global__ __launch_bounds__(256) void rmsnorm_split_kernel(
    const float* __restrict__ x, const float* __restrict__ w,
    u16* __restrict__ hi_out, u16* __restrict__ lo_out,
    int cols, int in_stride, float eps) {
  const int row = blockIdx.x;
  const float* xr = x + (size_t)row * in_stride;
  float ss = 0.f;
  for (int c = threadIdx.x; c < cols; c += 256) { float v = xr[c]; ss = fmaf(v, v, ss); }
#pragma unroll
  for (int off = 32; off > 0; off >>= 1) ss += __shfl_xor(ss, off);
  __shared__ float red[4];
  if ((threadIdx.x & 63) == 0) red[threadIdx.x >> 6] = ss;
  __syncthreads();
  float tot = red[0] + red[1] + red[2] + red[3];
  float sc = 1.f / sqrtf(tot / (float)cols + eps);
  for (int c = threadIdx.x; c < cols; c += 256) {
    float v = xr[c] * sc * w[c];
    u16 hi = f2b(v);
    hi_out[(size_t)row * cols + c] = hi;
    lo_out[(size_t)row * cols + c] = f2b(v - b2f(hi));
  }
}

// ---- split-precision GEMM (3-term), all-bf16 staging ----
__global__ __launch_bounds__(256) void gemm_split(
    const u16* __restrict__ Ahi, const u16* __restrict__ Alo,
    const u16* __restrict__ Bhi, const u16* __restrict__ Blo,
    float* __restrict__ C, int M, int N, int K) {
  __shared__ u16 Ah[64][72];
  __shared__ u16 Al[64][72];
  __shared__ u16 Bh[64][72];
  __shared__ u16 Bl[64][72];

  const int t = threadIdx.x;
  const int lane = t & 63;
  const int wv = t >> 6;
  const int wr = (wv >> 1) * 32;
  const int wc = (wv & 1) * 32;
  const int bm = blockIdx.y * 64;
  const int bn = blockIdx.x * 64;
  const int lr = t >> 2;
  const int lc = (t & 3) * 16;
  const int rsel = lane & 15;
  const int ksel = 8 * (lane >> 4);

  const u16* Ahrow = Ahi + (size_t)(bm + lr) * K + lc;
  const u16* Alrow = Alo + (size_t)(bm + lr) * K + lc;
  const bool bval = (bn + lr) < N;
  const u16* Bhrow = Bhi + (size_t)(bn + lr) * K + lc;
  const u16* Blrow = Blo + (size_t)(bn + lr) * K + lc;

  f32x4 acc[2][2] = {};

  for (int kt = 0; kt < K; kt += 64) {
    uint4 ah0 = *(const uint4*)(Ahrow + kt);
    uint4 ah1 = *(const uint4*)(Ahrow + kt + 8);
    uint4 al0 = *(const uint4*)(Alrow + kt);
    uint4 al1 = *(const uint4*)(Alrow + kt + 8);
    uint4 bh0 = {0, 0, 0, 0}, bh1 = {0, 0, 0, 0}, bl0 = {0, 0, 0, 0}, bl1 = {0, 0, 0, 0};
    if (bval) {
      bh0 = *(const uint4*)(Bhrow + kt); bh1 = *(const uint4*)(Bhrow + kt + 8);
      bl0 = *(const uint4*)(Blrow + kt); bl1 = *(const uint4*)(Blrow + kt + 8);
    }
    __syncthreads();
    *(uint4*)&Ah[lr][lc] = ah0; *(uint4*)&Ah[lr][lc + 8] = ah1;
    *(uint4*)&Al[lr][lc] = al0; *(uint4*)&Al[lr][lc + 8] = al1;
    *(uint4*)&Bh[lr][lc] = bh0; *(uint4*)&Bh[lr][lc + 8] = bh1;
    *(uint4*)&Bl[lr][lc] = bl0; *(uint4*)&Bl[lr][lc + 8] = bl1;
    __syncthreads();
#pragma unroll
    for (int ks = 0; ks < 2; ++ks) {
      const int ko = ks * 32 + ksel;
      bf16x8 a0h = *(const bf16x8*)&Ah[wr + rsel][ko];
      bf16x8 a1h = *(const bf16x8*)&Ah[wr + 16 + rsel][ko];
      bf16x8 a0l = *(const bf16x8*)&Al[wr + rsel][ko];
      bf16x8 a1l = *(const bf16x8*)&Al[wr + 16 + rsel][ko];
      bf16x8 b0h = *(const bf16x8*)&Bh[wc + rsel][ko];
      bf16x8 b1h = *(const bf16x8*)&Bh[wc + 16 + rsel][ko];
      bf16x8 b0l = *(const bf16x8*)&Bl[wc + rsel][ko];
      bf16x8 b1l = *(const bf16x8*)&Bl[wc + 16 + rsel][ko];
      acc[0][0] = MFMA16(a0h, b0h, acc[0][0]);
      acc[0][0] = MFMA16(a0h, b0l, acc[0][0]);
      acc[0][0] = MFMA16(a0l, b0h, acc[0][0]);
      acc[0][1] = MFMA16(a0h, b1h, acc[0][1]);
      acc[0][1] = MFMA16(a0h, b1l, acc[0][1]);
      acc[0][1] = MFMA16(a0l, b1h, acc[0][1]);
      acc[1][0] = MFMA16(a1h, b0h, acc[1][0]);
      acc[1][0] = MFMA16(a1h, b0l, acc[1][0]);
      acc[1][0] = MFMA16(a1l, b0h, acc[1][0]);
      acc[1][1] = MFMA16(a1h, b1h, acc[1][1]);
      acc[1][1] = MFMA16(a1h, b1l, acc[1][1]);
      acc[1][1] = MFMA16(a1l, b1h, acc[1][1]);
    }
  }
  const int r0 = (lane >> 4) * 4;
#pragma unroll
  for (int fm = 0; fm < 2; ++fm)
#pragma unroll
    for (int fn = 0; fn < 2; ++fn)
#pragma unroll
      for (int j = 0; j < 4; ++j) {
        int row = bm + wr + fm * 16 + r0 + j;
        int col = bn + wc + fn * 16 + rsel;
        if (col < N) C[(size_t)row * N + col] = acc[fm][fn][j];
      }
}

// ---- plain bf16 GEMM (o_w / FFN): 64x64 reg-staged (r20 version; M=128 tile
//      regressed — fewer blocks starved CUs). ADDX fuses residual add. ----
template <int GATED, int ADDX>
__global__ __launch_bounds__(256) void gemm_kernel(
    const u16* __restrict__ A, const u16* __restrict__ Bt, const float* __restrict__ X,
    float* __restrict__ C, u16* __restrict__ Cg, int M, int N, int K) {
  __shared__ u16 As[64][72];
  __shared__ u16 Bs[64][72];
  __shared__ u16 Bs2[GATED ? 64 : 1][72];

  const int t = threadIdx.x;
  const int lane = t & 63;
  const int wv = t >> 6;
  const int wr = (wv >> 1) * 32;
  const int wc = (wv & 1) * 32;
  const int bm = blockIdx.y * 64;
  const int bn = blockIdx.x * 64;
  const int lr = t >> 2;
  const int lc = (t & 3) * 16;
  const int rsel = lane & 15;
  const int ksel = 8 * (lane >> 4);

  const u16* Arow = A + (size_t)(bm + lr) * K + lc;
  const u16* Brow = Bt + (size_t)(bn + lr) * K + lc;
  const u16* Brow2 = Bt + (size_t)(4096 + bn + lr) * K + lc;

  f32x4 acc[2][2] = {};
  f32x4 accg[2][2] = {};

  for (int kt = 0; kt < K; kt += 64) {
    uint4 a0 = *(const uint4*)(Arow + kt);
    uint4 a1 = *(const uint4*)(Arow + kt + 8);
    uint4 b0 = *(const uint4*)(Brow + kt);
    uint4 b1 = *(const uint4*)(Brow + kt + 8);
    uint4 c0 = {0, 0, 0, 0}, c1 = {0, 0, 0, 0};
    if (GATED) { c0 = *(const uint4*)(Brow2 + kt); c1 = *(const uint4*)(Brow2 + kt + 8); }
    __syncthreads();
    *(uint4*)&As[lr][lc] = a0; *(uint4*)&As[lr][lc + 8] = a1;
    *(uint4*)&Bs[lr][lc] = b0; *(uint4*)&Bs[lr][lc + 8] = b1;
    if (GATED) { *(uint4*)&Bs2[lr][lc] = c0; *(uint4*)&Bs2[lr][lc + 8] = c1; }
    __syncthreads();
#pragma unroll
    for (int ks = 0; ks < 2; ++ks) {
      const int ko = ks * 32 + ksel;
      bf16x8 af0 = *(const bf16x8*)&As[wr + rsel][ko];
      bf16x8 af1 = *(const bf16x8*)&As[wr + 16 + rsel][ko];
      bf16x8 bf0 = *(const bf16x8*)&Bs[wc + rsel][ko];
      bf16x8 bf1 = *(const bf16x8*)&Bs[wc + 16 + rsel][ko];
      acc[0][0] = MFMA16(af0, bf0, acc[0][0]);
      acc[0][1] = MFMA16(af0, bf1, acc[0][1]);
      acc[1][0] = MFMA16(af1, bf0, acc[1][0]);
      acc[1][1] = MFMA16(af1, bf1, acc[1][1]);
      if (GATED) {
        bf16x8 cf0 = *(const bf16x8*)&Bs2[wc + rsel][ko];
        bf16x8 cf1 = *(const bf16x8*)&Bs2[wc + 16 + rsel][ko];
        accg[0][0] = MFMA16(af0, cf0, accg[0][0]);
        accg[0][1] = MFMA16(af0, cf1, accg[0][1]);
        accg[1][0] = MFMA16(af1, cf0, accg[1][0]);
        accg[1][1] = MFMA16(af1, cf1, accg[1][1]);
      }
    }
  }
  const int r0 = (lane >> 4) * 4;
#pragma unroll
  for (int fm = 0; fm < 2; ++fm)
#pragma unroll
    for (int fn = 0; fn < 2; ++fn)
#pragma unroll
      for (int j = 0; j < 4; ++j) {
        int row = bm + wr + fm * 16 + r0 + j;
        int col = bn + wc + fn * 16 + rsel;
        size_t o = (size_t)row * N + col;
        if (!GATED) {
          float v = acc[fm][fn][j];
          if (ADDX) v += X[o];
          C[o] = v;
        } else {
          float u = acc[fm][fn][j], g = accg[fm][fn][j];
          float sv = g / (1.f + __expf(-g));
          Cg[o] = f2b(u * sv);
        }
      }
}

// ---------------- build qh / kh (RoPE applied, padded 48->64, hi/lo split) ----------------
__global__ void build_qh_kernel(const float* __restrict__ qfull, const float* __restrict__ fr,
                                const float* __restrict__ fi, u16* __restrict__ qhi,
                                u16* __restrict__ qlo) {
  const int q = blockIdx.x;
  const int h2 = blockIdx.y * 4 + (threadIdx.x >> 6);
  const int d = threadIdx.x & 63;
  const int hh = h2 >> 1, s = h2 & 1;
  const float* row = qfull + (size_t)q * 1536 + hh * 96;
  float val;
  if (d < 32) {
    val = row[s * 32 + d];
  } else if (d < 48) {
    int r = d - 32;
    int pos = q & 511;
    const float* rp = row + 64 + s * 16;
    if (pos == 0) val = rp[r];
    else {
      int j = r >> 1;
      float cr = fr[(pos - 1) * 8 + j], ci = fi[(pos - 1) * 8 + j];
      float a = rp[2 * j], b = rp[2 * j + 1];
      val = (r & 1) ? (a * ci + b * cr) : (a * cr - b * ci);
    }
  } else val = 0.f;
  u16 hi = f2b(val);
  qhi[((size_t)h2 * LQ + q) * 64 + d] = hi;
  qlo[((size_t)h2 * LQ + q) * 64 + d] = f2b(val - b2f(hi));
}

__global__ void build_kh_kernel(const float* __restrict__ kv, const float* __restrict__ ckv,
                                const float* __restrict__ fr, const float* __restrict__ fi,
                                u16* __restrict__ khi, u16* __restrict__ klo) {
  const int kp = blockIdx.x;
  const int h2 = blockIdx.y * 4 + (threadIdx.x >> 6);
  const int d = threadIdx.x & 63;
  const int hh = h2 >> 1, s = h2 & 1;
  float val;
  if (d < 32) {
    val = kv[(size_t)kp * 2048 + hh * 128 + s * 32 + d];
  } else if (d < 48) {
    int r = d - 32;
    int pos = kp & 511;
    const float* rp = ckv + (size_t)kp * 544 + 512 + s * 16;
    if (pos == 0) val = rp[r];
    else {
      int j = r >> 1;
      float cr = fr[(pos - 1) * 8 + j], ci = fi[(pos - 1) * 8 + j];
      float a = rp[2 * j], b = rp[2 * j + 1];
      val = (r & 1) ? (a * ci + b * cr) : (a * cr - b * ci);
    }
  } else val = 0.f;
  u16 hi = f2b(val);
  khi[((size_t)h2 * LQ + kp) * 64 + d] = hi;
  klo[((size_t)h2 * LQ + kp) * 64 + d] = f2b(val - b2f(hi));
}

// vt[h][d][k] = bf16(kv[k][h*128+64+d])  (transposed V for PV B-fragments)
__global__ __launch_bounds__(256) void build_vt_kernel(const float* __restrict__ kv,
                                                       u16* __restrict__ vt) {
  __shared__ u16 tile[64][65];
  int h = blockIdx.y, k0 = blockIdx.x * 64;
  int t = threadIdx.x;
  int d = t & 63, kr = t >> 6;
#pragma unroll
  for (int i = 0; i < 16; ++i) {
    int k = kr + i * 4;
    tile[k][d] = f2b(kv[(size_t)(k0 + k) * 2048 + h * 128 + 64 + d]);
  }
  __syncthreads();
  int kk = t & 63, dr = t >> 6;
#pragma unroll
  for (int i = 0; i < 16; ++i) {
    int d2 = dr + i * 4;
    vt[((size_t)h * 64 + d2) * LQ + k0 + kk] = tile[kk][d2];
  }
}

// lam = exp(sum(lk1*lq1)) - exp(sum(lk2*lq2)) + 0.2
__global__ void lam_kernel(const float* lq1, const float* lk1, const float* lq2,
                           const float* lk2, float* lamp) {
  int t = threadIdx.x;  // 32
  float a = lq1[t] * lk1[t], b = lq2[t] * lk2[t];
#pragma unroll
  for (int off = 1; off < 32; off <<= 1) { a += __shfl_xor(a, off); b += __shfl_xor(b, off); }
  if (t == 0) lamp[0] = expf(a) - expf(b) + 0.2f;
}

// 6-MFMA split-precision 16x16 score tile
#define SCORE6(z, a0h, a1h, a0l, a1l, ph, pl)                         \
  {                                                                   \
    bf16x8 bh0 = *(const bf16x8*)(ph), bh1 = *(const bf16x8*)((ph) + 32); \
    bf16x8 bl0 = *(const bf16x8*)(pl), bl1 = *(const bf16x8*)((pl) + 32); \
    z = MFMA16(a0h, bh0, z); z = MFMA16(a1h, bh1, z);                 \
    z = MFMA16(a0h, bl0, z); z = MFMA16(a1h, bl1, z);                 \
    z = MFMA16(a0l, bh0, z); z = MFMA16(a1l, bh1, z);                 \
  }

// ---- attention Z: zp[s][h2][q] = sum over k-segment s of exp|a| (s = 0..3) ----
// K tiles COOPERATIVELY staged in dbuf LDS (dedup across 4 waves).
__global__ __launch_bounds__(256) void attn_z_kernel(
    const u16* __restrict__ qhi, const u16* __restrict__ khi,
    float* __restrict__ zp) {
  __shared__ u16 Kh[2][64][72];

  const int bid = blockIdx.x;
  const int c = 7 - (bid >> 9);                 // heavy-first
  const int r = bid & 511;
  const int h2 = r & 31;
  const int qtIdx = (r >> 5) & 3;
  const int s = r >> 7;                         // 0..3
  const int qt = qtIdx * 8 + c;
  const int qb = qt * 64;
  const int t = threadIdx.x;
  const int lane = t & 63, wv = t >> 6;
  const int rsel = lane & 15, grp = lane >> 4, ksel = 8 * grp;
  const int qrow = qb + wv * 16;

  const size_t qoff = ((size_t)h2 * LQ + qrow + rsel) * 64 + ksel;
  bf16x8 aq0h = *(const bf16x8*)(qhi + qoff), aq1h = *(const bf16x8*)(qhi + qoff + 32);
  const u16* kh = khi + (size_t)h2 * LQ * 64;

  const int srow = t >> 2;
  const int scol = (t & 3) * 16;

  int qm[4];
  float Z[4] = {0.f, 0.f, 0.f, 0.f};
#pragma unroll
  for (int j = 0; j < 4; ++j) qm[j] = (qrow + grp * 4 + j) & 511;

  const int kbeg = s * 512;
  int buf = 0;
  for (int jt = 0; jt <= c; ++jt) {             // computed tiles only
    const int kt = kbeg + jt * 64;
    const size_t kb = (size_t)(kt + srow) * 64 + scol;
    uint4 r0 = *(const uint4*)(kh + kb);
    uint4 r1 = *(const uint4*)(kh + kb + 8);
    *(uint4*)&Kh[buf][srow][scol] = r0;
    *(uint4*)&Kh[buf][srow][scol + 8] = r1;
    __syncthreads();   // K tile ready (dbuf protects against next-tile WAR)
#pragma unroll
    for (int fk = 0; fk < 4; ++fk) {
      const int krow = fk * 16 + rsel;
      const int k = kt + krow;
      bf16x8 b0 = *(const bf16x8*)&Kh[buf][krow][ksel];
      bf16x8 b1 = *(const bf16x8*)&Kh[buf][krow][ksel + 32];
      f32x4 z = {};
      z = MFMA16(aq0h, b0, z);
      z = MFMA16(aq1h, b1, z);
#pragma unroll
      for (int j = 0; j < 4; ++j)
        if ((k & 511) <= qm[j]) Z[j] += __expf(fabsf(z[j] * SCALING));
    }
    buf ^= 1;
  }
#pragma unroll
  for (int j = 0; j < 4; ++j) {
#pragma unroll
    for (int off = 1; off < 16; off <<= 1) Z[j] += __shfl_xor(Z[j], off);
    if (rsel == 0) {
      int q = qrow + grp * 4 + j;
      zp[((size_t)(s * 32 + h2) << 11) + q] = Z[j];
    }
  }
}

// ---- attention PV: 1D grid 2048 heavy-first, one 512-segment per block ----
// K AND V tiles COOPERATIVELY staged in LDS (dedup across waves), with
// ASYNC-STAGE SPLIT: tile jt+1's global loads issue right after tile jt's
// K-ready barrier, hiding L2/L3 latency under the 56-MFMA compute phase.
__global__ __launch_bounds__(256) void attn_pv_kernel(
    const u16* __restrict__ qhi, const u16* __restrict__ qlo,
    const u16* __restrict__ khi, const u16* __restrict__ klo,
    const u16* __restrict__ vt, const float* __restrict__ zp,
    const float* __restrict__ lamp,
    float* __restrict__ O0, float* __restrict__ O123, float* __restrict__ colsum) {
  __shared__ u16 KhA[64][72], KlA[64][72], KhB[64][72], KlB[64][72];
  __shared__ u16 Vs[64][72];
  __shared__ u16 pcLDS[4][16][72];
  __shared__ float csLDS[2][4][64];

  const int bid = blockIdx.x;
  const int c = 7 - (bid >> 8);                 // heavy-first
  const int r = bid & 255;
  const int h = r & 15;
  const int qtIdx = (r >> 4) & 3;
  const int s = r >> 6;                         // 0..3
  const int qt = qtIdx * 8 + c;
  const int qb = qt * 64;
  const int t = threadIdx.x;
  const int lane = t & 63, wv = t >> 6;
  const int rsel = lane & 15, grp = lane >> 4, ksel = 8 * grp;
  const int qrow = qb + wv * 16;
  const float lam = lamp[0];

  const int h2a = 2 * h, h2b = 2 * h + 1;
  const size_t qoffa = ((size_t)h2a * LQ + qrow + rsel) * 64 + ksel;
  const size_t qoffb = ((size_t)h2b * LQ + qrow + rsel) * 64 + ksel;
  bf16x8 aqa0h = *(const bf16x8*)(qhi + qoffa), aqa1h = *(const bf16x8*)(qhi + qoffa + 32);
  bf16x8 aqa0l = *(const bf16x8*)(qlo + qoffa), aqa1l = *(const bf16x8*)(qlo + qoffa + 32);
  bf16x8 aqb0h = *(const bf16x8*)(qhi + qoffb), aqb1h = *(const bf16x8*)(qhi + qoffb + 32);
  bf16x8 aqb0l = *(const bf16x8*)(qlo + qoffb), aqb1l = *(const bf16x8*)(qlo + qoffb + 32);
  const u16* kha = khi + (size_t)h2a * LQ * 64;
  const u16* kla = klo + (size_t)h2a * LQ * 64;
  const u16* khb = khi + (size_t)h2b * LQ * 64;
  const u16* klb = klo + (size_t)h2b * LQ * 64;
  const u16* vb = vt + (size_t)h * 64 * LQ;

  // cooperative staging coords: thread t covers row t>>2, 16 cols at (t&3)*16
  const int srow = t >> 2;
  const int scol = (t & 3) * 16;

  int qm[4];
  float iz1[4], iz2[4];
#pragma unroll
  for (int j = 0; j < 4; ++j) {
    int q = qrow + grp * 4 + j;
    qm[j] = q & 511;
    float z1 = 0.f, z2 = 0.f;
#pragma unroll
    for (int ss = 0; ss < 4; ++ss) {
      z1 += zp[((size_t)(ss * 32 + h2a) << 11) + q];
      z2 += zp[((size_t)(ss * 32 + h2b) << 11) + q];
    }
    iz1[j] = 1.f / z1;
    iz2[j] = 1.f / z2;
  }

  f32x4 accO[4] = {};
  const int kbeg = s * 512;
  int buf = 0;

  // zero colsum for skipped (fully-masked) tiles of this segment
  for (int jt = c + 1; jt < 8; ++jt) {
    if (t < 64) colsum[((size_t)h * 32 + qt) * LQ + kbeg + jt * 64 + t] = 0.f;
  }

  // prologue: load tile 0 into registers
  uint4 rha0, rha1, rla0, rla1, rhb0, rhb1, rlb0, rlb1, rv0, rv1;
  {
    const size_t kb = (size_t)(kbeg + srow) * 64 + scol;
    rha0 = *(const uint4*)(kha + kb);
    rha1 = *(const uint4*)(kha + kb + 8);
    rla0 = *(const uint4*)(kla + kb);
    rla1 = *(const uint4*)(kla + kb + 8);
    rhb0 = *(const uint4*)(khb + kb);
    rhb1 = *(const uint4*)(khb + kb + 8);
    rlb0 = *(const uint4*)(klb + kb);
    rlb1 = *(const uint4*)(klb + kb + 8);
    const u16* vsrc = vb + (size_t)srow * LQ + kbeg + scol;
    rv0 = *(const uint4*)(vsrc);
    rv1 = *(const uint4*)(vsrc + 8);
  }

  for (int jt = 0; jt <= c; ++jt) {
    const int kt = kbeg + jt * 64;

    // write prefetched tile to LDS
    // (prev tile's K/V-LDS reads are fenced by the csLDS barrier of tile jt-1)
    *(uint4*)&KhA[srow][scol] = rha0; *(uint4*)&KhA[srow][scol + 8] = rha1;
    *(uint4*)&KlA[srow][scol] = rla0; *(uint4*)&KlA[srow][scol + 8] = rla1;
    *(uint4*)&KhB[srow][scol] = rhb0; *(uint4*)&KhB[srow][scol + 8] = rhb1;
    *(uint4*)&KlB[srow][scol] = rlb0; *(uint4*)&KlB[srow][scol + 8] = rlb1;
    *(uint4*)&Vs[srow][scol] = rv0;  *(uint4*)&Vs[srow][scol + 8] = rv1;
    __syncthreads();   // K/V tile ready

    // ---- issue NEXT tile's global loads (latency hides under compute) ----
    if (jt < c) {
      const size_t kb = (size_t)(kt + 64 + srow) * 64 + scol;
      rha0 = *(const uint4*)(kha + kb);
      rha1 = *(const uint4*)(kha + kb + 8);
      rla0 = *(const uint4*)(kla + kb);
      rla1 = *(const uint4*)(kla + kb + 8);
      rhb0 = *(const uint4*)(khb + kb);
      rhb1 = *(const uint4*)(khb + kb + 8);
      rlb0 = *(const uint4*)(klb + kb);
      rlb1 = *(const uint4*)(klb + kb + 8);
      const u16* vsrc = vb + (size_t)srow * LQ + kt + 64 + scol;
      rv0 = *(const uint4*)(vsrc);
      rv1 = *(const uint4*)(vsrc + 8);
    }

    __builtin_amdgcn_s_setprio(1);
    float pc[4][4], cs[4];
#pragma unroll
    for (int fk = 0; fk < 4; ++fk) {
      const int krow = fk * 16 + rsel;
      const int k = kt + krow;
      f32x4 z = {};
      SCORE6(z, aqa0h, aqa1h, aqa0l, aqa1l, &KhA[krow][ksel], &KlA[krow][ksel]);
      f32x4 w = {};
      SCORE6(w, aqb0h, aqb1h, aqb0l, aqb1l, &KhB[krow][ksel], &KlB[krow][ksel]);
      float csj = 0.f;
#pragma unroll
      for (int j = 0; j < 4; ++j) {
        bool msk = ((k & 511) > qm[j]);
        float sa = z[j] * SCALING;
        float pa = __builtin_copysignf(__expf(fabsf(sa)) * iz1[j], sa);
        pa = msk ? 0.f : pa;
        csj += pa;
        float sb = w[j] * SCALING;
        float pb = __builtin_copysignf(__expf(fabsf(sb)) * iz2[j], sb);
        pc[fk][j] = pa - (msk ? 0.f : lam * pb);
      }
      cs[fk] = csj;
    }
    // pc relayout through OWN pcLDS slice (intra-wave, lgkmcnt-ordered)
#pragma unroll
    for (int fk = 0; fk < 4; ++fk)
#pragma unroll
      for (int j = 0; j < 4; ++j)
        pcLDS[wv][grp * 4 + j][fk * 16 + rsel] = f2b(pc[fk][j]);
    // PV (intra-wave; V read from LDS)
#pragma unroll
    for (int kc = 0; kc < 2; ++kc) {
      bf16x8 ap = *(const bf16x8*)&pcLDS[wv][rsel][kc * 32 + ksel];
#pragma unroll
      for (int fn = 0; fn < 4; ++fn) {
        bf16x8 bv = *(const bf16x8*)&Vs[fn * 16 + rsel][kc * 32 + ksel];
        accO[fn] = MFMA16(ap, bv, accO[fn]);
      }
    }
    __builtin_amdgcn_s_setprio(0);
    // cross-wave colsum (csLDS dbuf + barrier; barrier also fences K/V reads
    // of this tile before next tile's ds_writes)
#pragma unroll
    for (int fk = 0; fk < 4; ++fk) {
      float cc = cs[fk];
      cc += __shfl_xor(cc, 16);
      cc += __shfl_xor(cc, 32);
      if (grp == 0) csLDS[buf][wv][fk * 16 + rsel] = cc;
    }
    __syncthreads();
    if (t < 64) {
      float tot = csLDS[buf][0][t] + csLDS[buf][1][t] + csLDS[buf][2][t] + csLDS[buf][3][t];
      colsum[((size_t)h * 32 + qt) * LQ + kt + t] = tot;
    }
    buf ^= 1;
  }
  float* Op = (s == 0) ? O0 : (O123 + (size_t)(s - 1) * 16 * LQ * 64);
#pragma unroll
  for (int fn = 0; fn < 4; ++fn)
#pragma unroll
    for (int j = 0; j < 4; ++j) {
      int q = qrow + grp * 4 + j;
      int d = fn * 16 + rsel;
      Op[((size_t)h * LQ + q) * 64 + d] = accO[fn][j];
    }
}

// g[h][k] = sum_qt colsum[h][qt][k] / 2048
__global__ void g_reduce_kernel(const float* __restrict__ colsum, float* __restrict__ g) {
  int idx = blockIdx.x * 256 + threadIdx.x;
  if (idx >= 16 * LQ) return;
  int h = idx >> 11, k = idx & 2047;
  float s = 0.f;
#pragma unroll
  for (int qt = 0; qt < 32; ++qt) s += colsum[((size_t)h * 32 + qt) * LQ + k];
  g[idx] = s * (1.f / 2048.f);
}

// Gv[h][r][d] = sum_seg g[h][seg*512+r] * vt[h][d][seg*512+r]
__global__ void gv_kernel(const float* __restrict__ g, const u16* __restrict__ vt,
                          float* __restrict__ Gv) {
  int idx = blockIdx.x * 256 + threadIdx.x;
  if (idx >= 16 * 512 * 64) return;
  int d = idx & 63, r = (idx >> 6) & 511, h = idx >> 15;
  float s = 0.f;
#pragma unroll
  for (int seg = 0; seg < 4; ++seg) {
    int k = seg * 512 + r;
    s += g[h * 2048 + k] * b2f(vt[((size_t)h * 64 + d) * LQ + k]);
  }
  Gv[idx] = s;
}

// W[h][r][d] = inclusive prefix over r of Gv[h][r][d]
__global__ __launch_bounds__(512) void wscan_kernel(const float* __restrict__ Gv,
                                                    float* __restrict__ W) {
  __shared__ float s[512];
  int h = blockIdx.x >> 6, d = blockIdx.x & 63;
  int t = threadIdx.x;
  s[t] = Gv[((size_t)h * 512 + t) * 64 + d];
  __syncthreads();
  for (int off = 1; off < 512; off <<= 1) {
    float add = (t >= off) ? s[t - off] : 0.f;
    __syncthreads();
    s[t] += add;
    __syncthreads();
  }
  W[((size_t)h * 512 + t) * 64 + d] = s[t];
}

// out_pre = O0 + O1 + O2 + O3 + lam*W[q%512]; head rmsnorm -> bf16 [q][h*64+d]
__global__ __launch_bounds__(256) void combine_norm_kernel(
    const float* __restrict__ O0, const float* __restrict__ O123,
    const float* __restrict__ W, const float* __restrict__ hw,
    const float* __restrict__ lamp, u16* __restrict__ out) {
  const int q = blockIdx.x;
  const int h = blockIdx.y * 4 + (threadIdx.x >> 6);
  const int d = threadIdx.x & 63;
  const float lam = lamp[0];
  const size_t S = (size_t)16 * LQ * 64;
  const size_t idx = ((size_t)h * LQ + q) * 64 + d;
  float v = O0[idx] + O123[idx] + O123[idx + S] + O123[idx + 2 * S] +
            lam * W[((size_t)h * 512 + (q & 511)) * 64 + d];
  float ss = v * v;
#pragma unroll
  for (int off = 1; off < 64; off <<= 1) ss += __shfl_xor(ss, off);
  float sc = 1.f / sqrtf(ss * (1.f / 64.f) + 1e-5f);
  out[(size_t)q * 1024 + h * 64 + d] = f2b(v * sc * hw[d]);
}

// ============================== launch ==============================
extern "C" void kernel_launch(void* const* d_in, const int* in_sizes, int n_in,
                              void* d_out, int out_size, void* d_ws, size_t ws_size,
                              hipStream_t stream) {
  const float* x = (const float*)d_in[0];
  const float* freqs_r = (const float*)d_in[1];
  const float* freqs_i = (const float*)d_in[2];
  // d_in[3] = mask (recomputed analytically)
  const float* kv_down_w = (const float*)d_in[4];
  const float* q_down_w = (const float*)d_in[5];
  const float* kv_up_w = (const float*)d_in[6];
  const float* q_up_w = (const float*)d_in[7];
  const float* kv_norm_w = (const float*)d_in[8];
  const float* q_norm_w = (const float*)d_in[9];
  const float* o_w = (const float*)d_in[10];
  const float* lambda_q1 = (const float*)d_in[11];
  const float* lambda_k1 = (const float*)d_in[12];
  const float* lambda_q2 = (const float*)d_in[13];
  const float* lambda_k2 = (const float*)d_in[14];
  const float* head_norm_w = (const float*)d_in[15];
  const float* norm1_w = (const float*)d_in[16];
  const float* norm2_w = (const float*)d_in[17];
  const float* ff_in_w = (const float*)d_in[18];
  const float* ff_out_w = (const float*)d_in[19];
  float* out = (float*)d_out;
  char* ws = (char*)d_ws;

  // ---- weights region (persistent except down/up: dead after projections) ----
  const size_t WT_KVD_H = 0;                                  // 544x1024 bf16
  const size_t WT_KVD_L = WT_KVD_H + (size_t)544 * 1024 * 2;
  const size_t WT_QD_H  = WT_KVD_L + (size_t)544 * 1024 * 2;  // 512x1024
  const size_t WT_QD_L  = WT_QD_H + (size_t)512 * 1024 * 2;
  const size_t WT_KVU_H = WT_QD_L + (size_t)512 * 1024 * 2;   // 2048x512
  const size_t WT_KVU_L = WT_KVU_H + (size_t)2048 * 512 * 2;
  const size_t WT_QU_H  = WT_KVU_L + (size_t)2048 * 512 * 2;  // 1536x512
  const size_t WT_QU_L  = WT_QU_H + (size_t)1536 * 512 * 2;
  const size_t WT_OW    = WT_QU_L + (size_t)1536 * 512 * 2;   // = 11,714,560
  const size_t WT_FFI   = WT_OW + (size_t)1024 * 1024 * 2;
  const size_t WT_FFO   = WT_FFI + (size_t)8192 * 1024 * 2;
  const size_t A0 = WT_FFO + (size_t)1024 * 4096 * 2;         // = 38,928,384

  // ---- activations (lifetime-aliased) ----
  const size_t H     = A0;                  // h hi/lo bf16 (2x 4,194,304); dead after down-GEMMs
  const size_t CKV   = A0 + 8388608;        // f32 2048x544;  dead after build_kh
  const size_t CKVN  = A0 + 12845056;       // ckvn hi/lo bf16 (2x 2,097,152); dead after kv_up
  const size_t KVB   = A0 + 17039360;       // f32 2048x2048; dead after build_vt
  const size_t CQ    = A0 + 33816576;       // f32 2048x512;  dead after rmsnorm
  const size_t CQN   = A0 + 38010880;       // cqn hi/lo bf16 (2x 2,097,152); dead after q_up
  const size_t QFULL = A0 + 42205184;       // f32 2048x1536; dead after build_qh
  // mid buffers (aliases):
  const size_t QHI = H;                     // bf16 32x2048x64 over dead H
  const size_t KHI = QFULL;                 // bf16 32x2048x64 over dead QFULL[0:8.39M]
  const size_t KLO = A0 + 50593792;         // bf16 32x2048x64 over dead QFULL[8.39M:]+
  const size_t QLO = A0 + 58982400;         // bf16 32x2048x64
  const size_t VT  = CKVN;                  // bf16 16x64x2048 over dead CKVN
  // O partials (4 x 8,388,608 f32):
  const size_t OP0   = 0;                   // over dead down/up weights [0, 8.39M) < WT_OW
  const size_t OP123 = KVB;                 // 3 contiguous partials over dead KVB+CQ+CQN
  const size_t CS  = CKV;                   // f32 16x32x2048 over dead CKV
  const size_t GB  = A0 + 67371008;         // f32 16x2048 (131,072)
  const size_t GV  = A0 + 67502080;         // f32 16x512x64 (2,097,152)
  const size_t WB  = A0 + 69599232;         // f32 16x512x64 (2,097,152)
  const size_t LAM = A0 + 71696384;         // scalar
  const size_t ZP  = A0 + 71696640;         // f32 4x32x2048 (1,048,576)
  const size_t WS_END = A0 + 72745216;      // ~111.7 MB (known-safe)
  // late aliases:
  const size_t ATTN  = CKV;                 // bf16 2048x1024 (over consumed CS)
  const size_t X1    = KVB + 8388608;       // f32 2048x1024 (partials consumed by combine)
  const size_t H2N   = H;                   // bf16 2048x1024 over dead QHI
  const size_t FFACT = QFULL;               // bf16 2048x4096 over dead KHI+KLO

  if (ws_size < WS_END) return;

  u16* wt_kvd_h = (u16*)(ws + WT_KVD_H); u16* wt_kvd_l = (u16*)(ws + WT_KVD_L);
  u16* wt_qd_h  = (u16*)(ws + WT_QD_H);  u16* wt_qd_l  = (u16*)(ws + WT_QD_L);
  u16* wt_kvu_h = (u16*)(ws + WT_KVU_H); u16* wt_kvu_l = (u16*)(ws + WT_KVU_L);
  u16* wt_qu_h  = (u16*)(ws + WT_QU_H);  u16* wt_qu_l  = (u16*)(ws + WT_QU_L);
  u16* wt_ow  = (u16*)(ws + WT_OW);
  u16* wt_ffi = (u16*)(ws + WT_FFI);
  u16* wt_ffo = (u16*)(ws + WT_FFO);
  u16* h_hi   = (u16*)(ws + H);
  u16* h_lo   = (u16*)(ws + H + 4194304);
  float* ckv  = (float*)(ws + CKV);
  u16* ckvn_hi = (u16*)(ws + CKVN);
  u16* ckvn_lo = (u16*)(ws + CKVN + 2097152);
  float* kvb  = (float*)(ws + KVB);
  float* cq   = (float*)(ws + CQ);
  u16* cqn_hi = (u16*)(ws + CQN);
  u16* cqn_lo = (u16*)(ws + CQN + 2097152);
  float* qfull = (float*)(ws + QFULL);
  u16* qhib = (u16*)(ws + QHI); u16* qlob = (u16*)(ws + QLO);
  u16* khib = (u16*)(ws + KHI); u16* klob = (u16*)(ws + KLO);
  u16* vtb  = (u16*)(ws + VT);
  float* zpb = (float*)(ws + ZP);
  float* Op0 = (float*)(ws + OP0);
  float* Op123 = (float*)(ws + OP123);
  float* csb = (float*)(ws + CS);
  float* gb  = (float*)(ws + GB);
  float* gvb = (float*)(ws + GV);
  float* wbb = (float*)(ws + WB);
  float* lamp = (float*)(ws + LAM);
  u16* attn_n = (u16*)(ws + ATTN);
  float* x1 = (float*)(ws + X1);
  u16* h2n = (u16*)(ws + H2N);
  u16* ffact = (u16*)(ws + FFACT);

  dim3 tb(32, 8);
  transpose_split<<<dim3(17, 32), tb, 0, stream>>>(kv_down_w, wt_kvd_h, wt_kvd_l, 1024, 544);
  transpose_split<<<dim3(16, 32), tb, 0, stream>>>(q_down_w, wt_qd_h, wt_qd_l, 1024, 512);
  transpose_split<<<dim3(64, 16), tb, 0, stream>>>(kv_up_w, wt_kvu_h, wt_kvu_l, 512, 2048);
  transpose_split<<<dim3(48, 16), tb, 0, stream>>>(q_up_w, wt_qu_h, wt_qu_l, 512, 1536);
  transpose_to_bf16<<<dim3(32, 32), tb, 0, stream>>>(o_w, wt_ow, 1024, 1024);
  transpose_to_bf16<<<dim3(256, 32), tb, 0, stream>>>(ff_in_w, wt_ffi, 1024, 8192);
  transpose_to_bf16<<<dim3(32, 128), tb, 0, stream>>>(ff_out_w, wt_ffo, 4096, 1024);

  rmsnorm_split_kernel<<<2048, 256, 0, stream>>>(x, norm1_w, h_hi, h_lo, 1024, 1024, FEPS);
  gemm_split<<<dim3(9, 32), 256, 0, stream>>>(h_hi, h_lo, wt_kvd_h, wt_kvd_l, ckv,
                                              2048, 544, 1024);
  rmsnorm_split_kernel<<<2048, 256, 0, stream>>>(ckv, kv_norm_w, ckvn_hi, ckvn_lo,
                                                 512, 544, FEPS);
  gemm_split<<<dim3(32, 32), 256, 0, stream>>>(ckvn_hi, ckvn_lo, wt_kvu_h, wt_kvu_l, kvb,
                                               2048, 2048, 512);
  gemm_split<<<dim3(8, 32), 256, 0, stream>>>(h_hi, h_lo, wt_qd_h, wt_qd_l, cq,
                                              2048, 512, 1024);
  rmsnorm_split_kernel<<<2048, 256, 0, stream>>>(cq, q_norm_w, cqn_hi, cqn_lo,
                                                 512, 512, FEPS);
  gemm_split<<<dim3(24, 32), 256, 0, stream>>>(cqn_hi, cqn_lo, wt_qu_h, wt_qu_l, qfull,
                                               2048, 1536, 512);

  build_qh_kernel<<<dim3(2048, 8), 256, 0, stream>>>(qfull, freqs_r, freqs_i, qhib, qlob);
  build_kh_kernel<<<dim3(2048, 8), 256, 0, stream>>>(kvb, ckv, freqs_r, freqs_i, khib, klob);
  build_vt_kernel<<<dim3(32, 16), 256, 0, stream>>>(kvb, vtb);

  lam_kernel<<<1, 32, 0, stream>>>(lambda_q1, lambda_k1, lambda_q2, lambda_k2, lamp);
  attn_z_kernel<<<4096, 256, 0, stream>>>(qhib, khib, zpb);
  attn_pv_kernel<<<2048, 256, 0, stream>>>(qhib, qlob, khib, klob, vtb, zpb,
                                           lamp, Op0, Op123, csb);

  g_reduce_kernel<<<128, 256, 0, stream>>>(csb, gb);
  gv_kernel<<<2048, 256, 0, stream>>>(gb, vtb, gvb);
  wscan_kernel<<<1024, 512, 0, stream>>>(gvb, wbb);
  combine_norm_kernel<<<dim3(2048, 4), 256, 0, stream>>>(Op0, Op123, wbb, head_norm_w,
                                                         lamp, attn_n);

  // x1 = x + attn_n @ o_w  (residual fused into epilogue)
  gemm_kernel<0, 1><<<dim3(16, 32), 256, 0, stream>>>(attn_n, wt_ow, x, x1, nullptr,
                                                      2048, 1024, 1024);
  rmsnorm_kernel<1><<<2048, 256, 0, stream>>>(x1, norm2_w, h2n, 1024, 1024, FEPS);
  gemm_kernel<1, 0><<<dim3(64, 32), 256, 0, stream>>>(h2n, wt_ffi, nullptr, nullptr, ffact,
                                                      2048, 4096, 1024);
  // out = x1 + ffact @ ff_out  (residual fused into epilogue)
  gemm_kernel<0, 1><<<dim3(16, 32), 256, 0, stream>>>(ffact, wt_ffo, x1, out, nullptr,
                                                      2048, 1024, 4096);
}

// Round 23
// 391.213 us; speedup vs baseline: 1.0407x; 1.0025x over previous
//
#include <hip/hip_runtime.h>
#include <math.h>

#define LQ 2048
#define SCALING 0.14433756729740643f   // 48^-0.5
#define FEPS 1.1920928955078125e-07f   // np.finfo(float32).eps

typedef unsigned short u16;
typedef __attribute__((ext_vector_type(8))) short bf16x8;
typedef __attribute__((ext_vector_type(4))) float f32x4;

#define MFMA16(a, b, c) __builtin_amdgcn_mfma_f32_16x16x32_bf16((a), (b), (c), 0, 0, 0)

__device__ __forceinline__ u16 f2b(float x) {
  union { float f; unsigned u; } v; v.f = x;
  return (u16)((v.u + 0x7FFFu + ((v.u >> 16) & 1u)) >> 16);
}
__device__ __forceinline__ float b2f(u16 b) {
  union { unsigned u; float f; } v; v.u = ((unsigned)b) << 16;
  return v.f;
}

// ---------------- weight fp32 [K][N] -> bf16 [N][K] (single) ----------------
__global__ void transpose_to_bf16(const float* __restrict__ W, u16* __restrict__ Wt,
                                  int K, int N) {
  __shared__ float tile[32][33];
  int n0 = blockIdx.x * 32, k0 = blockIdx.y * 32;
  int tx = threadIdx.x, ty = threadIdx.y;  // 32 x 8
  for (int i = ty; i < 32; i += 8) {
    int k = k0 + i, n = n0 + tx;
    tile[i][tx] = (k < K && n < N) ? W[(size_t)k * N + n] : 0.f;
  }
  __syncthreads();
  for (int i = ty; i < 32; i += 8) {
    int n = n0 + i, k = k0 + tx;
    if (n < N && k < K) Wt[(size_t)n * K + k] = f2b(tile[tx][i]);
  }
}

// ---------------- weight fp32 [K][N] -> hi/lo bf16 [N][K] ----------------
__global__ void transpose_split(const float* __restrict__ W, u16* __restrict__ Whi,
                                u16* __restrict__ Wlo, int K, int N) {
  __shared__ float tile[32][33];
  int n0 = blockIdx.x * 32, k0 = blockIdx.y * 32;
  int tx = threadIdx.x, ty = threadIdx.y;  // 32 x 8
  for (int i = ty; i < 32; i += 8) {
    int k = k0 + i, n = n0 + tx;
    tile[i][tx] = (k < K && n < N) ? W[(size_t)k * N + n] : 0.f;
  }
  __syncthreads();
  for (int i = ty; i < 32; i += 8) {
    int n = n0 + i, k = k0 + tx;
    if (n < N && k < K) {
      float x = tile[tx][i];
      u16 hi = f2b(x);
      float lo = x - b2f(hi);
      Whi[(size_t)n * K + k] = hi;
      Wlo[(size_t)n * K + k] = f2b(lo);
    }
  }
}

// ---------------- rmsnorm fp32 in (strided) -> fp32 or bf16 out ----------------
template <int BF16OUT>
__global__ __launch_bounds__(256) void rmsnorm_kernel(
    const float* __restrict__ x, const float* __restrict__ w, void* __restrict__ outv,
    int cols, int in_stride, float eps) {
  const int row = blockIdx.x;
  const float* xr = x + (size_t)row * in_stride;
  float ss = 0.f;
  for (int c = threadIdx.x; c < cols; c += 256) { float v = xr[c]; ss = fmaf(v, v, ss); }
#pragma unroll
  for (int off = 32; off > 0; off >>= 1) ss += __shfl_xor(ss, off);
  __shared__ float red[4];
  if ((threadIdx.x & 63) == 0) red[threadIdx.x >> 6] = ss;
  __syncthreads();
  float tot = red[0] + red[1] + red[2] + red[3];
  float sc = 1.f / sqrtf(tot / (float)cols + eps);
  for (int c = threadIdx.x; c < cols; c += 256) {
    float v = xr[c] * sc * w[c];
    if (BF16OUT) ((u16*)outv)[(size_t)row * cols + c] = f2b(v);
    else ((float*)outv)[(size_t)row * cols + c] = v;
  }
}

// ---- rmsnorm fp32 in (strided) -> hi/lo bf16 out (split once, reused by gemm) ----
__global__ __launch_bounds__(256) void rmsnorm_split_kernel(
    const float* __restrict__ x, const float* __restrict__ w,
    u16* __restrict__ hi_out, u16* __restrict__ lo_out,
    int cols, int in_stride, float eps) {
  const int row = blockIdx.x;
  const float* xr = x + (size_t)row * in_stride;
  float ss = 0.f;
  for (int c = threadIdx.x; c < cols; c += 256) { float v = xr[c]; ss = fmaf(v, v, ss); }
#pragma unroll
  for (int off = 32; off > 0; off >>= 1) ss += __shfl_xor(ss, off);
  __shared__ float red[4];
  if ((threadIdx.x & 63) == 0) red[threadIdx.x >> 6] = ss;
  __syncthreads();
  float tot = red[0] + red[1] + red[2] + red[3];
  float sc = 1.f / sqrtf(tot / (float)cols + eps);
  for (int c = threadIdx.x; c < cols; c += 256) {
    float v = xr[c] * sc * w[c];
    u16 hi = f2b(v);
    hi_out[(size_t)row * cols + c] = hi;
    lo_out[(size_t)row * cols + c] = f2b(v - b2f(hi));
  }
}

// ---- split-precision GEMM (3-term), all-bf16 staging ----
__global__ __launch_bounds__(256) void gemm_split(
    const u16* __restrict__ Ahi, const u16* __restrict__ Alo,
    const u16* __restrict__ Bhi, const u16* __restrict__ Blo,
    float* __restrict__ C, int M, int N, int K) {
  __shared__ u16 Ah[64][72];
  __shared__ u16 Al[64][72];
  __shared__ u16 Bh[64][72];
  __shared__ u16 Bl[64][72];

  const int t = threadIdx.x;
  const int lane = t & 63;
  const int wv = t >> 6;
  const int wr = (wv >> 1) * 32;
  const int wc = (wv & 1) * 32;
  const int bm = blockIdx.y * 64;
  const int bn = blockIdx.x * 64;
  const int lr = t >> 2;
  const int lc = (t & 3) * 16;
  const int rsel = lane & 15;
  const int ksel = 8 * (lane >> 4);

  const u16* Ahrow = Ahi + (size_t)(bm + lr) * K + lc;
  const u16* Alrow = Alo + (size_t)(bm + lr) * K + lc;
  const bool bval = (bn + lr) < N;
  const u16* Bhrow = Bhi + (size_t)(bn + lr) * K + lc;
  const u16* Blrow = Blo + (size_t)(bn + lr) * K + lc;

  f32x4 acc[2][2] = {};

  for (int kt = 0; kt < K; kt += 64) {
    uint4 ah0 = *(const uint4*)(Ahrow + kt);
    uint4 ah1 = *(const uint4*)(Ahrow + kt + 8);
    uint4 al0 = *(const uint4*)(Alrow + kt);
    uint4 al1 = *(const uint4*)(Alrow + kt + 8);
    uint4 bh0 = {0, 0, 0, 0}, bh1 = {0, 0, 0, 0}, bl0 = {0, 0, 0, 0}, bl1 = {0, 0, 0, 0};
    if (bval) {
      bh0 = *(const uint4*)(Bhrow + kt); bh1 = *(const uint4*)(Bhrow + kt + 8);
      bl0 = *(const uint4*)(Blrow + kt); bl1 = *(const uint4*)(Blrow + kt + 8);
    }
    __syncthreads();
    *(uint4*)&Ah[lr][lc] = ah0; *(uint4*)&Ah[lr][lc + 8] = ah1;
    *(uint4*)&Al[lr][lc] = al0; *(uint4*)&Al[lr][lc + 8] = al1;
    *(uint4*)&Bh[lr][lc] = bh0; *(uint4*)&Bh[lr][lc + 8] = bh1;
    *(uint4*)&Bl[lr][lc] = bl0; *(uint4*)&Bl[lr][lc + 8] = bl1;
    __syncthreads();
#pragma unroll
    for (int ks = 0; ks < 2; ++ks) {
      const int ko = ks * 32 + ksel;
      bf16x8 a0h = *(const bf16x8*)&Ah[wr + rsel][ko];
      bf16x8 a1h = *(const bf16x8*)&Ah[wr + 16 + rsel][ko];
      bf16x8 a0l = *(const bf16x8*)&Al[wr + rsel][ko];
      bf16x8 a1l = *(const bf16x8*)&Al[wr + 16 + rsel][ko];
      bf16x8 b0h = *(const bf16x8*)&Bh[wc + rsel][ko];
      bf16x8 b1h = *(const bf16x8*)&Bh[wc + 16 + rsel][ko];
      bf16x8 b0l = *(const bf16x8*)&Bl[wc + rsel][ko];
      bf16x8 b1l = *(const bf16x8*)&Bl[wc + 16 + rsel][ko];
      acc[0][0] = MFMA16(a0h, b0h, acc[0][0]);
      acc[0][0] = MFMA16(a0h, b0l, acc[0][0]);
      acc[0][0] = MFMA16(a0l, b0h, acc[0][0]);
      acc[0][1] = MFMA16(a0h, b1h, acc[0][1]);
      acc[0][1] = MFMA16(a0h, b1l, acc[0][1]);
      acc[0][1] = MFMA16(a0l, b1h, acc[0][1]);
      acc[1][0] = MFMA16(a1h, b0h, acc[1][0]);
      acc[1][0] = MFMA16(a1h, b0l, acc[1][0]);
      acc[1][0] = MFMA16(a1l, b0h, acc[1][0]);
      acc[1][1] = MFMA16(a1h, b1h, acc[1][1]);
      acc[1][1] = MFMA16(a1h, b1l, acc[1][1]);
      acc[1][1] = MFMA16(a1l, b1h, acc[1][1]);
    }
  }
  const int r0 = (lane >> 4) * 4;
#pragma unroll
  for (int fm = 0; fm < 2; ++fm)
#pragma unroll
    for (int fn = 0; fn < 2; ++fn)
#pragma unroll
      for (int j = 0; j < 4; ++j) {
        int row = bm + wr + fm * 16 + r0 + j;
        int col = bn + wc + fn * 16 + rsel;
        if (col < N) C[(size_t)row * N + col] = acc[fm][fn][j];
      }
}

// ---- plain bf16 GEMM (o_w / FFN): 64x64 reg-staged. ADDX fuses residual add. ----
template <int GATED, int ADDX>
__global__ __launch_bounds__(256) void gemm_kernel(
    const u16* __restrict__ A, const u16* __restrict__ Bt, const float* __restrict__ X,
    float* __restrict__ C, u16* __restrict__ Cg, int M, int N, int K) {
  __shared__ u16 As[64][72];
  __shared__ u16 Bs[64][72];
  __shared__ u16 Bs2[GATED ? 64 : 1][72];

  const int t = threadIdx.x;
  const int lane = t & 63;
  const int wv = t >> 6;
  const int wr = (wv >> 1) * 32;
  const int wc = (wv & 1) * 32;
  const int bm = blockIdx.y * 64;
  const int bn = blockIdx.x * 64;
  const int lr = t >> 2;
  const int lc = (t & 3) * 16;
  const int rsel = lane & 15;
  const int ksel = 8 * (lane >> 4);

  const u16* Arow = A + (size_t)(bm + lr) * K + lc;
  const u16* Brow = Bt + (size_t)(bn + lr) * K + lc;
  const u16* Brow2 = Bt + (size_t)(4096 + bn + lr) * K + lc;

  f32x4 acc[2][2] = {};
  f32x4 accg[2][2] = {};

  for (int kt = 0; kt < K; kt += 64) {
    uint4 a0 = *(const uint4*)(Arow + kt);
    uint4 a1 = *(const uint4*)(Arow + kt + 8);
    uint4 b0 = *(const uint4*)(Brow + kt);
    uint4 b1 = *(const uint4*)(Brow + kt + 8);
    uint4 c0 = {0, 0, 0, 0}, c1 = {0, 0, 0, 0};
    if (GATED) { c0 = *(const uint4*)(Brow2 + kt); c1 = *(const uint4*)(Brow2 + kt + 8); }
    __syncthreads();
    *(uint4*)&As[lr][lc] = a0; *(uint4*)&As[lr][lc + 8] = a1;
    *(uint4*)&Bs[lr][lc] = b0; *(uint4*)&Bs[lr][lc + 8] = b1;
    if (GATED) { *(uint4*)&Bs2[lr][lc] = c0; *(uint4*)&Bs2[lr][lc + 8] = c1; }
    __syncthreads();
#pragma unroll
    for (int ks = 0; ks < 2; ++ks) {
      const int ko = ks * 32 + ksel;
      bf16x8 af0 = *(const bf16x8*)&As[wr + rsel][ko];
      bf16x8 af1 = *(const bf16x8*)&As[wr + 16 + rsel][ko];
      bf16x8 bf0 = *(const bf16x8*)&Bs[wc + rsel][ko];
      bf16x8 bf1 = *(const bf16x8*)&Bs[wc + 16 + rsel][ko];
      acc[0][0] = MFMA16(af0, bf0, acc[0][0]);
      acc[0][1] = MFMA16(af0, bf1, acc[0][1]);
      acc[1][0] = MFMA16(af1, bf0, acc[1][0]);
      acc[1][1] = MFMA16(af1, bf1, acc[1][1]);
      if (GATED) {
        bf16x8 cf0 = *(const bf16x8*)&Bs2[wc + rsel][ko];
        bf16x8 cf1 = *(const bf16x8*)&Bs2[wc + 16 + rsel][ko];
        accg[0][0] = MFMA16(af0, cf0, accg[0][0]);
        accg[0][1] = MFMA16(af0, cf1, accg[0][1]);
        accg[1][0] = MFMA16(af1, cf0, accg[1][0]);
        accg[1][1] = MFMA16(af1, cf1, accg[1][1]);
      }
    }
  }
  const int r0 = (lane >> 4) * 4;
#pragma unroll
  for (int fm = 0; fm < 2; ++fm)
#pragma unroll
    for (int fn = 0; fn < 2; ++fn)
#pragma unroll
      for (int j = 0; j < 4; ++j) {
        int row = bm + wr + fm * 16 + r0 + j;
        int col = bn + wc + fn * 16 + rsel;
        size_t o = (size_t)row * N + col;
        if (!GATED) {
          float v = acc[fm][fn][j];
          if (ADDX) v += X[o];
          C[o] = v;
        } else {
          float u = acc[fm][fn][j], g = accg[fm][fn][j];
          float sv = g / (1.f + __expf(-g));
          Cg[o] = f2b(u * sv);
        }
      }
}

// ---------------- build qh / kh (RoPE applied, padded 48->64, hi/lo split) ----------------
__global__ void build_qh_kernel(const float* __restrict__ qfull, const float* __restrict__ fr,
                                const float* __restrict__ fi, u16* __restrict__ qhi,
                                u16* __restrict__ qlo) {
  const int q = blockIdx.x;
  const int h2 = blockIdx.y * 4 + (threadIdx.x >> 6);
  const int d = threadIdx.x & 63;
  const int hh = h2 >> 1, s = h2 & 1;
  const float* row = qfull + (size_t)q * 1536 + hh * 96;
  float val;
  if (d < 32) {
    val = row[s * 32 + d];
  } else if (d < 48) {
    int r = d - 32;
    int pos = q & 511;
    const float* rp = row + 64 + s * 16;
    if (pos == 0) val = rp[r];
    else {
      int j = r >> 1;
      float cr = fr[(pos - 1) * 8 + j], ci = fi[(pos - 1) * 8 + j];
      float a = rp[2 * j], b = rp[2 * j + 1];
      val = (r & 1) ? (a * ci + b * cr) : (a * cr - b * ci);
    }
  } else val = 0.f;
  u16 hi = f2b(val);
  qhi[((size_t)h2 * LQ + q) * 64 + d] = hi;
  qlo[((size_t)h2 * LQ + q) * 64 + d] = f2b(val - b2f(hi));
}

__global__ void build_kh_kernel(const float* __restrict__ kv, const float* __restrict__ ckv,
                                const float* __restrict__ fr, const float* __restrict__ fi,
                                u16* __restrict__ khi, u16* __restrict__ klo) {
  const int kp = blockIdx.x;
  const int h2 = blockIdx.y * 4 + (threadIdx.x >> 6);
  const int d = threadIdx.x & 63;
  const int hh = h2 >> 1, s = h2 & 1;
  float val;
  if (d < 32) {
    val = kv[(size_t)kp * 2048 + hh * 128 + s * 32 + d];
  } else if (d < 48) {
    int r = d - 32;
    int pos = kp & 511;
    const float* rp = ckv + (size_t)kp * 544 + 512 + s * 16;
    if (pos == 0) val = rp[r];
    else {
      int j = r >> 1;
      float cr = fr[(pos - 1) * 8 + j], ci = fi[(pos - 1) * 8 + j];
      float a = rp[2 * j], b = rp[2 * j + 1];
      val = (r & 1) ? (a * ci + b * cr) : (a * cr - b * ci);
    }
  } else val = 0.f;
  u16 hi = f2b(val);
  khi[((size_t)h2 * LQ + kp) * 64 + d] = hi;
  klo[((size_t)h2 * LQ + kp) * 64 + d] = f2b(val - b2f(hi));
}

// vt[h][d][k] = bf16(kv[k][h*128+64+d])  (transposed V for PV B-fragments)
__global__ __launch_bounds__(256) void build_vt_kernel(const float* __restrict__ kv,
                                                       u16* __restrict__ vt) {
  __shared__ u16 tile[64][65];
  int h = blockIdx.y, k0 = blockIdx.x * 64;
  int t = threadIdx.x;
  int d = t & 63, kr = t >> 6;
#pragma unroll
  for (int i = 0; i < 16; ++i) {
    int k = kr + i * 4;
    tile[k][d] = f2b(kv[(size_t)(k0 + k) * 2048 + h * 128 + 64 + d]);
  }
  __syncthreads();
  int kk = t & 63, dr = t >> 6;
#pragma unroll
  for (int i = 0; i < 16; ++i) {
    int d2 = dr + i * 4;
    vt[((size_t)h * 64 + d2) * LQ + k0 + kk] = tile[kk][d2];
  }
}

// lam = exp(sum(lk1*lq1)) - exp(sum(lk2*lq2)) + 0.2
__global__ void lam_kernel(const float* lq1, const float* lk1, const float* lq2,
                           const float* lk2, float* lamp) {
  int t = threadIdx.x;  // 32
  float a = lq1[t] * lk1[t], b = lq2[t] * lk2[t];
#pragma unroll
  for (int off = 1; off < 32; off <<= 1) { a += __shfl_xor(a, off); b += __shfl_xor(b, off); }
  if (t == 0) lamp[0] = expf(a) - expf(b) + 0.2f;
}

// 6-MFMA split-precision 16x16 score tile
#define SCORE6(z, a0h, a1h, a0l, a1l, ph, pl)                         \
  {                                                                   \
    bf16x8 bh0 = *(const bf16x8*)(ph), bh1 = *(const bf16x8*)((ph) + 32); \
    bf16x8 bl0 = *(const bf16x8*)(pl), bl1 = *(const bf16x8*)((pl) + 32); \
    z = MFMA16(a0h, bh0, z); z = MFMA16(a1h, bh1, z);                 \
    z = MFMA16(a0h, bl0, z); z = MFMA16(a1h, bl1, z);                 \
    z = MFMA16(a0l, bh0, z); z = MFMA16(a1l, bh1, z);                 \
  }

// ---- attention Z: zp[s][h2][q] = sum over k-segment s of exp|a| (s = 0..3) ----
// K tiles COOPERATIVELY staged in dbuf LDS (dedup across 4 waves).
// XCD-pinned decode: each XCD (bid&7) owns 4 h2 values -> its khi working set
// (~1 MB) stays resident in the 4 MB per-XCD L2 across the ~18x re-reads.
__global__ __launch_bounds__(256) void attn_z_kernel(
    const u16* __restrict__ qhi, const u16* __restrict__ khi,
    float* __restrict__ zp) {
  __shared__ u16 Kh[2][64][72];

  const int bid = blockIdx.x;
  const int x = bid & 7;                        // XCD (round-robin heuristic)
  const int j2 = bid >> 3;                      // 0..511 within XCD
  const int c = 7 - (j2 >> 6);                  // heavy-first within XCD
  const int combo = j2 & 63;
  const int h2 = 4 * x + (combo & 3);
  const int qtIdx = (combo >> 2) & 3;
  const int s = combo >> 4;                     // 0..3
  const int qt = qtIdx * 8 + c;
  const int qb = qt * 64;
  const int t = threadIdx.x;
  const int lane = t & 63, wv = t >> 6;
  const int rsel = lane & 15, grp = lane >> 4, ksel = 8 * grp;
  const int qrow = qb + wv * 16;

  const size_t qoff = ((size_t)h2 * LQ + qrow + rsel) * 64 + ksel;
  bf16x8 aq0h = *(const bf16x8*)(qhi + qoff), aq1h = *(const bf16x8*)(qhi + qoff + 32);
  const u16* kh = khi + (size_t)h2 * LQ * 64;

  const int srow = t >> 2;
  const int scol = (t & 3) * 16;

  int qm[4];
  float Z[4] = {0.f, 0.f, 0.f, 0.f};
#pragma unroll
  for (int j = 0; j < 4; ++j) qm[j] = (qrow + grp * 4 + j) & 511;

  const int kbeg = s * 512;
  int buf = 0;
  for (int jt = 0; jt <= c; ++jt) {             // computed tiles only
    const int kt = kbeg + jt * 64;
    const size_t kb = (size_t)(kt + srow) * 64 + scol;
    uint4 r0 = *(const uint4*)(kh + kb);
    uint4 r1 = *(const uint4*)(kh + kb + 8);
    *(uint4*)&Kh[buf][srow][scol] = r0;
    *(uint4*)&Kh[buf][srow][scol + 8] = r1;
    __syncthreads();   // K tile ready (dbuf protects against next-tile WAR)
#pragma unroll
    for (int fk = 0; fk < 4; ++fk) {
      const int krow = fk * 16 + rsel;
      const int k = kt + krow;
      bf16x8 b0 = *(const bf16x8*)&Kh[buf][krow][ksel];
      bf16x8 b1 = *(const bf16x8*)&Kh[buf][krow][ksel + 32];
      f32x4 z = {};
      z = MFMA16(aq0h, b0, z);
      z = MFMA16(aq1h, b1, z);
#pragma unroll
      for (int j = 0; j < 4; ++j)
        if ((k & 511) <= qm[j]) Z[j] += __expf(fabsf(z[j] * SCALING));
    }
    buf ^= 1;
  }
#pragma unroll
  for (int j = 0; j < 4; ++j) {
#pragma unroll
    for (int off = 1; off < 16; off <<= 1) Z[j] += __shfl_xor(Z[j], off);
    if (rsel == 0) {
      int q = qrow + grp * 4 + j;
      zp[((size_t)(s * 32 + h2) << 11) + q] = Z[j];
    }
  }
}

// ---- attention PV: 1D grid 2048, one 512-segment per block ----
// K AND V tiles COOPERATIVELY staged in LDS (dedup across waves), async-stage
// split (next tile's loads issue under compute). XCD-pinned decode: each XCD
// owns 2 heads -> K hi/lo (4 h2) + vt (~2.5 MB) stay L2-resident across the
// ~18x re-reads (4 qtIdx x 8 c-levels per segment).
__global__ __launch_bounds__(256) void attn_pv_kernel(
    const u16* __restrict__ qhi, const u16* __restrict__ qlo,
    const u16* __restrict__ khi, const u16* __restrict__ klo,
    const u16* __restrict__ vt, const float* __restrict__ zp,
    const float* __restrict__ lamp,
    float* __restrict__ O0, float* __restrict__ O123, float* __restrict__ colsum) {
  __shared__ u16 KhA[64][72], KlA[64][72], KhB[64][72], KlB[64][72];
  __shared__ u16 Vs[64][72];
  __shared__ u16 pcLDS[4][16][72];
  __shared__ float csLDS[2][4][64];

  const int bid = blockIdx.x;
  const int x = bid & 7;                        // XCD (round-robin heuristic)
  const int j2 = bid >> 3;                      // 0..255 within XCD
  const int c = 7 - (j2 >> 5);                  // heavy-first within XCD
  const int combo = j2 & 31;
  const int h = 2 * x + (combo & 1);
  const int qtIdx = (combo >> 1) & 3;
  const int s = combo >> 3;                     // 0..3
  const int qt = qtIdx * 8 + c;
  const int qb = qt * 64;
  const int t = threadIdx.x;
  const int lane = t & 63, wv = t >> 6;
  const int rsel = lane & 15, grp = lane >> 4, ksel = 8 * grp;
  const int qrow = qb + wv * 16;
  const float lam = lamp[0];

  const int h2a = 2 * h, h2b = 2 * h + 1;
  const size_t qoffa = ((size_t)h2a * LQ + qrow + rsel) * 64 + ksel;
  const size_t qoffb = ((size_t)h2b * LQ + qrow + rsel) * 64 + ksel;
  bf16x8 aqa0h = *(const bf16x8*)(qhi + qoffa), aqa1h = *(const bf16x8*)(qhi + qoffa + 32);
  bf16x8 aqa0l = *(const bf16x8*)(qlo + qoffa), aqa1l = *(const bf16x8*)(qlo + qoffa + 32);
  bf16x8 aqb0h = *(const bf16x8*)(qhi + qoffb), aqb1h = *(const bf16x8*)(qhi + qoffb + 32);
  bf16x8 aqb0l = *(const bf16x8*)(qlo + qoffb), aqb1l = *(const bf16x8*)(qlo + qoffb + 32);
  const u16* kha = khi + (size_t)h2a * LQ * 64;
  const u16* kla = klo + (size_t)h2a * LQ * 64;
  const u16* khb = khi + (size_t)h2b * LQ * 64;
  const u16* klb = klo + (size_t)h2b * LQ * 64;
  const u16* vb = vt + (size_t)h * 64 * LQ;

  // cooperative staging coords: thread t covers row t>>2, 16 cols at (t&3)*16
  const int srow = t >> 2;
  const int scol = (t & 3) * 16;

  int qm[4];
  float iz1[4], iz2[4];
#pragma unroll
  for (int j = 0; j < 4; ++j) {
    int q = qrow + grp * 4 + j;
    qm[j] = q & 511;
    float z1 = 0.f, z2 = 0.f;
#pragma unroll
    for (int ss = 0; ss < 4; ++ss) {
      z1 += zp[((size_t)(ss * 32 + h2a) << 11) + q];
      z2 += zp[((size_t)(ss * 32 + h2b) << 11) + q];
    }
    iz1[j] = 1.f / z1;
    iz2[j] = 1.f / z2;
  }

  f32x4 accO[4] = {};
  const int kbeg = s * 512;
  int buf = 0;

  // zero colsum for skipped (fully-masked) tiles of this segment
  for (int jt = c + 1; jt < 8; ++jt) {
    if (t < 64) colsum[((size_t)h * 32 + qt) * LQ + kbeg + jt * 64 + t] = 0.f;
  }

  // prologue: load tile 0 into registers
  uint4 rha0, rha1, rla0, rla1, rhb0, rhb1, rlb0, rlb1, rv0, rv1;
  {
    const size_t kb = (size_t)(kbeg + srow) * 64 + scol;
    rha0 = *(const uint4*)(kha + kb);
    rha1 = *(const uint4*)(kha + kb + 8);
    rla0 = *(const uint4*)(kla + kb);
    rla1 = *(const uint4*)(kla + kb + 8);
    rhb0 = *(const uint4*)(khb + kb);
    rhb1 = *(const uint4*)(khb + kb + 8);
    rlb0 = *(const uint4*)(klb + kb);
    rlb1 = *(const uint4*)(klb + kb + 8);
    const u16* vsrc = vb + (size_t)srow * LQ + kbeg + scol;
    rv0 = *(const uint4*)(vsrc);
    rv1 = *(const uint4*)(vsrc + 8);
  }

  for (int jt = 0; jt <= c; ++jt) {
    const int kt = kbeg + jt * 64;

    // write prefetched tile to LDS
    // (prev tile's K/V-LDS reads are fenced by the csLDS barrier of tile jt-1)
    *(uint4*)&KhA[srow][scol] = rha0; *(uint4*)&KhA[srow][scol + 8] = rha1;
    *(uint4*)&KlA[srow][scol] = rla0; *(uint4*)&KlA[srow][scol + 8] = rla1;
    *(uint4*)&KhB[srow][scol] = rhb0; *(uint4*)&KhB[srow][scol + 8] = rhb1;
    *(uint4*)&KlB[srow][scol] = rlb0; *(uint4*)&KlB[srow][scol + 8] = rlb1;
    *(uint4*)&Vs[srow][scol] = rv0;  *(uint4*)&Vs[srow][scol + 8] = rv1;
    __syncthreads();   // K/V tile ready

    // ---- issue NEXT tile's global loads (latency hides under compute) ----
    if (jt < c) {
      const size_t kb = (size_t)(kt + 64 + srow) * 64 + scol;
      rha0 = *(const uint4*)(kha + kb);
      rha1 = *(const uint4*)(kha + kb + 8);
      rla0 = *(const uint4*)(kla + kb);
      rla1 = *(const uint4*)(kla + kb + 8);
      rhb0 = *(const uint4*)(khb + kb);
      rhb1 = *(const uint4*)(khb + kb + 8);
      rlb0 = *(const uint4*)(klb + kb);
      rlb1 = *(const uint4*)(klb + kb + 8);
      const u16* vsrc = vb + (size_t)srow * LQ + kt + 64 + scol;
      rv0 = *(const uint4*)(vsrc);
      rv1 = *(const uint4*)(vsrc + 8);
    }

    __builtin_amdgcn_s_setprio(1);
    float pc[4][4], cs[4];
#pragma unroll
    for (int fk = 0; fk < 4; ++fk) {
      const int krow = fk * 16 + rsel;
      const int k = kt + krow;
      f32x4 z = {};
      SCORE6(z, aqa0h, aqa1h, aqa0l, aqa1l, &KhA[krow][ksel], &KlA[krow][ksel]);
      f32x4 w = {};
      SCORE6(w, aqb0h, aqb1h, aqb0l, aqb1l, &KhB[krow][ksel], &KlB[krow][ksel]);
      float csj = 0.f;
#pragma unroll
      for (int j = 0; j < 4; ++j) {
        bool msk = ((k & 511) > qm[j]);
        float sa = z[j] * SCALING;
        float pa = __builtin_copysignf(__expf(fabsf(sa)) * iz1[j], sa);
        pa = msk ? 0.f : pa;
        csj += pa;
        float sb = w[j] * SCALING;
        float pb = __builtin_copysignf(__expf(fabsf(sb)) * iz2[j], sb);
        pc[fk][j] = pa - (msk ? 0.f : lam * pb);
      }
      cs[fk] = csj;
    }
    // pc relayout through OWN pcLDS slice (intra-wave, lgkmcnt-ordered)
#pragma unroll
    for (int fk = 0; fk < 4; ++fk)
#pragma unroll
      for (int j = 0; j < 4; ++j)
        pcLDS[wv][grp * 4 + j][fk * 16 + rsel] = f2b(pc[fk][j]);
    // PV (intra-wave; V read from LDS)
#pragma unroll
    for (int kc = 0; kc < 2; ++kc) {
      bf16x8 ap = *(const bf16x8*)&pcLDS[wv][rsel][kc * 32 + ksel];
#pragma unroll
      for (int fn = 0; fn < 4; ++fn) {
        bf16x8 bv = *(const bf16x8*)&Vs[fn * 16 + rsel][kc * 32 + ksel];
        accO[fn] = MFMA16(ap, bv, accO[fn]);
      }
    }
    __builtin_amdgcn_s_setprio(0);
    // cross-wave colsum (csLDS dbuf + barrier; barrier also fences K/V reads
    // of this tile before next tile's ds_writes)
#pragma unroll
    for (int fk = 0; fk < 4; ++fk) {
      float cc = cs[fk];
      cc += __shfl_xor(cc, 16);
      cc += __shfl_xor(cc, 32);
      if (grp == 0) csLDS[buf][wv][fk * 16 + rsel] = cc;
    }
    __syncthreads();
    if (t < 64) {
      float tot = csLDS[buf][0][t] + csLDS[buf][1][t] + csLDS[buf][2][t] + csLDS[buf][3][t];
      colsum[((size_t)h * 32 + qt) * LQ + kt + t] = tot;
    }
    buf ^= 1;
  }
  float* Op = (s == 0) ? O0 : (O123 + (size_t)(s - 1) * 16 * LQ * 64);
#pragma unroll
  for (int fn = 0; fn < 4; ++fn)
#pragma unroll
    for (int j = 0; j < 4; ++j) {
      int q = qrow + grp * 4 + j;
      int d = fn * 16 + rsel;
      Op[((size_t)h * LQ + q) * 64 + d] = accO[fn][j];
    }
}

// g[h][k] = sum_qt colsum[h][qt][k] / 2048
__global__ void g_reduce_kernel(const float* __restrict__ colsum, float* __restrict__ g) {
  int idx = blockIdx.x * 256 + threadIdx.x;
  if (idx >= 16 * LQ) return;
  int h = idx >> 11, k = idx & 2047;
  float s = 0.f;
#pragma unroll
  for (int qt = 0; qt < 32; ++qt) s += colsum[((size_t)h * 32 + qt) * LQ + k];
  g[idx] = s * (1.f / 2048.f);
}

// Gv[h][r][d] = sum_seg g[h][seg*512+r] * vt[h][d][seg*512+r]
__global__ void gv_kernel(const float* __restrict__ g, const u16* __restrict__ vt,
                          float* __restrict__ Gv) {
  int idx = blockIdx.x * 256 + threadIdx.x;
  if (idx >= 16 * 512 * 64) return;
  int d = idx & 63, r = (idx >> 6) & 511, h = idx >> 15;
  float s = 0.f;
#pragma unroll
  for (int seg = 0; seg < 4; ++seg) {
    int k = seg * 512 + r;
    s += g[h * 2048 + k] * b2f(vt[((size_t)h * 64 + d) * LQ + k]);
  }
  Gv[idx] = s;
}

// W[h][r][d] = inclusive prefix over r of Gv[h][r][d]
__global__ __launch_bounds__(512) void wscan_kernel(const float* __restrict__ Gv,
                                                    float* __restrict__ W) {
  __shared__ float s[512];
  int h = blockIdx.x >> 6, d = blockIdx.x & 63;
  int t = threadIdx.x;
  s[t] = Gv[((size_t)h * 512 + t) * 64 + d];
  __syncthreads();
  for (int off = 1; off < 512; off <<= 1) {
    float add = (t >= off) ? s[t - off] : 0.f;
    __syncthreads();
    s[t] += add;
    __syncthreads();
  }
  W[((size_t)h * 512 + t) * 64 + d] = s[t];
}

// out_pre = O0 + O1 + O2 + O3 + lam*W[q%512]; head rmsnorm -> bf16 [q][h*64+d]
__global__ __launch_bounds__(256) void combine_norm_kernel(
    const float* __restrict__ O0, const float* __restrict__ O123,
    const float* __restrict__ W, const float* __restrict__ hw,
    const float* __restrict__ lamp, u16* __restrict__ out) {
  const int q = blockIdx.x;
  const int h = blockIdx.y * 4 + (threadIdx.x >> 6);
  const int d = threadIdx.x & 63;
  const float lam = lamp[0];
  const size_t S = (size_t)16 * LQ * 64;
  const size_t idx = ((size_t)h * LQ + q) * 64 + d;
  float v = O0[idx] + O123[idx] + O123[idx + S] + O123[idx + 2 * S] +
            lam * W[((size_t)h * 512 + (q & 511)) * 64 + d];
  float ss = v * v;
#pragma unroll
  for (int off = 1; off < 64; off <<= 1) ss += __shfl_xor(ss, off);
  float sc = 1.f / sqrtf(ss * (1.f / 64.f) + 1e-5f);
  out[(size_t)q * 1024 + h * 64 + d] = f2b(v * sc * hw[d]);
}

// ============================== launch ==============================
extern "C" void kernel_launch(void* const* d_in, const int* in_sizes, int n_in,
                              void* d_out, int out_size, void* d_ws, size_t ws_size,
                              hipStream_t stream) {
  const float* x = (const float*)d_in[0];
  const float* freqs_r = (const float*)d_in[1];
  const float* freqs_i = (const float*)d_in[2];
  // d_in[3] = mask (recomputed analytically)
  const float* kv_down_w = (const float*)d_in[4];
  const float* q_down_w = (const float*)d_in[5];
  const float* kv_up_w = (const float*)d_in[6];
  const float* q_up_w = (const float*)d_in[7];
  const float* kv_norm_w = (const float*)d_in[8];
  const float* q_norm_w = (const float*)d_in[9];
  const float* o_w = (const float*)d_in[10];
  const float* lambda_q1 = (const float*)d_in[11];
  const float* lambda_k1 = (const float*)d_in[12];
  const float* lambda_q2 = (const float*)d_in[13];
  const float* lambda_k2 = (const float*)d_in[14];
  const float* head_norm_w = (const float*)d_in[15];
  const float* norm1_w = (const float*)d_in[16];
  const float* norm2_w = (const float*)d_in[17];
  const float* ff_in_w = (const float*)d_in[18];
  const float* ff_out_w = (const float*)d_in[19];
  float* out = (float*)d_out;
  char* ws = (char*)d_ws;

  // ---- weights region (persistent except down/up: dead after projections) ----
  const size_t WT_KVD_H = 0;                                  // 544x1024 bf16
  const size_t WT_KVD_L = WT_KVD_H + (size_t)544 * 1024 * 2;
  const size_t WT_QD_H  = WT_KVD_L + (size_t)544 * 1024 * 2;  // 512x1024
  const size_t WT_QD_L  = WT_QD_H + (size_t)512 * 1024 * 2;
  const size_t WT_KVU_H = WT_QD_L + (size_t)512 * 1024 * 2;   // 2048x512
  const size_t WT_KVU_L = WT_KVU_H + (size_t)2048 * 512 * 2;
  const size_t WT_QU_H  = WT_KVU_L + (size_t)2048 * 512 * 2;  // 1536x512
  const size_t WT_QU_L  = WT_QU_H + (size_t)1536 * 512 * 2;
  const size_t WT_OW    = WT_QU_L + (size_t)1536 * 512 * 2;   // = 11,714,560
  const size_t WT_FFI   = WT_OW + (size_t)1024 * 1024 * 2;
  const size_t WT_FFO   = WT_FFI + (size_t)8192 * 1024 * 2;
  const size_t A0 = WT_FFO + (size_t)1024 * 4096 * 2;         // = 38,928,384

  // ---- activations (lifetime-aliased) ----
  const size_t H     = A0;                  // h hi/lo bf16 (2x 4,194,304); dead after down-GEMMs
  const size_t CKV   = A0 + 8388608;        // f32 2048x544;  dead after build_kh
  const size_t CKVN  = A0 + 12845056;       // ckvn hi/lo bf16 (2x 2,097,152); dead after kv_up
  const size_t KVB   = A0 + 17039360;       // f32 2048x2048; dead after build_vt
  const size_t CQ    = A0 + 33816576;       // f32 2048x512;  dead after rmsnorm
  const size_t CQN   = A0 + 38010880;       // cqn hi/lo bf16 (2x 2,097,152); dead after q_up
  const size_t QFULL = A0 + 42205184;       // f32 2048x1536; dead after build_qh
  // mid buffers (aliases):
  const size_t QHI = H;                     // bf16 32x2048x64 over dead H
  const size_t KHI = QFULL;                 // bf16 32x2048x64 over dead QFULL[0:8.39M]
  const size_t KLO = A0 + 50593792;         // bf16 32x2048x64 over dead QFULL[8.39M:]+
  const size_t QLO = A0 + 58982400;         // bf16 32x2048x64
  const size_t VT  = CKVN;                  // bf16 16x64x2048 over dead CKVN
  // O partials (4 x 8,388,608 f32):
  const size_t OP0   = 0;                   // over dead down/up weights [0, 8.39M) < WT_OW
  const size_t OP123 = KVB;                 // 3 contiguous partials over dead KVB+CQ+CQN
  const size_t CS  = CKV;                   // f32 16x32x2048 over dead CKV
  const size_t GB  = A0 + 67371008;         // f32 16x2048 (131,072)
  const size_t GV  = A0 + 67502080;         // f32 16x512x64 (2,097,152)
  const size_t WB  = A0 + 69599232;         // f32 16x512x64 (2,097,152)
  const size_t LAM = A0 + 71696384;         // scalar
  const size_t ZP  = A0 + 71696640;         // f32 4x32x2048 (1,048,576)
  const size_t WS_END = A0 + 72745216;      // ~111.7 MB (known-safe)
  // late aliases:
  const size_t ATTN  = CKV;                 // bf16 2048x1024 (over consumed CS)
  const size_t X1    = KVB + 8388608;       // f32 2048x1024 (partials consumed by combine)
  const size_t H2N   = H;                   // bf16 2048x1024 over dead QHI
  const size_t FFACT = QFULL;               // bf16 2048x4096 over dead KHI+KLO

  if (ws_size < WS_END) return;

  u16* wt_kvd_h = (u16*)(ws + WT_KVD_H); u16* wt_kvd_l = (u16*)(ws + WT_KVD_L);
  u16* wt_qd_h  = (u16*)(ws + WT_QD_H);  u16* wt_qd_l  = (u16*)(ws + WT_QD_L);
  u16* wt_kvu_h = (u16*)(ws + WT_KVU_H); u16* wt_kvu_l = (u16*)(ws + WT_KVU_L);
  u16* wt_qu_h  = (u16*)(ws + WT_QU_H);  u16* wt_qu_l  = (u16*)(ws + WT_QU_L);
  u16* wt_ow  = (u16*)(ws + WT_OW);
  u16* wt_ffi = (u16*)(ws + WT_FFI);
  u16* wt_ffo = (u16*)(ws + WT_FFO);
  u16* h_hi   = (u16*)(ws + H);
  u16* h_lo   = (u16*)(ws + H + 4194304);
  float* ckv  = (float*)(ws + CKV);
  u16* ckvn_hi = (u16*)(ws + CKVN);
  u16* ckvn_lo = (u16*)(ws + CKVN + 2097152);
  float* kvb  = (float*)(ws + KVB);
  float* cq   = (float*)(ws + CQ);
  u16* cqn_hi = (u16*)(ws + CQN);
  u16* cqn_lo = (u16*)(ws + CQN + 2097152);
  float* qfull = (float*)(ws + QFULL);
  u16* qhib = (u16*)(ws + QHI); u16* qlob = (u16*)(ws + QLO);
  u16* khib = (u16*)(ws + KHI); u16* klob = (u16*)(ws + KLO);
  u16* vtb  = (u16*)(ws + VT);
  float* zpb = (float*)(ws + ZP);
  float* Op0 = (float*)(ws + OP0);
  float* Op123 = (float*)(ws + OP123);
  float* csb = (float*)(ws + CS);
  float* gb  = (float*)(ws + GB);
  float* gvb = (float*)(ws + GV);
  float* wbb = (float*)(ws + WB);
  float* lamp = (float*)(ws + LAM);
  u16* attn_n = (u16*)(ws + ATTN);
  float* x1 = (float*)(ws + X1);
  u16* h2n = (u16*)(ws + H2N);
  u16* ffact = (u16*)(ws + FFACT);

  dim3 tb(32, 8);
  transpose_split<<<dim3(17, 32), tb, 0, stream>>>(kv_down_w, wt_kvd_h, wt_kvd_l, 1024, 544);
  transpose_split<<<dim3(16, 32), tb, 0, stream>>>(q_down_w, wt_qd_h, wt_qd_l, 1024, 512);
  transpose_split<<<dim3(64, 16), tb, 0, stream>>>(kv_up_w, wt_kvu_h, wt_kvu_l, 512, 2048);
  transpose_split<<<dim3(48, 16), tb, 0, stream>>>(q_up_w, wt_qu_h, wt_qu_l, 512, 1536);
  transpose_to_bf16<<<dim3(32, 32), tb, 0, stream>>>(o_w, wt_ow, 1024, 1024);
  transpose_to_bf16<<<dim3(256, 32), tb, 0, stream>>>(ff_in_w, wt_ffi, 1024, 8192);
  transpose_to_bf16<<<dim3(32, 128), tb, 0, stream>>>(ff_out_w, wt_ffo, 4096, 1024);

  rmsnorm_split_kernel<<<2048, 256, 0, stream>>>(x, norm1_w, h_hi, h_lo, 1024, 1024, FEPS);
  gemm_split<<<dim3(9, 32), 256, 0, stream>>>(h_hi, h_lo, wt_kvd_h, wt_kvd_l, ckv,
                                              2048, 544, 1024);
  rmsnorm_split_kernel<<<2048, 256, 0, stream>>>(ckv, kv_norm_w, ckvn_hi, ckvn_lo,
                                                 512, 544, FEPS);
  gemm_split<<<dim3(32, 32), 256, 0, stream>>>(ckvn_hi, ckvn_lo, wt_kvu_h, wt_kvu_l, kvb,
                                               2048, 2048, 512);
  gemm_split<<<dim3(8, 32), 256, 0, stream>>>(h_hi, h_lo, wt_qd_h, wt_qd_l, cq,
                                              2048, 512, 1024);
  rmsnorm_split_kernel<<<2048, 256, 0, stream>>>(cq, q_norm_w, cqn_hi, cqn_lo,
                                                 512, 512, FEPS);
  gemm_split<<<dim3(24, 32), 256, 0, stream>>>(cqn_hi, cqn_lo, wt_qu_h, wt_qu_l, qfull,
                                               2048, 1536, 512);

  build_qh_kernel<<<dim3(2048, 8), 256, 0, stream>>>(qfull, freqs_r, freqs_i, qhib, qlob);
  build_kh_kernel<<<dim3(2048, 8), 256, 0, stream>>>(kvb, ckv, freqs_r, freqs_i, khib, klob);
  build_vt_kernel<<<dim3(32, 16), 256, 0, stream>>>(kvb, vtb);

  lam_kernel<<<1, 32, 0, stream>>>(lambda_q1, lambda_k1, lambda_q2, lambda_k2, lamp);
  attn_z_kernel<<<4096, 256, 0, stream>>>(qhib, khib, zpb);
  attn_pv_kernel<<<2048, 256, 0, stream>>>(qhib, qlob, khib, klob, vtb, zpb,
                                           lamp, Op0, Op123, csb);

  g_reduce_kernel<<<128, 256, 0, stream>>>(csb, gb);
  gv_kernel<<<2048, 256, 0, stream>>>(gb, vtb, gvb);
  wscan_kernel<<<1024, 512, 0, stream>>>(gvb, wbb);
  combine_norm_kernel<<<dim3(2048, 4), 256, 0, stream>>>(Op0, Op123, wbb, head_norm_w,
                                                         lamp, attn_n);

  // x1 = x + attn_n @ o_w  (residual fused into epilogue)
  gemm_kernel<0, 1><<<dim3(16, 32), 256, 0, stream>>>(attn_n, wt_ow, x, x1, nullptr,
                                                      2048, 1024, 1024);
  rmsnorm_kernel<1><<<2048, 256, 0, stream>>>(x1, norm2_w, h2n, 1024, 1024, FEPS);
  gemm_kernel<1, 0><<<dim3(64, 32), 256, 0, stream>>>(h2n, wt_ffi, nullptr, nullptr, ffact,
                                                      2048, 4096, 1024);
  // out = x1 + ffact @ ff_out  (residual fused into epilogue)
  gemm_kernel<0, 1><<<dim3(16, 32), 256, 0, stream>>>(ffact, wt_ffo, x1, out, nullptr,
                                                      2048, 1024, 4096);
}

// Round 24
// 368.353 us; speedup vs baseline: 1.1052x; 1.0621x over previous
//
#include <hip/hip_runtime.h>
#include <math.h>

#define LQ 2048
#define SCALING 0.14433756729740643f   // 48^-0.5
#define FEPS 1.1920928955078125e-07f   // np.finfo(float32).eps

typedef unsigned short u16;
typedef __attribute__((ext_vector_type(8))) short bf16x8;
typedef __attribute__((ext_vector_type(4))) float f32x4;

#define MFMA16(a, b, c) __builtin_amdgcn_mfma_f32_16x16x32_bf16((a), (b), (c), 0, 0, 0)

__device__ __forceinline__ u16 f2b(float x) {
  union { float f; unsigned u; } v; v.f = x;
  return (u16)((v.u + 0x7FFFu + ((v.u >> 16) & 1u)) >> 16);
}
__device__ __forceinline__ float b2f(u16 b) {
  union { unsigned u; float f; } v; v.u = ((unsigned)b) << 16;
  return v.f;
}

// ---- fused weight prep: all 7 transposes in one kernel (flat-grid segments).
//      split segments write hi/lo bf16 [N][K]; single segments write bf16 [N][K]. ----
__global__ __launch_bounds__(256) void prep_weights_kernel(
    const float* __restrict__ kvd, u16* __restrict__ kvd_h, u16* __restrict__ kvd_l,
    const float* __restrict__ qd,  u16* __restrict__ qd_h,  u16* __restrict__ qd_l,
    const float* __restrict__ kvu, u16* __restrict__ kvu_h, u16* __restrict__ kvu_l,
    const float* __restrict__ qu,  u16* __restrict__ qu_h,  u16* __restrict__ qu_l,
    const float* __restrict__ ow,  u16* __restrict__ ow_t,
    const float* __restrict__ ffi, u16* __restrict__ ffi_t,
    const float* __restrict__ ffo, u16* __restrict__ ffo_t) {
  __shared__ float tile[32][33];
  int id = blockIdx.x;
  const float* W; u16* Whi; u16* Wlo = nullptr; int K, N, bx, by;
  if (id < 8192) {                       // ff_in 1024x8192 (heaviest first)
    W = ffi; Whi = ffi_t; K = 1024; N = 8192; bx = id % 256; by = id / 256;
  } else if (id < 8192 + 4096) {         // ff_out 4096x1024
    id -= 8192;
    W = ffo; Whi = ffo_t; K = 4096; N = 1024; bx = id % 32; by = id / 32;
  } else if (id < 12288 + 1024) {        // o_w 1024x1024
    id -= 12288;
    W = ow; Whi = ow_t; K = 1024; N = 1024; bx = id % 32; by = id / 32;
  } else if (id < 13312 + 544) {         // kv_down 1024x544 (split)
    id -= 13312;
    W = kvd; Whi = kvd_h; Wlo = kvd_l; K = 1024; N = 544; bx = id % 17; by = id / 17;
  } else if (id < 13856 + 512) {         // q_down 1024x512 (split)
    id -= 13856;
    W = qd; Whi = qd_h; Wlo = qd_l; K = 1024; N = 512; bx = id % 16; by = id / 16;
  } else if (id < 14368 + 1024) {        // kv_up 512x2048 (split)
    id -= 14368;
    W = kvu; Whi = kvu_h; Wlo = kvu_l; K = 512; N = 2048; bx = id % 64; by = id / 64;
  } else {                               // q_up 512x1536 (split)
    id -= 15392;
    W = qu; Whi = qu_h; Wlo = qu_l; K = 512; N = 1536; bx = id % 48; by = id / 48;
  }

  int n0 = bx * 32, k0 = by * 32;
  int tx = threadIdx.x, ty = threadIdx.y;  // 32 x 8
  for (int i = ty; i < 32; i += 8) {
    int k = k0 + i, n = n0 + tx;
    tile[i][tx] = (k < K && n < N) ? W[(size_t)k * N + n] : 0.f;
  }
  __syncthreads();
  for (int i = ty; i < 32; i += 8) {
    int n = n0 + i, k = k0 + tx;
    if (n < N && k < K) {
      float xv = tile[tx][i];
      u16 hi = f2b(xv);
      Whi[(size_t)n * K + k] = hi;
      if (Wlo) Wlo[(size_t)n * K + k] = f2b(xv - b2f(hi));
    }
  }
}

// ---------------- rmsnorm fp32 in (strided) -> fp32 or bf16 out ----------------
template <int BF16OUT>
__global__ __launch_bounds__(256) void rmsnorm_kernel(
    const float* __restrict__ x, const float* __restrict__ w, void* __restrict__ outv,
    int cols, int in_stride, float eps) {
  const int row = blockIdx.x;
  const float* xr = x + (size_t)row * in_stride;
  float ss = 0.f;
  for (int c = threadIdx.x; c < cols; c += 256) { float v = xr[c]; ss = fmaf(v, v, ss); }
#pragma unroll
  for (int off = 32; off > 0; off >>= 1) ss += __shfl_xor(ss, off);
  __shared__ float red[4];
  if ((threadIdx.x & 63) == 0) red[threadIdx.x >> 6] = ss;
  __syncthreads();
  float tot = red[0] + red[1] + red[2] + red[3];
  float sc = 1.f / sqrtf(tot / (float)cols + eps);
  for (int c = threadIdx.x; c < cols; c += 256) {
    float v = xr[c] * sc * w[c];
    if (BF16OUT) ((u16*)outv)[(size_t)row * cols + c] = f2b(v);
    else ((float*)outv)[(size_t)row * cols + c] = v;
  }
}

// ---- rmsnorm fp32 in (strided) -> hi/lo bf16 out (split once, reused by gemm) ----
__global__ __launch_bounds__(256) void rmsnorm_split_kernel(
    const float* __restrict__ x, const float* __restrict__ w,
    u16* __restrict__ hi_out, u16* __restrict__ lo_out,
    int cols, int in_stride, float eps) {
  const int row = blockIdx.x;
  const float* xr = x + (size_t)row * in_stride;
  float ss = 0.f;
  for (int c = threadIdx.x; c < cols; c += 256) { float v = xr[c]; ss = fmaf(v, v, ss); }
#pragma unroll
  for (int off = 32; off > 0; off >>= 1) ss += __shfl_xor(ss, off);
  __shared__ float red[4];
  if ((threadIdx.x & 63) == 0) red[threadIdx.x >> 6] = ss;
  __syncthreads();
  float tot = red[0] + red[1] + red[2] + red[3];
  float sc = 1.f / sqrtf(tot / (float)cols + eps);
  for (int c = threadIdx.x; c < cols; c += 256) {
    float v = xr[c] * sc * w[c];
    u16 hi = f2b(v);
    hi_out[(size_t)row * cols + c] = hi;
    lo_out[(size_t)row * cols + c] = f2b(v - b2f(hi));
  }
}

// ---- split-precision GEMM (3-term), all-bf16 staging ----
__global__ __launch_bounds__(256) void gemm_split(
    const u16* __restrict__ Ahi, const u16* __restrict__ Alo,
    const u16* __restrict__ Bhi, const u16* __restrict__ Blo,
    float* __restrict__ C, int M, int N, int K) {
  __shared__ u16 Ah[64][72];
  __shared__ u16 Al[64][72];
  __shared__ u16 Bh[64][72];
  __shared__ u16 Bl[64][72];

  const int t = threadIdx.x;
  const int lane = t & 63;
  const int wv = t >> 6;
  const int wr = (wv >> 1) * 32;
  const int wc = (wv & 1) * 32;
  const int bm = blockIdx.y * 64;
  const int bn = blockIdx.x * 64;
  const int lr = t >> 2;
  const int lc = (t & 3) * 16;
  const int rsel = lane & 15;
  const int ksel = 8 * (lane >> 4);

  const u16* Ahrow = Ahi + (size_t)(bm + lr) * K + lc;
  const u16* Alrow = Alo + (size_t)(bm + lr) * K + lc;
  const bool bval = (bn + lr) < N;
  const u16* Bhrow = Bhi + (size_t)(bn + lr) * K + lc;
  const u16* Blrow = Blo + (size_t)(bn + lr) * K + lc;

  f32x4 acc[2][2] = {};

  for (int kt = 0; kt < K; kt += 64) {
    uint4 ah0 = *(const uint4*)(Ahrow + kt);
    uint4 ah1 = *(const uint4*)(Ahrow + kt + 8);
    uint4 al0 = *(const uint4*)(Alrow + kt);
    uint4 al1 = *(const uint4*)(Alrow + kt + 8);
    uint4 bh0 = {0, 0, 0, 0}, bh1 = {0, 0, 0, 0}, bl0 = {0, 0, 0, 0}, bl1 = {0, 0, 0, 0};
    if (bval) {
      bh0 = *(const uint4*)(Bhrow + kt); bh1 = *(const uint4*)(Bhrow + kt + 8);
      bl0 = *(const uint4*)(Blrow + kt); bl1 = *(const uint4*)(Blrow + kt + 8);
    }
    __syncthreads();
    *(uint4*)&Ah[lr][lc] = ah0; *(uint4*)&Ah[lr][lc + 8] = ah1;
    *(uint4*)&Al[lr][lc] = al0; *(uint4*)&Al[lr][lc + 8] = al1;
    *(uint4*)&Bh[lr][lc] = bh0; *(uint4*)&Bh[lr][lc + 8] = bh1;
    *(uint4*)&Bl[lr][lc] = bl0; *(uint4*)&Bl[lr][lc + 8] = bl1;
    __syncthreads();
#pragma unroll
    for (int ks = 0; ks < 2; ++ks) {
      const int ko = ks * 32 + ksel;
      bf16x8 a0h = *(const bf16x8*)&Ah[wr + rsel][ko];
      bf16x8 a1h = *(const bf16x8*)&Ah[wr + 16 + rsel][ko];
      bf16x8 a0l = *(const bf16x8*)&Al[wr + rsel][ko];
      bf16x8 a1l = *(const bf16x8*)&Al[wr + 16 + rsel][ko];
      bf16x8 b0h = *(const bf16x8*)&Bh[wc + rsel][ko];
      bf16x8 b1h = *(const bf16x8*)&Bh[wc + 16 + rsel][ko];
      bf16x8 b0l = *(const bf16x8*)&Bl[wc + rsel][ko];
      bf16x8 b1l = *(const bf16x8*)&Bl[wc + 16 + rsel][ko];
      acc[0][0] = MFMA16(a0h, b0h, acc[0][0]);
      acc[0][0] = MFMA16(a0h, b0l, acc[0][0]);
      acc[0][0] = MFMA16(a0l, b0h, acc[0][0]);
      acc[0][1] = MFMA16(a0h, b1h, acc[0][1]);
      acc[0][1] = MFMA16(a0h, b1l, acc[0][1]);
      acc[0][1] = MFMA16(a0l, b1h, acc[0][1]);
      acc[1][0] = MFMA16(a1h, b0h, acc[1][0]);
      acc[1][0] = MFMA16(a1h, b0l, acc[1][0]);
      acc[1][0] = MFMA16(a1l, b0h, acc[1][0]);
      acc[1][1] = MFMA16(a1h, b1h, acc[1][1]);
      acc[1][1] = MFMA16(a1h, b1l, acc[1][1]);
      acc[1][1] = MFMA16(a1l, b1h, acc[1][1]);
    }
  }
  const int r0 = (lane >> 4) * 4;
#pragma unroll
  for (int fm = 0; fm < 2; ++fm)
#pragma unroll
    for (int fn = 0; fn < 2; ++fn)
#pragma unroll
      for (int j = 0; j < 4; ++j) {
        int row = bm + wr + fm * 16 + r0 + j;
        int col = bn + wc + fn * 16 + rsel;
        if (col < N) C[(size_t)row * N + col] = acc[fm][fn][j];
      }
}

// ---- plain bf16 GEMM (o_w / FFN): 64x64 reg-staged. ADDX fuses residual add. ----
template <int GATED, int ADDX>
__global__ __launch_bounds__(256) void gemm_kernel(
    const u16* __restrict__ A, const u16* __restrict__ Bt, const float* __restrict__ X,
    float* __restrict__ C, u16* __restrict__ Cg, int M, int N, int K) {
  __shared__ u16 As[64][72];
  __shared__ u16 Bs[64][72];
  __shared__ u16 Bs2[GATED ? 64 : 1][72];

  const int t = threadIdx.x;
  const int lane = t & 63;
  const int wv = t >> 6;
  const int wr = (wv >> 1) * 32;
  const int wc = (wv & 1) * 32;
  const int bm = blockIdx.y * 64;
  const int bn = blockIdx.x * 64;
  const int lr = t >> 2;
  const int lc = (t & 3) * 16;
  const int rsel = lane & 15;
  const int ksel = 8 * (lane >> 4);

  const u16* Arow = A + (size_t)(bm + lr) * K + lc;
  const u16* Brow = Bt + (size_t)(bn + lr) * K + lc;
  const u16* Brow2 = Bt + (size_t)(4096 + bn + lr) * K + lc;

  f32x4 acc[2][2] = {};
  f32x4 accg[2][2] = {};

  for (int kt = 0; kt < K; kt += 64) {
    uint4 a0 = *(const uint4*)(Arow + kt);
    uint4 a1 = *(const uint4*)(Arow + kt + 8);
    uint4 b0 = *(const uint4*)(Brow + kt);
    uint4 b1 = *(const uint4*)(Brow + kt + 8);
    uint4 c0 = {0, 0, 0, 0}, c1 = {0, 0, 0, 0};
    if (GATED) { c0 = *(const uint4*)(Brow2 + kt); c1 = *(const uint4*)(Brow2 + kt + 8); }
    __syncthreads();
    *(uint4*)&As[lr][lc] = a0; *(uint4*)&As[lr][lc + 8] = a1;
    *(uint4*)&Bs[lr][lc] = b0; *(uint4*)&Bs[lr][lc + 8] = b1;
    if (GATED) { *(uint4*)&Bs2[lr][lc] = c0; *(uint4*)&Bs2[lr][lc + 8] = c1; }
    __syncthreads();
#pragma unroll
    for (int ks = 0; ks < 2; ++ks) {
      const int ko = ks * 32 + ksel;
      bf16x8 af0 = *(const bf16x8*)&As[wr + rsel][ko];
      bf16x8 af1 = *(const bf16x8*)&As[wr + 16 + rsel][ko];
      bf16x8 bf0 = *(const bf16x8*)&Bs[wc + rsel][ko];
      bf16x8 bf1 = *(const bf16x8*)&Bs[wc + 16 + rsel][ko];
      acc[0][0] = MFMA16(af0, bf0, acc[0][0]);
      acc[0][1] = MFMA16(af0, bf1, acc[0][1]);
      acc[1][0] = MFMA16(af1, bf0, acc[1][0]);
      acc[1][1] = MFMA16(af1, bf1, acc[1][1]);
      if (GATED) {
        bf16x8 cf0 = *(const bf16x8*)&Bs2[wc + rsel][ko];
        bf16x8 cf1 = *(const bf16x8*)&Bs2[wc + 16 + rsel][ko];
        accg[0][0] = MFMA16(af0, cf0, accg[0][0]);
        accg[0][1] = MFMA16(af0, cf1, accg[0][1]);
        accg[1][0] = MFMA16(af1, cf0, accg[1][0]);
        accg[1][1] = MFMA16(af1, cf1, accg[1][1]);
      }
    }
  }
  const int r0 = (lane >> 4) * 4;
#pragma unroll
  for (int fm = 0; fm < 2; ++fm)
#pragma unroll
    for (int fn = 0; fn < 2; ++fn)
#pragma unroll
      for (int j = 0; j < 4; ++j) {
        int row = bm + wr + fm * 16 + r0 + j;
        int col = bn + wc + fn * 16 + rsel;
        size_t o = (size_t)row * N + col;
        if (!GATED) {
          float v = acc[fm][fn][j];
          if (ADDX) v += X[o];
          C[o] = v;
        } else {
          float u = acc[fm][fn][j], g = accg[fm][fn][j];
          float sv = g / (1.f + __expf(-g));
          Cg[o] = f2b(u * sv);
        }
      }
}

// ---- fused mid build: build_qh + build_kh + build_vt + lam in one kernel ----
__global__ __launch_bounds__(256) void build_mid_kernel(
    const float* __restrict__ qfull, const float* __restrict__ kv,
    const float* __restrict__ ckv, const float* __restrict__ fr,
    const float* __restrict__ fi, u16* __restrict__ qhi, u16* __restrict__ qlo,
    u16* __restrict__ khi, u16* __restrict__ klo, u16* __restrict__ vt,
    const float* __restrict__ lq1, const float* __restrict__ lk1,
    const float* __restrict__ lq2, const float* __restrict__ lk2,
    float* __restrict__ lamp) {
  __shared__ u16 tile[64][65];
  int id = blockIdx.x;
  if (id < 16384) {
    // ---- build_qh ----
    const int q = id & 2047;
    const int h2 = ((id >> 11) << 2) + (threadIdx.x >> 6);
    const int d = threadIdx.x & 63;
    const int hh = h2 >> 1, s = h2 & 1;
    const float* row = qfull + (size_t)q * 1536 + hh * 96;
    float val;
    if (d < 32) {
      val = row[s * 32 + d];
    } else if (d < 48) {
      int r = d - 32;
      int pos = q & 511;
      const float* rp = row + 64 + s * 16;
      if (pos == 0) val = rp[r];
      else {
        int j = r >> 1;
        float cr = fr[(pos - 1) * 8 + j], ci = fi[(pos - 1) * 8 + j];
        float a = rp[2 * j], b = rp[2 * j + 1];
        val = (r & 1) ? (a * ci + b * cr) : (a * cr - b * ci);
      }
    } else val = 0.f;
    u16 hi = f2b(val);
    qhi[((size_t)h2 * LQ + q) * 64 + d] = hi;
    qlo[((size_t)h2 * LQ + q) * 64 + d] = f2b(val - b2f(hi));
    return;
  }
  id -= 16384;
  if (id < 16384) {
    // ---- build_kh ----
    const int kp = id & 2047;
    const int h2 = ((id >> 11) << 2) + (threadIdx.x >> 6);
    const int d = threadIdx.x & 63;
    const int hh = h2 >> 1, s = h2 & 1;
    float val;
    if (d < 32) {
      val = kv[(size_t)kp * 2048 + hh * 128 + s * 32 + d];
    } else if (d < 48) {
      int r = d - 32;
      int pos = kp & 511;
      const float* rp = ckv + (size_t)kp * 544 + 512 + s * 16;
      if (pos == 0) val = rp[r];
      else {
        int j = r >> 1;
        float cr = fr[(pos - 1) * 8 + j], ci = fi[(pos - 1) * 8 + j];
        float a = rp[2 * j], b = rp[2 * j + 1];
        val = (r & 1) ? (a * ci + b * cr) : (a * cr - b * ci);
      }
    } else val = 0.f;
    u16 hi = f2b(val);
    khi[((size_t)h2 * LQ + kp) * 64 + d] = hi;
    klo[((size_t)h2 * LQ + kp) * 64 + d] = f2b(val - b2f(hi));
    return;
  }
  id -= 16384;
  if (id < 512) {
    // ---- build_vt: vt[h][d][k] = bf16(kv[k][h*128+64+d]) ----
    int h = id >> 5, k0 = (id & 31) * 64;
    int t = threadIdx.x;
    int d = t & 63, kr = t >> 6;
#pragma unroll
    for (int i = 0; i < 16; ++i) {
      int k = kr + i * 4;
      tile[k][d] = f2b(kv[(size_t)(k0 + k) * 2048 + h * 128 + 64 + d]);
    }
    __syncthreads();
    int kk = t & 63, dr = t >> 6;
#pragma unroll
    for (int i = 0; i < 16; ++i) {
      int d2 = dr + i * 4;
      vt[((size_t)h * 64 + d2) * LQ + k0 + kk] = tile[kk][d2];
    }
    return;
  }
  // ---- lam = exp(sum(lk1*lq1)) - exp(sum(lk2*lq2)) + 0.2 ----
  int t = threadIdx.x;
  if (t < 32) {
    float a = lq1[t] * lk1[t], b = lq2[t] * lk2[t];
#pragma unroll
    for (int off = 1; off < 32; off <<= 1) { a += __shfl_xor(a, off); b += __shfl_xor(b, off); }
    if (t == 0) lamp[0] = expf(a) - expf(b) + 0.2f;
  }
}

// 6-MFMA split-precision 16x16 score tile
#define SCORE6(z, a0h, a1h, a0l, a1l, ph, pl)                         \
  {                                                                   \
    bf16x8 bh0 = *(const bf16x8*)(ph), bh1 = *(const bf16x8*)((ph) + 32); \
    bf16x8 bl0 = *(const bf16x8*)(pl), bl1 = *(const bf16x8*)((pl) + 32); \
    z = MFMA16(a0h, bh0, z); z = MFMA16(a1h, bh1, z);                 \
    z = MFMA16(a0h, bl0, z); z = MFMA16(a1h, bl1, z);                 \
    z = MFMA16(a0l, bh0, z); z = MFMA16(a1l, bh1, z);                 \
  }

// ---- attention Z: zp[s][h2][q] = sum over k-segment s of exp|a| (s = 0..3) ----
// K tiles COOPERATIVELY staged in dbuf LDS (dedup across 4 waves).
__global__ __launch_bounds__(256) void attn_z_kernel(
    const u16* __restrict__ qhi, const u16* __restrict__ khi,
    float* __restrict__ zp) {
  __shared__ u16 Kh[2][64][72];

  const int bid = blockIdx.x;
  const int c = 7 - (bid >> 9);                 // heavy-first
  const int r = bid & 511;
  const int h2 = r & 31;
  const int qtIdx = (r >> 5) & 3;
  const int s = r >> 7;                         // 0..3
  const int qt = qtIdx * 8 + c;
  const int qb = qt * 64;
  const int t = threadIdx.x;
  const int lane = t & 63, wv = t >> 6;
  const int rsel = lane & 15, grp = lane >> 4, ksel = 8 * grp;
  const int qrow = qb + wv * 16;

  const size_t qoff = ((size_t)h2 * LQ + qrow + rsel) * 64 + ksel;
  bf16x8 aq0h = *(const bf16x8*)(qhi + qoff), aq1h = *(const bf16x8*)(qhi + qoff + 32);
  const u16* kh = khi + (size_t)h2 * LQ * 64;

  const int srow = t >> 2;
  const int scol = (t & 3) * 16;

  int qm[4];
  float Z[4] = {0.f, 0.f, 0.f, 0.f};
#pragma unroll
  for (int j = 0; j < 4; ++j) qm[j] = (qrow + grp * 4 + j) & 511;

  const int kbeg = s * 512;
  int buf = 0;
  for (int jt = 0; jt <= c; ++jt) {             // computed tiles only
    const int kt = kbeg + jt * 64;
    const size_t kb = (size_t)(kt + srow) * 64 + scol;
    uint4 r0 = *(const uint4*)(kh + kb);
    uint4 r1 = *(const uint4*)(kh + kb + 8);
    *(uint4*)&Kh[buf][srow][scol] = r0;
    *(uint4*)&Kh[buf][srow][scol + 8] = r1;
    __syncthreads();   // K tile ready (dbuf protects against next-tile WAR)
#pragma unroll
    for (int fk = 0; fk < 4; ++fk) {
      const int krow = fk * 16 + rsel;
      const int k = kt + krow;
      bf16x8 b0 = *(const bf16x8*)&Kh[buf][krow][ksel];
      bf16x8 b1 = *(const bf16x8*)&Kh[buf][krow][ksel + 32];
      f32x4 z = {};
      z = MFMA16(aq0h, b0, z);
      z = MFMA16(aq1h, b1, z);
#pragma unroll
      for (int j = 0; j < 4; ++j)
        if ((k & 511) <= qm[j]) Z[j] += __expf(fabsf(z[j] * SCALING));
    }
    buf ^= 1;
  }
#pragma unroll
  for (int j = 0; j < 4; ++j) {
#pragma unroll
    for (int off = 1; off < 16; off <<= 1) Z[j] += __shfl_xor(Z[j], off);
    if (rsel == 0) {
      int q = qrow + grp * 4 + j;
      zp[((size_t)(s * 32 + h2) << 11) + q] = Z[j];
    }
  }
}

// ---- attention PV: 1D grid 2048 heavy-first, one 512-segment per block ----
// K AND V tiles COOPERATIVELY staged in LDS (dedup across waves), async-stage
// split (next tile's loads issue under compute).
__global__ __launch_bounds__(256) void attn_pv_kernel(
    const u16* __restrict__ qhi, const u16* __restrict__ qlo,
    const u16* __restrict__ khi, const u16* __restrict__ klo,
    const u16* __restrict__ vt, const float* __restrict__ zp,
    const float* __restrict__ lamp,
    float* __restrict__ O0, float* __restrict__ O123, float* __restrict__ colsum) {
  __shared__ u16 KhA[64][72], KlA[64][72], KhB[64][72], KlB[64][72];
  __shared__ u16 Vs[64][72];
  __shared__ u16 pcLDS[4][16][72];
  __shared__ float csLDS[2][4][64];

  const int bid = blockIdx.x;
  const int c = 7 - (bid >> 8);                 // heavy-first
  const int r = bid & 255;
  const int h = r & 15;
  const int qtIdx = (r >> 4) & 3;
  const int s = r >> 6;                         // 0..3
  const int qt = qtIdx * 8 + c;
  const int qb = qt * 64;
  const int t = threadIdx.x;
  const int lane = t & 63, wv = t >> 6;
  const int rsel = lane & 15, grp = lane >> 4, ksel = 8 * grp;
  const int qrow = qb + wv * 16;
  const float lam = lamp[0];

  const int h2a = 2 * h, h2b = 2 * h + 1;
  const size_t qoffa = ((size_t)h2a * LQ + qrow + rsel) * 64 + ksel;
  const size_t qoffb = ((size_t)h2b * LQ + qrow + rsel) * 64 + ksel;
  bf16x8 aqa0h = *(const bf16x8*)(qhi + qoffa), aqa1h = *(const bf16x8*)(qhi + qoffa + 32);
  bf16x8 aqa0l = *(const bf16x8*)(qlo + qoffa), aqa1l = *(const bf16x8*)(qlo + qoffa + 32);
  bf16x8 aqb0h = *(const bf16x8*)(qhi + qoffb), aqb1h = *(const bf16x8*)(qhi + qoffb + 32);
  bf16x8 aqb0l = *(const bf16x8*)(qlo + qoffb), aqb1l = *(const bf16x8*)(qlo + qoffb + 32);
  const u16* kha = khi + (size_t)h2a * LQ * 64;
  const u16* kla = klo + (size_t)h2a * LQ * 64;
  const u16* khb = khi + (size_t)h2b * LQ * 64;
  const u16* klb = klo + (size_t)h2b * LQ * 64;
  const u16* vb = vt + (size_t)h * 64 * LQ;

  // cooperative staging coords: thread t covers row t>>2, 16 cols at (t&3)*16
  const int srow = t >> 2;
  const int scol = (t & 3) * 16;

  int qm[4];
  float iz1[4], iz2[4];
#pragma unroll
  for (int j = 0; j < 4; ++j) {
    int q = qrow + grp * 4 + j;
    qm[j] = q & 511;
    float z1 = 0.f, z2 = 0.f;
#pragma unroll
    for (int ss = 0; ss < 4; ++ss) {
      z1 += zp[((size_t)(ss * 32 + h2a) << 11) + q];
      z2 += zp[((size_t)(ss * 32 + h2b) << 11) + q];
    }
    iz1[j] = 1.f / z1;
    iz2[j] = 1.f / z2;
  }

  f32x4 accO[4] = {};
  const int kbeg = s * 512;
  int buf = 0;

  // zero colsum for skipped (fully-masked) tiles of this segment
  for (int jt = c + 1; jt < 8; ++jt) {
    if (t < 64) colsum[((size_t)h * 32 + qt) * LQ + kbeg + jt * 64 + t] = 0.f;
  }

  // prologue: load tile 0 into registers
  uint4 rha0, rha1, rla0, rla1, rhb0, rhb1, rlb0, rlb1, rv0, rv1;
  {
    const size_t kb = (size_t)(kbeg + srow) * 64 + scol;
    rha0 = *(const uint4*)(kha + kb);
    rha1 = *(const uint4*)(kha + kb + 8);
    rla0 = *(const uint4*)(kla + kb);
    rla1 = *(const uint4*)(kla + kb + 8);
    rhb0 = *(const uint4*)(khb + kb);
    rhb1 = *(const uint4*)(khb + kb + 8);
    rlb0 = *(const uint4*)(klb + kb);
    rlb1 = *(const uint4*)(klb + kb + 8);
    const u16* vsrc = vb + (size_t)srow * LQ + kbeg + scol;
    rv0 = *(const uint4*)(vsrc);
    rv1 = *(const uint4*)(vsrc + 8);
  }

  for (int jt = 0; jt <= c; ++jt) {
    const int kt = kbeg + jt * 64;

    // write prefetched tile to LDS
    // (prev tile's K/V-LDS reads are fenced by the csLDS barrier of tile jt-1)
    *(uint4*)&KhA[srow][scol] = rha0; *(uint4*)&KhA[srow][scol + 8] = rha1;
    *(uint4*)&KlA[srow][scol] = rla0; *(uint4*)&KlA[srow][scol + 8] = rla1;
    *(uint4*)&KhB[srow][scol] = rhb0; *(uint4*)&KhB[srow][scol + 8] = rhb1;
    *(uint4*)&KlB[srow][scol] = rlb0; *(uint4*)&KlB[srow][scol + 8] = rlb1;
    *(uint4*)&Vs[srow][scol] = rv0;  *(uint4*)&Vs[srow][scol + 8] = rv1;
    __syncthreads();   // K/V tile ready

    // ---- issue NEXT tile's global loads (latency hides under compute) ----
    if (jt < c) {
      const size_t kb = (size_t)(kt + 64 + srow) * 64 + scol;
      rha0 = *(const uint4*)(kha + kb);
      rha1 = *(const uint4*)(kha + kb + 8);
      rla0 = *(const uint4*)(kla + kb);
      rla1 = *(const uint4*)(kla + kb + 8);
      rhb0 = *(const uint4*)(khb + kb);
      rhb1 = *(const uint4*)(khb + kb + 8);
      rlb0 = *(const uint4*)(klb + kb);
      rlb1 = *(const uint4*)(klb + kb + 8);
      const u16* vsrc = vb + (size_t)srow * LQ + kt + 64 + scol;
      rv0 = *(const uint4*)(vsrc);
      rv1 = *(const uint4*)(vsrc + 8);
    }

    __builtin_amdgcn_s_setprio(1);
    float pc[4][4], cs[4];
#pragma unroll
    for (int fk = 0; fk < 4; ++fk) {
      const int krow = fk * 16 + rsel;
      const int k = kt + krow;
      f32x4 z = {};
      SCORE6(z, aqa0h, aqa1h, aqa0l, aqa1l, &KhA[krow][ksel], &KlA[krow][ksel]);
      f32x4 w = {};
      SCORE6(w, aqb0h, aqb1h, aqb0l, aqb1l, &KhB[krow][ksel], &KlB[krow][ksel]);
      float csj = 0.f;
#pragma unroll
      for (int j = 0; j < 4; ++j) {
        bool msk = ((k & 511) > qm[j]);
        float sa = z[j] * SCALING;
        float pa = __builtin_copysignf(__expf(fabsf(sa)) * iz1[j], sa);
        pa = msk ? 0.f : pa;
        csj += pa;
        float sb = w[j] * SCALING;
        float pb = __builtin_copysignf(__expf(fabsf(sb)) * iz2[j], sb);
        pc[fk][j] = pa - (msk ? 0.f : lam * pb);
      }
      cs[fk] = csj;
    }
    // pc relayout through OWN pcLDS slice (intra-wave, lgkmcnt-ordered)
#pragma unroll
    for (int fk = 0; fk < 4; ++fk)
#pragma unroll
      for (int j = 0; j < 4; ++j)
        pcLDS[wv][grp * 4 + j][fk * 16 + rsel] = f2b(pc[fk][j]);
    // PV (intra-wave; V read from LDS)
#pragma unroll
    for (int kc = 0; kc < 2; ++kc) {
      bf16x8 ap = *(const bf16x8*)&pcLDS[wv][rsel][kc * 32 + ksel];
#pragma unroll
      for (int fn = 0; fn < 4; ++fn) {
        bf16x8 bv = *(const bf16x8*)&Vs[fn * 16 + rsel][kc * 32 + ksel];
        accO[fn] = MFMA16(ap, bv, accO[fn]);
      }
    }
    __builtin_amdgcn_s_setprio(0);
    // cross-wave colsum (csLDS dbuf + barrier; barrier also fences K/V reads
    // of this tile before next tile's ds_writes)
#pragma unroll
    for (int fk = 0; fk < 4; ++fk) {
      float cc = cs[fk];
      cc += __shfl_xor(cc, 16);
      cc += __shfl_xor(cc, 32);
      if (grp == 0) csLDS[buf][wv][fk * 16 + rsel] = cc;
    }
    __syncthreads();
    if (t < 64) {
      float tot = csLDS[buf][0][t] + csLDS[buf][1][t] + csLDS[buf][2][t] + csLDS[buf][3][t];
      colsum[((size_t)h * 32 + qt) * LQ + kt + t] = tot;
    }
    buf ^= 1;
  }
  float* Op = (s == 0) ? O0 : (O123 + (size_t)(s - 1) * 16 * LQ * 64);
#pragma unroll
  for (int fn = 0; fn < 4; ++fn)
#pragma unroll
    for (int j = 0; j < 4; ++j) {
      int q = qrow + grp * 4 + j;
      int d = fn * 16 + rsel;
      Op[((size_t)h * LQ + q) * 64 + d] = accO[fn][j];
    }
}

// g[h][k] = sum_qt colsum[h][qt][k] / 2048
__global__ void g_reduce_kernel(const float* __restrict__ colsum, float* __restrict__ g) {
  int idx = blockIdx.x * 256 + threadIdx.x;
  if (idx >= 16 * LQ) return;
  int h = idx >> 11, k = idx & 2047;
  float s = 0.f;
#pragma unroll
  for (int qt = 0; qt < 32; ++qt) s += colsum[((size_t)h * 32 + qt) * LQ + k];
  g[idx] = s * (1.f / 2048.f);
}

// Gv[h][r][d] = sum_seg g[h][seg*512+r] * vt[h][d][seg*512+r]
__global__ void gv_kernel(const float* __restrict__ g, const u16* __restrict__ vt,
                          float* __restrict__ Gv) {
  int idx = blockIdx.x * 256 + threadIdx.x;
  if (idx >= 16 * 512 * 64) return;
  int d = idx & 63, r = (idx >> 6) & 511, h = idx >> 15;
  float s = 0.f;
#pragma unroll
  for (int seg = 0; seg < 4; ++seg) {
    int k = seg * 512 + r;
    s += g[h * 2048 + k] * b2f(vt[((size_t)h * 64 + d) * LQ + k]);
  }
  Gv[idx] = s;
}

// W[h][r][d] = inclusive prefix over r of Gv[h][r][d]
__global__ __launch_bounds__(512) void wscan_kernel(const float* __restrict__ Gv,
                                                    float* __restrict__ W) {
  __shared__ float s[512];
  int h = blockIdx.x >> 6, d = blockIdx.x & 63;
  int t = threadIdx.x;
  s[t] = Gv[((size_t)h * 512 + t) * 64 + d];
  __syncthreads();
  for (int off = 1; off < 512; off <<= 1) {
    float add = (t >= off) ? s[t - off] : 0.f;
    __syncthreads();
    s[t] += add;
    __syncthreads();
  }
  W[((size_t)h * 512 + t) * 64 + d] = s[t];
}

// out_pre = O0 + O1 + O2 + O3 + lam*W[q%512]; head rmsnorm -> bf16 [q][h*64+d]
__global__ __launch_bounds__(256) void combine_norm_kernel(
    const float* __restrict__ O0, const float* __restrict__ O123,
    const float* __restrict__ W, const float* __restrict__ hw,
    const float* __restrict__ lamp, u16* __restrict__ out) {
  const int q = blockIdx.x;
  const int h = blockIdx.y * 4 + (threadIdx.x >> 6);
  const int d = threadIdx.x & 63;
  const float lam = lamp[0];
  const size_t S = (size_t)16 * LQ * 64;
  const size_t idx = ((size_t)h * LQ + q) * 64 + d;
  float v = O0[idx] + O123[idx] + O123[idx + S] + O123[idx + 2 * S] +
            lam * W[((size_t)h * 512 + (q & 511)) * 64 + d];
  float ss = v * v;
#pragma unroll
  for (int off = 1; off < 64; off <<= 1) ss += __shfl_xor(ss, off);
  float sc = 1.f / sqrtf(ss * (1.f / 64.f) + 1e-5f);
  out[(size_t)q * 1024 + h * 64 + d] = f2b(v * sc * hw[d]);
}

// ============================== launch ==============================
extern "C" void kernel_launch(void* const* d_in, const int* in_sizes, int n_in,
                              void* d_out, int out_size, void* d_ws, size_t ws_size,
                              hipStream_t stream) {
  const float* x = (const float*)d_in[0];
  const float* freqs_r = (const float*)d_in[1];
  const float* freqs_i = (const float*)d_in[2];
  // d_in[3] = mask (recomputed analytically)
  const float* kv_down_w = (const float*)d_in[4];
  const float* q_down_w = (const float*)d_in[5];
  const float* kv_up_w = (const float*)d_in[6];
  const float* q_up_w = (const float*)d_in[7];
  const float* kv_norm_w = (const float*)d_in[8];
  const float* q_norm_w = (const float*)d_in[9];
  const float* o_w = (const float*)d_in[10];
  const float* lambda_q1 = (const float*)d_in[11];
  const float* lambda_k1 = (const float*)d_in[12];
  const float* lambda_q2 = (const float*)d_in[13];
  const float* lambda_k2 = (const float*)d_in[14];
  const float* head_norm_w = (const float*)d_in[15];
  const float* norm1_w = (const float*)d_in[16];
  const float* norm2_w = (const float*)d_in[17];
  const float* ff_in_w = (const float*)d_in[18];
  const float* ff_out_w = (const float*)d_in[19];
  float* out = (float*)d_out;
  char* ws = (char*)d_ws;

  // ---- weights region (persistent except down/up: dead after projections) ----
  const size_t WT_KVD_H = 0;                                  // 544x1024 bf16
  const size_t WT_KVD_L = WT_KVD_H + (size_t)544 * 1024 * 2;
  const size_t WT_QD_H  = WT_KVD_L + (size_t)544 * 1024 * 2;  // 512x1024
  const size_t WT_QD_L  = WT_QD_H + (size_t)512 * 1024 * 2;
  const size_t WT_KVU_H = WT_QD_L + (size_t)512 * 1024 * 2;   // 2048x512
  const size_t WT_KVU_L = WT_KVU_H + (size_t)2048 * 512 * 2;
  const size_t WT_QU_H  = WT_KVU_L + (size_t)2048 * 512 * 2;  // 1536x512
  const size_t WT_QU_L  = WT_QU_H + (size_t)1536 * 512 * 2;
  const size_t WT_OW    = WT_QU_L + (size_t)1536 * 512 * 2;   // = 11,714,560
  const size_t WT_FFI   = WT_OW + (size_t)1024 * 1024 * 2;
  const size_t WT_FFO   = WT_FFI + (size_t)8192 * 1024 * 2;
  const size_t A0 = WT_FFO + (size_t)1024 * 4096 * 2;         // = 38,928,384

  // ---- activations (lifetime-aliased) ----
  const size_t H     = A0;                  // h hi/lo bf16 (2x 4,194,304); dead after down-GEMMs
  const size_t CKV   = A0 + 8388608;        // f32 2048x544;  dead after build_kh
  const size_t CKVN  = A0 + 12845056;       // ckvn hi/lo bf16 (2x 2,097,152); dead after kv_up
  const size_t KVB   = A0 + 17039360;       // f32 2048x2048; dead after build_vt
  const size_t CQ    = A0 + 33816576;       // f32 2048x512;  dead after rmsnorm
  const size_t CQN   = A0 + 38010880;       // cqn hi/lo bf16 (2x 2,097,152); dead after q_up
  const size_t QFULL = A0 + 42205184;       // f32 2048x1536; dead after build_qh
  // mid buffers (aliases):
  const size_t QHI = H;                     // bf16 32x2048x64 over dead H
  const size_t KHI = QFULL;                 // bf16 32x2048x64 over dead QFULL[0:8.39M]
  const size_t KLO = A0 + 50593792;         // bf16 32x2048x64 over dead QFULL[8.39M:]+
  const size_t QLO = A0 + 58982400;         // bf16 32x2048x64
  const size_t VT  = CKVN;                  // bf16 16x64x2048 over dead CKVN
  // O partials (4 x 8,388,608 f32):
  const size_t OP0   = 0;                   // over dead down/up weights [0, 8.39M) < WT_OW
  const size_t OP123 = KVB;                 // 3 contiguous partials over dead KVB+CQ+CQN
  const size_t CS  = CKV;                   // f32 16x32x2048 over dead CKV
  const size_t GB  = A0 + 67371008;         // f32 16x2048 (131,072)
  const size_t GV  = A0 + 67502080;         // f32 16x512x64 (2,097,152)
  const size_t WB  = A0 + 69599232;         // f32 16x512x64 (2,097,152)
  const size_t LAM = A0 + 71696384;         // scalar
  const size_t ZP  = A0 + 71696640;         // f32 4x32x2048 (1,048,576)
  const size_t WS_END = A0 + 72745216;      // ~111.7 MB (known-safe)
  // late aliases:
  const size_t ATTN  = CKV;                 // bf16 2048x1024 (over consumed CS)
  const size_t X1    = KVB + 8388608;       // f32 2048x1024 (partials consumed by combine)
  const size_t H2N   = H;                   // bf16 2048x1024 over dead QHI
  const size_t FFACT = QFULL;               // bf16 2048x4096 over dead KHI+KLO

  if (ws_size < WS_END) return;

  u16* wt_kvd_h = (u16*)(ws + WT_KVD_H); u16* wt_kvd_l = (u16*)(ws + WT_KVD_L);
  u16* wt_qd_h  = (u16*)(ws + WT_QD_H);  u16* wt_qd_l  = (u16*)(ws + WT_QD_L);
  u16* wt_kvu_h = (u16*)(ws + WT_KVU_H); u16* wt_kvu_l = (u16*)(ws + WT_KVU_L);
  u16* wt_qu_h  = (u16*)(ws + WT_QU_H);  u16* wt_qu_l  = (u16*)(ws + WT_QU_L);
  u16* wt_ow  = (u16*)(ws + WT_OW);
  u16* wt_ffi = (u16*)(ws + WT_FFI);
  u16* wt_ffo = (u16*)(ws + WT_FFO);
  u16* h_hi   = (u16*)(ws + H);
  u16* h_lo   = (u16*)(ws + H + 4194304);
  float* ckv  = (float*)(ws + CKV);
  u16* ckvn_hi = (u16*)(ws + CKVN);
  u16* ckvn_lo = (u16*)(ws + CKVN + 2097152);
  float* kvb  = (float*)(ws + KVB);
  float* cq   = (float*)(ws + CQ);
  u16* cqn_hi = (u16*)(ws + CQN);
  u16* cqn_lo = (u16*)(ws + CQN + 2097152);
  float* qfull = (float*)(ws + QFULL);
  u16* qhib = (u16*)(ws + QHI); u16* qlob = (u16*)(ws + QLO);
  u16* khib = (u16*)(ws + KHI); u16* klob = (u16*)(ws + KLO);
  u16* vtb  = (u16*)(ws + VT);
  float* zpb = (float*)(ws + ZP);
  float* Op0 = (float*)(ws + OP0);
  float* Op123 = (float*)(ws + OP123);
  float* csb = (float*)(ws + CS);
  float* gb  = (float*)(ws + GB);
  float* gvb = (float*)(ws + GV);
  float* wbb = (float*)(ws + WB);
  float* lamp = (float*)(ws + LAM);
  u16* attn_n = (u16*)(ws + ATTN);
  float* x1 = (float*)(ws + X1);
  u16* h2n = (u16*)(ws + H2N);
  u16* ffact = (u16*)(ws + FFACT);

  // fused weight prep (7 transposes -> 1 kernel; 16160 blocks of 32x8)
  prep_weights_kernel<<<16160, dim3(32, 8), 0, stream>>>(
      kv_down_w, wt_kvd_h, wt_kvd_l, q_down_w, wt_qd_h, wt_qd_l,
      kv_up_w, wt_kvu_h, wt_kvu_l, q_up_w, wt_qu_h, wt_qu_l,
      o_w, wt_ow, ff_in_w, wt_ffi, ff_out_w, wt_ffo);

  rmsnorm_split_kernel<<<2048, 256, 0, stream>>>(x, norm1_w, h_hi, h_lo, 1024, 1024, FEPS);
  gemm_split<<<dim3(9, 32), 256, 0, stream>>>(h_hi, h_lo, wt_kvd_h, wt_kvd_l, ckv,
                                              2048, 544, 1024);
  rmsnorm_split_kernel<<<2048, 256, 0, stream>>>(ckv, kv_norm_w, ckvn_hi, ckvn_lo,
                                                 512, 544, FEPS);
  gemm_split<<<dim3(32, 32), 256, 0, stream>>>(ckvn_hi, ckvn_lo, wt_kvu_h, wt_kvu_l, kvb,
                                               2048, 2048, 512);
  gemm_split<<<dim3(8, 32), 256, 0, stream>>>(h_hi, h_lo, wt_qd_h, wt_qd_l, cq,
                                              2048, 512, 1024);
  rmsnorm_split_kernel<<<2048, 256, 0, stream>>>(cq, q_norm_w, cqn_hi, cqn_lo,
                                                 512, 512, FEPS);
  gemm_split<<<dim3(24, 32), 256, 0, stream>>>(cqn_hi, cqn_lo, wt_qu_h, wt_qu_l, qfull,
                                               2048, 1536, 512);

  // fused mid build (build_qh + build_kh + build_vt + lam -> 1 kernel)
  build_mid_kernel<<<33281, 256, 0, stream>>>(qfull, kvb, ckv, freqs_r, freqs_i,
                                              qhib, qlob, khib, klob, vtb,
                                              lambda_q1, lambda_k1, lambda_q2, lambda_k2,
                                              lamp);

  attn_z_kernel<<<4096, 256, 0, stream>>>(qhib, khib, zpb);
  attn_pv_kernel<<<2048, 256, 0, stream>>>(qhib, qlob, khib, klob, vtb, zpb,
                                           lamp, Op0, Op123, csb);

  g_reduce_kernel<<<128, 256, 0, stream>>>(csb, gb);
  gv_kernel<<<2048, 256, 0, stream>>>(gb, vtb, gvb);
  wscan_kernel<<<1024, 512, 0, stream>>>(gvb, wbb);
  combine_norm_kernel<<<dim3(2048, 4), 256, 0, stream>>>(Op0, Op123, wbb, head_norm_w,
                                                         lamp, attn_n);

  // x1 = x + attn_n @ o_w  (residual fused into epilogue)
  gemm_kernel<0, 1><<<dim3(16, 32), 256, 0, stream>>>(attn_n, wt_ow, x, x1, nullptr,
                                                      2048, 1024, 1024);
  rmsnorm_kernel<1><<<2048, 256, 0, stream>>>(x1, norm2_w, h2n, 1024, 1024, FEPS);
  gemm_kernel<1, 0><<<dim3(64, 32), 256, 0, stream>>>(h2n, wt_ffi, nullptr, nullptr, ffact,
                                                      2048, 4096, 1024);
  // out = x1 + ffact @ ff_out  (residual fused into epilogue)
  gemm_kernel<0, 1><<<dim3(16, 32), 256, 0, stream>>>(ffact, wt_ffo, x1, out, nullptr,
                                                      2048, 1024, 4096);
}

// Round 25
// 355.456 us; speedup vs baseline: 1.1453x; 1.0363x over previous
//
#include <hip/hip_runtime.h>
#include <math.h>

#define LQ 2048
#define SCALING 0.14433756729740643f   // 48^-0.5
#define FEPS 1.1920928955078125e-07f   // np.finfo(float32).eps

typedef unsigned short u16;
typedef __attribute__((ext_vector_type(8))) short bf16x8;
typedef __attribute__((ext_vector_type(4))) float f32x4;

#define MFMA16(a, b, c) __builtin_amdgcn_mfma_f32_16x16x32_bf16((a), (b), (c), 0, 0, 0)

__device__ __forceinline__ u16 f2b(float x) {
  union { float f; unsigned u; } v; v.f = x;
  return (u16)((v.u + 0x7FFFu + ((v.u >> 16) & 1u)) >> 16);
}
__device__ __forceinline__ float b2f(u16 b) {
  union { unsigned u; float f; } v; v.u = ((unsigned)b) << 16;
  return v.f;
}

// ---- fused weight prep: all 7 transposes in one kernel (flat-grid segments). ----
__global__ __launch_bounds__(256) void prep_weights_kernel(
    const float* __restrict__ kvd, u16* __restrict__ kvd_h, u16* __restrict__ kvd_l,
    const float* __restrict__ qd,  u16* __restrict__ qd_h,  u16* __restrict__ qd_l,
    const float* __restrict__ kvu, u16* __restrict__ kvu_h, u16* __restrict__ kvu_l,
    const float* __restrict__ qu,  u16* __restrict__ qu_h,  u16* __restrict__ qu_l,
    const float* __restrict__ ow,  u16* __restrict__ ow_t,
    const float* __restrict__ ffi, u16* __restrict__ ffi_t,
    const float* __restrict__ ffo, u16* __restrict__ ffo_t) {
  __shared__ float tile[32][33];
  int id = blockIdx.x;
  const float* W; u16* Whi; u16* Wlo = nullptr; int K, N, bx, by;
  if (id < 8192) {                       // ff_in 1024x8192 (heaviest first)
    W = ffi; Whi = ffi_t; K = 1024; N = 8192; bx = id % 256; by = id / 256;
  } else if (id < 8192 + 4096) {         // ff_out 4096x1024
    id -= 8192;
    W = ffo; Whi = ffo_t; K = 4096; N = 1024; bx = id % 32; by = id / 32;
  } else if (id < 12288 + 1024) {        // o_w 1024x1024
    id -= 12288;
    W = ow; Whi = ow_t; K = 1024; N = 1024; bx = id % 32; by = id / 32;
  } else if (id < 13312 + 544) {         // kv_down 1024x544 (split)
    id -= 13312;
    W = kvd; Whi = kvd_h; Wlo = kvd_l; K = 1024; N = 544; bx = id % 17; by = id / 17;
  } else if (id < 13856 + 512) {         // q_down 1024x512 (split)
    id -= 13856;
    W = qd; Whi = qd_h; Wlo = qd_l; K = 1024; N = 512; bx = id % 16; by = id / 16;
  } else if (id < 14368 + 1024) {        // kv_up 512x2048 (split)
    id -= 14368;
    W = kvu; Whi = kvu_h; Wlo = kvu_l; K = 512; N = 2048; bx = id % 64; by = id / 64;
  } else {                               // q_up 512x1536 (split)
    id -= 15392;
    W = qu; Whi = qu_h; Wlo = qu_l; K = 512; N = 1536; bx = id % 48; by = id / 48;
  }

  int n0 = bx * 32, k0 = by * 32;
  int tx = threadIdx.x, ty = threadIdx.y;  // 32 x 8
  for (int i = ty; i < 32; i += 8) {
    int k = k0 + i, n = n0 + tx;
    tile[i][tx] = (k < K && n < N) ? W[(size_t)k * N + n] : 0.f;
  }
  __syncthreads();
  for (int i = ty; i < 32; i += 8) {
    int n = n0 + i, k = k0 + tx;
    if (n < N && k < K) {
      float xv = tile[tx][i];
      u16 hi = f2b(xv);
      Whi[(size_t)n * K + k] = hi;
      if (Wlo) Wlo[(size_t)n * K + k] = f2b(xv - b2f(hi));
    }
  }
}

// ---------------- rmsnorm fp32 in (strided) -> fp32 or bf16 out ----------------
template <int BF16OUT>
__global__ __launch_bounds__(256) void rmsnorm_kernel(
    const float* __restrict__ x, const float* __restrict__ w, void* __restrict__ outv,
    int cols, int in_stride, float eps) {
  const int row = blockIdx.x;
  const float* xr = x + (size_t)row * in_stride;
  float ss = 0.f;
  for (int c = threadIdx.x; c < cols; c += 256) { float v = xr[c]; ss = fmaf(v, v, ss); }
#pragma unroll
  for (int off = 32; off > 0; off >>= 1) ss += __shfl_xor(ss, off);
  __shared__ float red[4];
  if ((threadIdx.x & 63) == 0) red[threadIdx.x >> 6] = ss;
  __syncthreads();
  float tot = red[0] + red[1] + red[2] + red[3];
  float sc = 1.f / sqrtf(tot / (float)cols + eps);
  for (int c = threadIdx.x; c < cols; c += 256) {
    float v = xr[c] * sc * w[c];
    if (BF16OUT) ((u16*)outv)[(size_t)row * cols + c] = f2b(v);
    else ((float*)outv)[(size_t)row * cols + c] = v;
  }
}

// ---- rmsnorm fp32 in (strided) -> hi/lo bf16 out (split once, reused by gemm) ----
__global__ __launch_bounds__(256) void rmsnorm_split_kernel(
    const float* __restrict__ x, const float* __restrict__ w,
    u16* __restrict__ hi_out, u16* __restrict__ lo_out,
    int cols, int in_stride, float eps) {
  const int row = blockIdx.x;
  const float* xr = x + (size_t)row * in_stride;
  float ss = 0.f;
  for (int c = threadIdx.x; c < cols; c += 256) { float v = xr[c]; ss = fmaf(v, v, ss); }
#pragma unroll
  for (int off = 32; off > 0; off >>= 1) ss += __shfl_xor(ss, off);
  __shared__ float red[4];
  if ((threadIdx.x & 63) == 0) red[threadIdx.x >> 6] = ss;
  __syncthreads();
  float tot = red[0] + red[1] + red[2] + red[3];
  float sc = 1.f / sqrtf(tot / (float)cols + eps);
  for (int c = threadIdx.x; c < cols; c += 256) {
    float v = xr[c] * sc * w[c];
    u16 hi = f2b(v);
    hi_out[(size_t)row * cols + c] = hi;
    lo_out[(size_t)row * cols + c] = f2b(v - b2f(hi));
  }
}

// ---- fused pair: rmsnorm_split for ckv (cols 512, stride 544) + cq (512/512) ----
__global__ __launch_bounds__(256) void rmsnorm_split2_kernel(
    const float* __restrict__ in0, const float* __restrict__ w0,
    u16* __restrict__ hi0, u16* __restrict__ lo0, int stride0,
    const float* __restrict__ in1, const float* __restrict__ w1,
    u16* __restrict__ hi1, u16* __restrict__ lo1, int stride1) {
  int row = blockIdx.x;
  const float* xr; const float* w; u16* ho; u16* lo;
  if (row < 2048) {
    xr = in0 + (size_t)row * stride0; w = w0;
    ho = hi0 + (size_t)row * 512; lo = lo0 + (size_t)row * 512;
  } else {
    row -= 2048;
    xr = in1 + (size_t)row * stride1; w = w1;
    ho = hi1 + (size_t)row * 512; lo = lo1 + (size_t)row * 512;
  }
  float ss = 0.f;
  for (int c = threadIdx.x; c < 512; c += 256) { float v = xr[c]; ss = fmaf(v, v, ss); }
#pragma unroll
  for (int off = 32; off > 0; off >>= 1) ss += __shfl_xor(ss, off);
  __shared__ float red[4];
  if ((threadIdx.x & 63) == 0) red[threadIdx.x >> 6] = ss;
  __syncthreads();
  float tot = red[0] + red[1] + red[2] + red[3];
  float sc = 1.f / sqrtf(tot / 512.f + FEPS);
  for (int c = threadIdx.x; c < 512; c += 256) {
    float v = xr[c] * sc * w[c];
    u16 hi = f2b(v);
    ho[c] = hi;
    lo[c] = f2b(v - b2f(hi));
  }
}

// ---- split-precision GEMM (3-term), all-bf16 staging ----
__global__ __launch_bounds__(256) void gemm_split(
    const u16* __restrict__ Ahi, const u16* __restrict__ Alo,
    const u16* __restrict__ Bhi, const u16* __restrict__ Blo,
    float* __restrict__ C, int M, int N, int K) {
  __shared__ u16 Ah[64][72];
  __shared__ u16 Al[64][72];
  __shared__ u16 Bh[64][72];
  __shared__ u16 Bl[64][72];

  const int t = threadIdx.x;
  const int lane = t & 63;
  const int wv = t >> 6;
  const int wr = (wv >> 1) * 32;
  const int wc = (wv & 1) * 32;
  const int bm = blockIdx.y * 64;
  const int bn = blockIdx.x * 64;
  const int lr = t >> 2;
  const int lc = (t & 3) * 16;
  const int rsel = lane & 15;
  const int ksel = 8 * (lane >> 4);

  const u16* Ahrow = Ahi + (size_t)(bm + lr) * K + lc;
  const u16* Alrow = Alo + (size_t)(bm + lr) * K + lc;
  const bool bval = (bn + lr) < N;
  const u16* Bhrow = Bhi + (size_t)(bn + lr) * K + lc;
  const u16* Blrow = Blo + (size_t)(bn + lr) * K + lc;

  f32x4 acc[2][2] = {};

  for (int kt = 0; kt < K; kt += 64) {
    uint4 ah0 = *(const uint4*)(Ahrow + kt);
    uint4 ah1 = *(const uint4*)(Ahrow + kt + 8);
    uint4 al0 = *(const uint4*)(Alrow + kt);
    uint4 al1 = *(const uint4*)(Alrow + kt + 8);
    uint4 bh0 = {0, 0, 0, 0}, bh1 = {0, 0, 0, 0}, bl0 = {0, 0, 0, 0}, bl1 = {0, 0, 0, 0};
    if (bval) {
      bh0 = *(const uint4*)(Bhrow + kt); bh1 = *(const uint4*)(Bhrow + kt + 8);
      bl0 = *(const uint4*)(Blrow + kt); bl1 = *(const uint4*)(Blrow + kt + 8);
    }
    __syncthreads();
    *(uint4*)&Ah[lr][lc] = ah0; *(uint4*)&Ah[lr][lc + 8] = ah1;
    *(uint4*)&Al[lr][lc] = al0; *(uint4*)&Al[lr][lc + 8] = al1;
    *(uint4*)&Bh[lr][lc] = bh0; *(uint4*)&Bh[lr][lc + 8] = bh1;
    *(uint4*)&Bl[lr][lc] = bl0; *(uint4*)&Bl[lr][lc + 8] = bl1;
    __syncthreads();
#pragma unroll
    for (int ks = 0; ks < 2; ++ks) {
      const int ko = ks * 32 + ksel;
      bf16x8 a0h = *(const bf16x8*)&Ah[wr + rsel][ko];
      bf16x8 a1h = *(const bf16x8*)&Ah[wr + 16 + rsel][ko];
      bf16x8 a0l = *(const bf16x8*)&Al[wr + rsel][ko];
      bf16x8 a1l = *(const bf16x8*)&Al[wr + 16 + rsel][ko];
      bf16x8 b0h = *(const bf16x8*)&Bh[wc + rsel][ko];
      bf16x8 b1h = *(const bf16x8*)&Bh[wc + 16 + rsel][ko];
      bf16x8 b0l = *(const bf16x8*)&Bl[wc + rsel][ko];
      bf16x8 b1l = *(const bf16x8*)&Bl[wc + 16 + rsel][ko];
      acc[0][0] = MFMA16(a0h, b0h, acc[0][0]);
      acc[0][0] = MFMA16(a0h, b0l, acc[0][0]);
      acc[0][0] = MFMA16(a0l, b0h, acc[0][0]);
      acc[0][1] = MFMA16(a0h, b1h, acc[0][1]);
      acc[0][1] = MFMA16(a0h, b1l, acc[0][1]);
      acc[0][1] = MFMA16(a0l, b1h, acc[0][1]);
      acc[1][0] = MFMA16(a1h, b0h, acc[1][0]);
      acc[1][0] = MFMA16(a1h, b0l, acc[1][0]);
      acc[1][0] = MFMA16(a1l, b0h, acc[1][0]);
      acc[1][1] = MFMA16(a1h, b1h, acc[1][1]);
      acc[1][1] = MFMA16(a1h, b1l, acc[1][1]);
      acc[1][1] = MFMA16(a1l, b1h, acc[1][1]);
    }
  }
  const int r0 = (lane >> 4) * 4;
#pragma unroll
  for (int fm = 0; fm < 2; ++fm)
#pragma unroll
    for (int fn = 0; fn < 2; ++fn)
#pragma unroll
      for (int j = 0; j < 4; ++j) {
        int row = bm + wr + fm * 16 + r0 + j;
        int col = bn + wc + fn * 16 + rsel;
        if (col < N) C[(size_t)row * N + col] = acc[fm][fn][j];
      }
}

// ---- plain bf16 GEMM (o_w / FFN): 64x64 reg-staged. ADDX fuses residual add. ----
template <int GATED, int ADDX>
__global__ __launch_bounds__(256) void gemm_kernel(
    const u16* __restrict__ A, const u16* __restrict__ Bt, const float* __restrict__ X,
    float* __restrict__ C, u16* __restrict__ Cg, int M, int N, int K) {
  __shared__ u16 As[64][72];
  __shared__ u16 Bs[64][72];
  __shared__ u16 Bs2[GATED ? 64 : 1][72];

  const int t = threadIdx.x;
  const int lane = t & 63;
  const int wv = t >> 6;
  const int wr = (wv >> 1) * 32;
  const int wc = (wv & 1) * 32;
  const int bm = blockIdx.y * 64;
  const int bn = blockIdx.x * 64;
  const int lr = t >> 2;
  const int lc = (t & 3) * 16;
  const int rsel = lane & 15;
  const int ksel = 8 * (lane >> 4);

  const u16* Arow = A + (size_t)(bm + lr) * K + lc;
  const u16* Brow = Bt + (size_t)(bn + lr) * K + lc;
  const u16* Brow2 = Bt + (size_t)(4096 + bn + lr) * K + lc;

  f32x4 acc[2][2] = {};
  f32x4 accg[2][2] = {};

  for (int kt = 0; kt < K; kt += 64) {
    uint4 a0 = *(const uint4*)(Arow + kt);
    uint4 a1 = *(const uint4*)(Arow + kt + 8);
    uint4 b0 = *(const uint4*)(Brow + kt);
    uint4 b1 = *(const uint4*)(Brow + kt + 8);
    uint4 c0 = {0, 0, 0, 0}, c1 = {0, 0, 0, 0};
    if (GATED) { c0 = *(const uint4*)(Brow2 + kt); c1 = *(const uint4*)(Brow2 + kt + 8); }
    __syncthreads();
    *(uint4*)&As[lr][lc] = a0; *(uint4*)&As[lr][lc + 8] = a1;
    *(uint4*)&Bs[lr][lc] = b0; *(uint4*)&Bs[lr][lc + 8] = b1;
    if (GATED) { *(uint4*)&Bs2[lr][lc] = c0; *(uint4*)&Bs2[lr][lc + 8] = c1; }
    __syncthreads();
#pragma unroll
    for (int ks = 0; ks < 2; ++ks) {
      const int ko = ks * 32 + ksel;
      bf16x8 af0 = *(const bf16x8*)&As[wr + rsel][ko];
      bf16x8 af1 = *(const bf16x8*)&As[wr + 16 + rsel][ko];
      bf16x8 bf0 = *(const bf16x8*)&Bs[wc + rsel][ko];
      bf16x8 bf1 = *(const bf16x8*)&Bs[wc + 16 + rsel][ko];
      acc[0][0] = MFMA16(af0, bf0, acc[0][0]);
      acc[0][1] = MFMA16(af0, bf1, acc[0][1]);
      acc[1][0] = MFMA16(af1, bf0, acc[1][0]);
      acc[1][1] = MFMA16(af1, bf1, acc[1][1]);
      if (GATED) {
        bf16x8 cf0 = *(const bf16x8*)&Bs2[wc + rsel][ko];
        bf16x8 cf1 = *(const bf16x8*)&Bs2[wc + 16 + rsel][ko];
        accg[0][0] = MFMA16(af0, cf0, accg[0][0]);
        accg[0][1] = MFMA16(af0, cf1, accg[0][1]);
        accg[1][0] = MFMA16(af1, cf0, accg[1][0]);
        accg[1][1] = MFMA16(af1, cf1, accg[1][1]);
      }
    }
  }
  const int r0 = (lane >> 4) * 4;
#pragma unroll
  for (int fm = 0; fm < 2; ++fm)
#pragma unroll
    for (int fn = 0; fn < 2; ++fn)
#pragma unroll
      for (int j = 0; j < 4; ++j) {
        int row = bm + wr + fm * 16 + r0 + j;
        int col = bn + wc + fn * 16 + rsel;
        size_t o = (size_t)row * N + col;
        if (!GATED) {
          float v = acc[fm][fn][j];
          if (ADDX) v += X[o];
          C[o] = v;
        } else {
          float u = acc[fm][fn][j], g = accg[fm][fn][j];
          float sv = g / (1.f + __expf(-g));
          Cg[o] = f2b(u * sv);
        }
      }
}

// ---- fused mid build: build_qh + build_kh + build_vt + lam in one kernel ----
__global__ __launch_bounds__(256) void build_mid_kernel(
    const float* __restrict__ qfull, const float* __restrict__ kv,
    const float* __restrict__ ckv, const float* __restrict__ fr,
    const float* __restrict__ fi, u16* __restrict__ qhi, u16* __restrict__ qlo,
    u16* __restrict__ khi, u16* __restrict__ klo, u16* __restrict__ vt,
    const float* __restrict__ lq1, const float* __restrict__ lk1,
    const float* __restrict__ lq2, const float* __restrict__ lk2,
    float* __restrict__ lamp) {
  __shared__ u16 tile[64][65];
  int id = blockIdx.x;
  if (id < 16384) {
    // ---- build_qh ----
    const int q = id & 2047;
    const int h2 = ((id >> 11) << 2) + (threadIdx.x >> 6);
    const int d = threadIdx.x & 63;
    const int hh = h2 >> 1, s = h2 & 1;
    const float* row = qfull + (size_t)q * 1536 + hh * 96;
    float val;
    if (d < 32) {
      val = row[s * 32 + d];
    } else if (d < 48) {
      int r = d - 32;
      int pos = q & 511;
      const float* rp = row + 64 + s * 16;
      if (pos == 0) val = rp[r];
      else {
        int j = r >> 1;
        float cr = fr[(pos - 1) * 8 + j], ci = fi[(pos - 1) * 8 + j];
        float a = rp[2 * j], b = rp[2 * j + 1];
        val = (r & 1) ? (a * ci + b * cr) : (a * cr - b * ci);
      }
    } else val = 0.f;
    u16 hi = f2b(val);
    qhi[((size_t)h2 * LQ + q) * 64 + d] = hi;
    qlo[((size_t)h2 * LQ + q) * 64 + d] = f2b(val - b2f(hi));
    return;
  }
  id -= 16384;
  if (id < 16384) {
    // ---- build_kh ----
    const int kp = id & 2047;
    const int h2 = ((id >> 11) << 2) + (threadIdx.x >> 6);
    const int d = threadIdx.x & 63;
    const int hh = h2 >> 1, s = h2 & 1;
    float val;
    if (d < 32) {
      val = kv[(size_t)kp * 2048 + hh * 128 + s * 32 + d];
    } else if (d < 48) {
      int r = d - 32;
      int pos = kp & 511;
      const float* rp = ckv + (size_t)kp * 544 + 512 + s * 16;
      if (pos == 0) val = rp[r];
      else {
        int j = r >> 1;
        float cr = fr[(pos - 1) * 8 + j], ci = fi[(pos - 1) * 8 + j];
        float a = rp[2 * j], b = rp[2 * j + 1];
        val = (r & 1) ? (a * ci + b * cr) : (a * cr - b * ci);
      }
    } else val = 0.f;
    u16 hi = f2b(val);
    khi[((size_t)h2 * LQ + kp) * 64 + d] = hi;
    klo[((size_t)h2 * LQ + kp) * 64 + d] = f2b(val - b2f(hi));
    return;
  }
  id -= 16384;
  if (id < 512) {
    // ---- build_vt: vt[h][d][k] = bf16(kv[k][h*128+64+d]) ----
    int h = id >> 5, k0 = (id & 31) * 64;
    int t = threadIdx.x;
    int d = t & 63, kr = t >> 6;
#pragma unroll
    for (int i = 0; i < 16; ++i) {
      int k = kr + i * 4;
      tile[k][d] = f2b(kv[(size_t)(k0 + k) * 2048 + h * 128 + 64 + d]);
    }
    __syncthreads();
    int kk = t & 63, dr = t >> 6;
#pragma unroll
    for (int i = 0; i < 16; ++i) {
      int d2 = dr + i * 4;
      vt[((size_t)h * 64 + d2) * LQ + k0 + kk] = tile[kk][d2];
    }
    return;
  }
  // ---- lam = exp(sum(lk1*lq1)) - exp(sum(lk2*lq2)) + 0.2 ----
  int t = threadIdx.x;
  if (t < 32) {
    float a = lq1[t] * lk1[t], b = lq2[t] * lk2[t];
#pragma unroll
    for (int off = 1; off < 32; off <<= 1) { a += __shfl_xor(a, off); b += __shfl_xor(b, off); }
    if (t == 0) lamp[0] = expf(a) - expf(b) + 0.2f;
  }
}

// 6-MFMA split-precision 16x16 score tile
#define SCORE6(z, a0h, a1h, a0l, a1l, ph, pl)                         \
  {                                                                   \
    bf16x8 bh0 = *(const bf16x8*)(ph), bh1 = *(const bf16x8*)((ph) + 32); \
    bf16x8 bl0 = *(const bf16x8*)(pl), bl1 = *(const bf16x8*)((pl) + 32); \
    z = MFMA16(a0h, bh0, z); z = MFMA16(a1h, bh1, z);                 \
    z = MFMA16(a0h, bl0, z); z = MFMA16(a1h, bl1, z);                 \
    z = MFMA16(a0l, bh0, z); z = MFMA16(a1l, bh1, z);                 \
  }

// ---- attention Z: zp[s][h2][q] = sum over k-segment s of exp|a| (s = 0..3) ----
// K tiles COOPERATIVELY staged in dbuf LDS (dedup across 4 waves).
__global__ __launch_bounds__(256) void attn_z_kernel(
    const u16* __restrict__ qhi, const u16* __restrict__ khi,
    float* __restrict__ zp) {
  __shared__ u16 Kh[2][64][72];

  const int bid = blockIdx.x;
  const int c = 7 - (bid >> 9);                 // heavy-first
  const int r = bid & 511;
  const int h2 = r & 31;
  const int qtIdx = (r >> 5) & 3;
  const int s = r >> 7;                         // 0..3
  const int qt = qtIdx * 8 + c;
  const int qb = qt * 64;
  const int t = threadIdx.x;
  const int lane = t & 63, wv = t >> 6;
  const int rsel = lane & 15, grp = lane >> 4, ksel = 8 * grp;
  const int qrow = qb + wv * 16;

  const size_t qoff = ((size_t)h2 * LQ + qrow + rsel) * 64 + ksel;
  bf16x8 aq0h = *(const bf16x8*)(qhi + qoff), aq1h = *(const bf16x8*)(qhi + qoff + 32);
  const u16* kh = khi + (size_t)h2 * LQ * 64;

  const int srow = t >> 2;
  const int scol = (t & 3) * 16;

  int qm[4];
  float Z[4] = {0.f, 0.f, 0.f, 0.f};
#pragma unroll
  for (int j = 0; j < 4; ++j) qm[j] = (qrow + grp * 4 + j) & 511;

  const int kbeg = s * 512;
  int buf = 0;
  for (int jt = 0; jt <= c; ++jt) {             // computed tiles only
    const int kt = kbeg + jt * 64;
    const size_t kb = (size_t)(kt + srow) * 64 + scol;
    uint4 r0 = *(const uint4*)(kh + kb);
    uint4 r1 = *(const uint4*)(kh + kb + 8);
    *(uint4*)&Kh[buf][srow][scol] = r0;
    *(uint4*)&Kh[buf][srow][scol + 8] = r1;
    __syncthreads();   // K tile ready (dbuf protects against next-tile WAR)
#pragma unroll
    for (int fk = 0; fk < 4; ++fk) {
      const int krow = fk * 16 + rsel;
      const int k = kt + krow;
      bf16x8 b0 = *(const bf16x8*)&Kh[buf][krow][ksel];
      bf16x8 b1 = *(const bf16x8*)&Kh[buf][krow][ksel + 32];
      f32x4 z = {};
      z = MFMA16(aq0h, b0, z);
      z = MFMA16(aq1h, b1, z);
#pragma unroll
      for (int j = 0; j < 4; ++j)
        if ((k & 511) <= qm[j]) Z[j] += __expf(fabsf(z[j] * SCALING));
    }
    buf ^= 1;
  }
#pragma unroll
  for (int j = 0; j < 4; ++j) {
#pragma unroll
    for (int off = 1; off < 16; off <<= 1) Z[j] += __shfl_xor(Z[j], off);
    if (rsel == 0) {
      int q = qrow + grp * 4 + j;
      zp[((size_t)(s * 32 + h2) << 11) + q] = Z[j];
    }
  }
}

// ---- attention PV: 1D grid 2048 heavy-first, one 512-segment per block ----
// K AND V tiles COOPERATIVELY staged in LDS (dedup across waves), async-stage
// split (next tile's loads issue under compute).
__global__ __launch_bounds__(256) void attn_pv_kernel(
    const u16* __restrict__ qhi, const u16* __restrict__ qlo,
    const u16* __restrict__ khi, const u16* __restrict__ klo,
    const u16* __restrict__ vt, const float* __restrict__ zp,
    const float* __restrict__ lamp,
    float* __restrict__ O0, float* __restrict__ O123, float* __restrict__ colsum) {
  __shared__ u16 KhA[64][72], KlA[64][72], KhB[64][72], KlB[64][72];
  __shared__ u16 Vs[64][72];
  __shared__ u16 pcLDS[4][16][72];
  __shared__ float csLDS[2][4][64];

  const int bid = blockIdx.x;
  const int c = 7 - (bid >> 8);                 // heavy-first
  const int r = bid & 255;
  const int h = r & 15;
  const int qtIdx = (r >> 4) & 3;
  const int s = r >> 6;                         // 0..3
  const int qt = qtIdx * 8 + c;
  const int qb = qt * 64;
  const int t = threadIdx.x;
  const int lane = t & 63, wv = t >> 6;
  const int rsel = lane & 15, grp = lane >> 4, ksel = 8 * grp;
  const int qrow = qb + wv * 16;
  const float lam = lamp[0];

  const int h2a = 2 * h, h2b = 2 * h + 1;
  const size_t qoffa = ((size_t)h2a * LQ + qrow + rsel) * 64 + ksel;
  const size_t qoffb = ((size_t)h2b * LQ + qrow + rsel) * 64 + ksel;
  bf16x8 aqa0h = *(const bf16x8*)(qhi + qoffa), aqa1h = *(const bf16x8*)(qhi + qoffa + 32);
  bf16x8 aqa0l = *(const bf16x8*)(qlo + qoffa), aqa1l = *(const bf16x8*)(qlo + qoffa + 32);
  bf16x8 aqb0h = *(const bf16x8*)(qhi + qoffb), aqb1h = *(const bf16x8*)(qhi + qoffb + 32);
  bf16x8 aqb0l = *(const bf16x8*)(qlo + qoffb), aqb1l = *(const bf16x8*)(qlo + qoffb + 32);
  const u16* kha = khi + (size_t)h2a * LQ * 64;
  const u16* kla = klo + (size_t)h2a * LQ * 64;
  const u16* khb = khi + (size_t)h2b * LQ * 64;
  const u16* klb = klo + (size_t)h2b * LQ * 64;
  const u16* vb = vt + (size_t)h * 64 * LQ;

  // cooperative staging coords: thread t covers row t>>2, 16 cols at (t&3)*16
  const int srow = t >> 2;
  const int scol = (t & 3) * 16;

  int qm[4];
  float iz1[4], iz2[4];
#pragma unroll
  for (int j = 0; j < 4; ++j) {
    int q = qrow + grp * 4 + j;
    qm[j] = q & 511;
    float z1 = 0.f, z2 = 0.f;
#pragma unroll
    for (int ss = 0; ss < 4; ++ss) {
      z1 += zp[((size_t)(ss * 32 + h2a) << 11) + q];
      z2 += zp[((size_t)(ss * 32 + h2b) << 11) + q];
    }
    iz1[j] = 1.f / z1;
    iz2[j] = 1.f / z2;
  }

  f32x4 accO[4] = {};
  const int kbeg = s * 512;
  int buf = 0;

  // zero colsum for skipped (fully-masked) tiles of this segment
  for (int jt = c + 1; jt < 8; ++jt) {
    if (t < 64) colsum[((size_t)h * 32 + qt) * LQ + kbeg + jt * 64 + t] = 0.f;
  }

  // prologue: load tile 0 into registers
  uint4 rha0, rha1, rla0, rla1, rhb0, rhb1, rlb0, rlb1, rv0, rv1;
  {
    const size_t kb = (size_t)(kbeg + srow) * 64 + scol;
    rha0 = *(const uint4*)(kha + kb);
    rha1 = *(const uint4*)(kha + kb + 8);
    rla0 = *(const uint4*)(kla + kb);
    rla1 = *(const uint4*)(kla + kb + 8);
    rhb0 = *(const uint4*)(khb + kb);
    rhb1 = *(const uint4*)(khb + kb + 8);
    rlb0 = *(const uint4*)(klb + kb);
    rlb1 = *(const uint4*)(klb + kb + 8);
    const u16* vsrc = vb + (size_t)srow * LQ + kbeg + scol;
    rv0 = *(const uint4*)(vsrc);
    rv1 = *(const uint4*)(vsrc + 8);
  }

  for (int jt = 0; jt <= c; ++jt) {
    const int kt = kbeg + jt * 64;

    // write prefetched tile to LDS
    // (prev tile's K/V-LDS reads are fenced by the csLDS barrier of tile jt-1)
    *(uint4*)&KhA[srow][scol] = rha0; *(uint4*)&KhA[srow][scol + 8] = rha1;
    *(uint4*)&KlA[srow][scol] = rla0; *(uint4*)&KlA[srow][scol + 8] = rla1;
    *(uint4*)&KhB[srow][scol] = rhb0; *(uint4*)&KhB[srow][scol + 8] = rhb1;
    *(uint4*)&KlB[srow][scol] = rlb0; *(uint4*)&KlB[srow][scol + 8] = rlb1;
    *(uint4*)&Vs[srow][scol] = rv0;  *(uint4*)&Vs[srow][scol + 8] = rv1;
    __syncthreads();   // K/V tile ready

    // ---- issue NEXT tile's global loads (latency hides under compute) ----
    if (jt < c) {
      const size_t kb = (size_t)(kt + 64 + srow) * 64 + scol;
      rha0 = *(const uint4*)(kha + kb);
      rha1 = *(const uint4*)(kha + kb + 8);
      rla0 = *(const uint4*)(kla + kb);
      rla1 = *(const uint4*)(kla + kb + 8);
      rhb0 = *(const uint4*)(khb + kb);
      rhb1 = *(const uint4*)(khb + kb + 8);
      rlb0 = *(const uint4*)(klb + kb);
      rlb1 = *(const uint4*)(klb + kb + 8);
      const u16* vsrc = vb + (size_t)srow * LQ + kt + 64 + scol;
      rv0 = *(const uint4*)(vsrc);
      rv1 = *(const uint4*)(vsrc + 8);
    }

    __builtin_amdgcn_s_setprio(1);
    float pc[4][4], cs[4];
#pragma unroll
    for (int fk = 0; fk < 4; ++fk) {
      const int krow = fk * 16 + rsel;
      const int k = kt + krow;
      f32x4 z = {};
      SCORE6(z, aqa0h, aqa1h, aqa0l, aqa1l, &KhA[krow][ksel], &KlA[krow][ksel]);
      f32x4 w = {};
      SCORE6(w, aqb0h, aqb1h, aqb0l, aqb1l, &KhB[krow][ksel], &KlB[krow][ksel]);
      float csj = 0.f;
#pragma unroll
      for (int j = 0; j < 4; ++j) {
        bool msk = ((k & 511) > qm[j]);
        float sa = z[j] * SCALING;
        float pa = __builtin_copysignf(__expf(fabsf(sa)) * iz1[j], sa);
        pa = msk ? 0.f : pa;
        csj += pa;
        float sb = w[j] * SCALING;
        float pb = __builtin_copysignf(__expf(fabsf(sb)) * iz2[j], sb);
        pc[fk][j] = pa - (msk ? 0.f : lam * pb);
      }
      cs[fk] = csj;
    }
    // pc relayout through OWN pcLDS slice (intra-wave, lgkmcnt-ordered)
#pragma unroll
    for (int fk = 0; fk < 4; ++fk)
#pragma unroll
      for (int j = 0; j < 4; ++j)
        pcLDS[wv][grp * 4 + j][fk * 16 + rsel] = f2b(pc[fk][j]);
    // PV (intra-wave; V read from LDS)
#pragma unroll
    for (int kc = 0; kc < 2; ++kc) {
      bf16x8 ap = *(const bf16x8*)&pcLDS[wv][rsel][kc * 32 + ksel];
#pragma unroll
      for (int fn = 0; fn < 4; ++fn) {
        bf16x8 bv = *(const bf16x8*)&Vs[fn * 16 + rsel][kc * 32 + ksel];
        accO[fn] = MFMA16(ap, bv, accO[fn]);
      }
    }
    __builtin_amdgcn_s_setprio(0);
    // cross-wave colsum (csLDS dbuf + barrier; barrier also fences K/V reads
    // of this tile before next tile's ds_writes)
#pragma unroll
    for (int fk = 0; fk < 4; ++fk) {
      float cc = cs[fk];
      cc += __shfl_xor(cc, 16);
      cc += __shfl_xor(cc, 32);
      if (grp == 0) csLDS[buf][wv][fk * 16 + rsel] = cc;
    }
    __syncthreads();
    if (t < 64) {
      float tot = csLDS[buf][0][t] + csLDS[buf][1][t] + csLDS[buf][2][t] + csLDS[buf][3][t];
      colsum[((size_t)h * 32 + qt) * LQ + kt + t] = tot;
    }
    buf ^= 1;
  }
  float* Op = (s == 0) ? O0 : (O123 + (size_t)(s - 1) * 16 * LQ * 64);
#pragma unroll
  for (int fn = 0; fn < 4; ++fn)
#pragma unroll
    for (int j = 0; j < 4; ++j) {
      int q = qrow + grp * 4 + j;
      int d = fn * 16 + rsel;
      Op[((size_t)h * LQ + q) * 64 + d] = accO[fn][j];
    }
}

// g[h][k] = sum_qt colsum[h][qt][k] / 2048
__global__ void g_reduce_kernel(const float* __restrict__ colsum, float* __restrict__ g) {
  int idx = blockIdx.x * 256 + threadIdx.x;
  if (idx >= 16 * LQ) return;
  int h = idx >> 11, k = idx & 2047;
  float s = 0.f;
#pragma unroll
  for (int qt = 0; qt < 32; ++qt) s += colsum[((size_t)h * 32 + qt) * LQ + k];
  g[idx] = s * (1.f / 2048.f);
}

// W[h][r][d] = inclusive prefix over r of Gv[h][r][d], where
// Gv[h][r][d] = sum_seg g[h][seg*512+r] * vt[h][d][seg*512+r]  (gv fused in)
__global__ __launch_bounds__(512) void gv_wscan_kernel(const float* __restrict__ g,
                                                       const u16* __restrict__ vt,
                                                       float* __restrict__ W) {
  __shared__ float s[512];
  int h = blockIdx.x >> 6, d = blockIdx.x & 63;
  int t = threadIdx.x;  // r
  float v = 0.f;
#pragma unroll
  for (int seg = 0; seg < 4; ++seg) {
    int k = seg * 512 + t;
    v += g[h * 2048 + k] * b2f(vt[((size_t)h * 64 + d) * LQ + k]);
  }
  s[t] = v;
  __syncthreads();
  for (int off = 1; off < 512; off <<= 1) {
    float add = (t >= off) ? s[t - off] : 0.f;
    __syncthreads();
    s[t] += add;
    __syncthreads();
  }
  W[((size_t)h * 512 + t) * 64 + d] = s[t];
}

// out_pre = O0 + O1 + O2 + O3 + lam*W[q%512]; head rmsnorm -> bf16 [q][h*64+d]
__global__ __launch_bounds__(256) void combine_norm_kernel(
    const float* __restrict__ O0, const float* __restrict__ O123,
    const float* __restrict__ W, const float* __restrict__ hw,
    const float* __restrict__ lamp, u16* __restrict__ out) {
  const int q = blockIdx.x;
  const int h = blockIdx.y * 4 + (threadIdx.x >> 6);
  const int d = threadIdx.x & 63;
  const float lam = lamp[0];
  const size_t S = (size_t)16 * LQ * 64;
  const size_t idx = ((size_t)h * LQ + q) * 64 + d;
  float v = O0[idx] + O123[idx] + O123[idx + S] + O123[idx + 2 * S] +
            lam * W[((size_t)h * 512 + (q & 511)) * 64 + d];
  float ss = v * v;
#pragma unroll
  for (int off = 1; off < 64; off <<= 1) ss += __shfl_xor(ss, off);
  float sc = 1.f / sqrtf(ss * (1.f / 64.f) + 1e-5f);
  out[(size_t)q * 1024 + h * 64 + d] = f2b(v * sc * hw[d]);
}

// ============================== launch ==============================
extern "C" void kernel_launch(void* const* d_in, const int* in_sizes, int n_in,
                              void* d_out, int out_size, void* d_ws, size_t ws_size,
                              hipStream_t stream) {
  const float* x = (const float*)d_in[0];
  const float* freqs_r = (const float*)d_in[1];
  const float* freqs_i = (const float*)d_in[2];
  // d_in[3] = mask (recomputed analytically)
  const float* kv_down_w = (const float*)d_in[4];
  const float* q_down_w = (const float*)d_in[5];
  const float* kv_up_w = (const float*)d_in[6];
  const float* q_up_w = (const float*)d_in[7];
  const float* kv_norm_w = (const float*)d_in[8];
  const float* q_norm_w = (const float*)d_in[9];
  const float* o_w = (const float*)d_in[10];
  const float* lambda_q1 = (const float*)d_in[11];
  const float* lambda_k1 = (const float*)d_in[12];
  const float* lambda_q2 = (const float*)d_in[13];
  const float* lambda_k2 = (const float*)d_in[14];
  const float* head_norm_w = (const float*)d_in[15];
  const float* norm1_w = (const float*)d_in[16];
  const float* norm2_w = (const float*)d_in[17];
  const float* ff_in_w = (const float*)d_in[18];
  const float* ff_out_w = (const float*)d_in[19];
  float* out = (float*)d_out;
  char* ws = (char*)d_ws;

  // ---- weights region (persistent except down/up: dead after projections) ----
  const size_t WT_KVD_H = 0;                                  // 544x1024 bf16
  const size_t WT_KVD_L = WT_KVD_H + (size_t)544 * 1024 * 2;
  const size_t WT_QD_H  = WT_KVD_L + (size_t)544 * 1024 * 2;  // 512x1024
  const size_t WT_QD_L  = WT_QD_H + (size_t)512 * 1024 * 2;
  const size_t WT_KVU_H = WT_QD_L + (size_t)512 * 1024 * 2;   // 2048x512
  const size_t WT_KVU_L = WT_KVU_H + (size_t)2048 * 512 * 2;
  const size_t WT_QU_H  = WT_KVU_L + (size_t)2048 * 512 * 2;  // 1536x512
  const size_t WT_QU_L  = WT_QU_H + (size_t)1536 * 512 * 2;
  const size_t WT_OW    = WT_QU_L + (size_t)1536 * 512 * 2;   // = 11,714,560
  const size_t WT_FFI   = WT_OW + (size_t)1024 * 1024 * 2;
  const size_t WT_FFO   = WT_FFI + (size_t)8192 * 1024 * 2;
  const size_t A0 = WT_FFO + (size_t)1024 * 4096 * 2;         // = 38,928,384

  // ---- activations (lifetime-aliased) ----
  const size_t H     = A0;                  // h hi/lo bf16 (2x 4,194,304); dead after down-GEMMs
  const size_t CKV   = A0 + 8388608;        // f32 2048x544;  dead after build_kh
  const size_t CKVN  = A0 + 12845056;       // ckvn hi/lo bf16 (2x 2,097,152); dead after kv_up
  const size_t KVB   = A0 + 17039360;       // f32 2048x2048; dead after build_vt
  const size_t CQ    = A0 + 33816576;       // f32 2048x512;  dead after rmsnorm
  const size_t CQN   = A0 + 38010880;       // cqn hi/lo bf16 (2x 2,097,152); dead after q_up
  const size_t QFULL = A0 + 42205184;       // f32 2048x1536; dead after build_qh
  // mid buffers (aliases):
  const size_t QHI = H;                     // bf16 32x2048x64 over dead H
  const size_t KHI = QFULL;                 // bf16 32x2048x64 over dead QFULL[0:8.39M]
  const size_t KLO = A0 + 50593792;         // bf16 32x2048x64 over dead QFULL[8.39M:]+
  const size_t QLO = A0 + 58982400;         // bf16 32x2048x64
  const size_t VT  = CKVN;                  // bf16 16x64x2048 over dead CKVN
  // O partials (4 x 8,388,608 f32):
  const size_t OP0   = 0;                   // over dead down/up weights [0, 8.39M) < WT_OW
  const size_t OP123 = KVB;                 // 3 contiguous partials over dead KVB+CQ+CQN
  const size_t CS  = CKV;                   // f32 16x32x2048 over dead CKV
  const size_t GB  = A0 + 67371008;         // f32 16x2048 (131,072)
  const size_t GV  = A0 + 67502080;         // f32 16x512x64 (2,097,152) [unused now]
  const size_t WB  = A0 + 69599232;         // f32 16x512x64 (2,097,152)
  const size_t LAM = A0 + 71696384;         // scalar
  const size_t ZP  = A0 + 71696640;         // f32 4x32x2048 (1,048,576)
  const size_t WS_END = A0 + 72745216;      // ~111.7 MB (known-safe)
  // late aliases:
  const size_t ATTN  = CKV;                 // bf16 2048x1024 (over consumed CS)
  const size_t X1    = KVB + 8388608;       // f32 2048x1024 (partials consumed by combine)
  const size_t H2N   = H;                   // bf16 2048x1024 over dead QHI
  const size_t FFACT = QFULL;               // bf16 2048x4096 over dead KHI+KLO

  if (ws_size < WS_END) return;

  u16* wt_kvd_h = (u16*)(ws + WT_KVD_H); u16* wt_kvd_l = (u16*)(ws + WT_KVD_L);
  u16* wt_qd_h  = (u16*)(ws + WT_QD_H);  u16* wt_qd_l  = (u16*)(ws + WT_QD_L);
  u16* wt_kvu_h = (u16*)(ws + WT_KVU_H); u16* wt_kvu_l = (u16*)(ws + WT_KVU_L);
  u16* wt_qu_h  = (u16*)(ws + WT_QU_H);  u16* wt_qu_l  = (u16*)(ws + WT_QU_L);
  u16* wt_ow  = (u16*)(ws + WT_OW);
  u16* wt_ffi = (u16*)(ws + WT_FFI);
  u16* wt_ffo = (u16*)(ws + WT_FFO);
  u16* h_hi   = (u16*)(ws + H);
  u16* h_lo   = (u16*)(ws + H + 4194304);
  float* ckv  = (float*)(ws + CKV);
  u16* ckvn_hi = (u16*)(ws + CKVN);
  u16* ckvn_lo = (u16*)(ws + CKVN + 2097152);
  float* kvb  = (float*)(ws + KVB);
  float* cq   = (float*)(ws + CQ);
  u16* cqn_hi = (u16*)(ws + CQN);
  u16* cqn_lo = (u16*)(ws + CQN + 2097152);
  float* qfull = (float*)(ws + QFULL);
  u16* qhib = (u16*)(ws + QHI); u16* qlob = (u16*)(ws + QLO);
  u16* khib = (u16*)(ws + KHI); u16* klob = (u16*)(ws + KLO);
  u16* vtb  = (u16*)(ws + VT);
  float* zpb = (float*)(ws + ZP);
  float* Op0 = (float*)(ws + OP0);
  float* Op123 = (float*)(ws + OP123);
  float* csb = (float*)(ws + CS);
  float* gb  = (float*)(ws + GB);
  float* wbb = (float*)(ws + WB);
  float* lamp = (float*)(ws + LAM);
  u16* attn_n = (u16*)(ws + ATTN);
  float* x1 = (float*)(ws + X1);
  u16* h2n = (u16*)(ws + H2N);
  u16* ffact = (u16*)(ws + FFACT);

  // fused weight prep (7 transposes -> 1 kernel; 16160 blocks of 32x8)
  prep_weights_kernel<<<16160, dim3(32, 8), 0, stream>>>(
      kv_down_w, wt_kvd_h, wt_kvd_l, q_down_w, wt_qd_h, wt_qd_l,
      kv_up_w, wt_kvu_h, wt_kvu_l, q_up_w, wt_qu_h, wt_qu_l,
      o_w, wt_ow, ff_in_w, wt_ffi, ff_out_w, wt_ffo);

  rmsnorm_split_kernel<<<2048, 256, 0, stream>>>(x, norm1_w, h_hi, h_lo, 1024, 1024, FEPS);
  // both down-projections (share A = h)
  gemm_split<<<dim3(9, 32), 256, 0, stream>>>(h_hi, h_lo, wt_kvd_h, wt_kvd_l, ckv,
                                              2048, 544, 1024);
  gemm_split<<<dim3(8, 32), 256, 0, stream>>>(h_hi, h_lo, wt_qd_h, wt_qd_l, cq,
                                              2048, 512, 1024);
  // fused rmsnorm of ckv (stride 544) + cq (stride 512)
  rmsnorm_split2_kernel<<<4096, 256, 0, stream>>>(ckv, kv_norm_w, ckvn_hi, ckvn_lo, 544,
                                                  cq, q_norm_w, cqn_hi, cqn_lo, 512);
  gemm_split<<<dim3(32, 32), 256, 0, stream>>>(ckvn_hi, ckvn_lo, wt_kvu_h, wt_kvu_l, kvb,
                                               2048, 2048, 512);
  gemm_split<<<dim3(24, 32), 256, 0, stream>>>(cqn_hi, cqn_lo, wt_qu_h, wt_qu_l, qfull,
                                               2048, 1536, 512);

  // fused mid build (build_qh + build_kh + build_vt + lam -> 1 kernel)
  build_mid_kernel<<<33281, 256, 0, stream>>>(qfull, kvb, ckv, freqs_r, freqs_i,
                                              qhib, qlob, khib, klob, vtb,
                                              lambda_q1, lambda_k1, lambda_q2, lambda_k2,
                                              lamp);

  attn_z_kernel<<<4096, 256, 0, stream>>>(qhib, khib, zpb);
  attn_pv_kernel<<<2048, 256, 0, stream>>>(qhib, qlob, khib, klob, vtb, zpb,
                                           lamp, Op0, Op123, csb);

  g_reduce_kernel<<<128, 256, 0, stream>>>(csb, gb);
  gv_wscan_kernel<<<1024, 512, 0, stream>>>(gb, vtb, wbb);
  combine_norm_kernel<<<dim3(2048, 4), 256, 0, stream>>>(Op0, Op123, wbb, head_norm_w,
                                                         lamp, attn_n);

  // x1 = x + attn_n @ o_w  (residual fused into epilogue)
  gemm_kernel<0, 1><<<dim3(16, 32), 256, 0, stream>>>(attn_n, wt_ow, x, x1, nullptr,
                                                      2048, 1024, 1024);
  rmsnorm_kernel<1><<<2048, 256, 0, stream>>>(x1, norm2_w, h2n, 1024, 1024, FEPS);
  gemm_kernel<1, 0><<<dim3(64, 32), 256, 0, stream>>>(h2n, wt_ffi, nullptr, nullptr, ffact,
                                                      2048, 4096, 1024);
  // out = x1 + ffact @ ff_out  (residual fused into epilogue)
  gemm_kernel<0, 1><<<dim3(16, 32), 256, 0, stream>>>(ffact, wt_ffo, x1, out, nullptr,
                                                      2048, 1024, 4096);
}

// Round 26
// 351.943 us; speedup vs baseline: 1.1568x; 1.0100x over previous
//
#include <hip/hip_runtime.h>
#include <math.h>

#define LQ 2048
#define SCALING 0.14433756729740643f   // 48^-0.5
#define FEPS 1.1920928955078125e-07f   // np.finfo(float32).eps

typedef unsigned short u16;
typedef __attribute__((ext_vector_type(8))) short bf16x8;
typedef __attribute__((ext_vector_type(4))) float f32x4;

#define MFMA16(a, b, c) __builtin_amdgcn_mfma_f32_16x16x32_bf16((a), (b), (c), 0, 0, 0)

__device__ __forceinline__ u16 f2b(float x) {
  union { float f; unsigned u; } v; v.f = x;
  return (u16)((v.u + 0x7FFFu + ((v.u >> 16) & 1u)) >> 16);
}
__device__ __forceinline__ float b2f(u16 b) {
  union { unsigned u; float f; } v; v.u = ((unsigned)b) << 16;
  return v.f;
}

// ---- fused weight prep: 7 transposes + rmsnorm_split(x) in one kernel ----
__global__ __launch_bounds__(256) void prep_weights_kernel(
    const float* __restrict__ kvd, u16* __restrict__ kvd_h, u16* __restrict__ kvd_l,
    const float* __restrict__ qd,  u16* __restrict__ qd_h,  u16* __restrict__ qd_l,
    const float* __restrict__ kvu, u16* __restrict__ kvu_h, u16* __restrict__ kvu_l,
    const float* __restrict__ qu,  u16* __restrict__ qu_h,  u16* __restrict__ qu_l,
    const float* __restrict__ ow,  u16* __restrict__ ow_t,
    const float* __restrict__ ffi, u16* __restrict__ ffi_t,
    const float* __restrict__ ffo, u16* __restrict__ ffo_t,
    const float* __restrict__ x, const float* __restrict__ norm1_w,
    u16* __restrict__ h_hi, u16* __restrict__ h_lo) {
  __shared__ float tile[32][33];
  __shared__ float red[4];
  int id = blockIdx.x;

  if (id >= 16160) {
    // ---- rmsnorm_split of x: row = id - 16160, cols 1024 ----
    const int row = id - 16160;
    const int tid = threadIdx.y * 32 + threadIdx.x;  // flat 0..255
    const float* xr = x + (size_t)row * 1024;
    float ss = 0.f;
    for (int c = tid; c < 1024; c += 256) { float v = xr[c]; ss = fmaf(v, v, ss); }
#pragma unroll
    for (int off = 32; off > 0; off >>= 1) ss += __shfl_xor(ss, off);
    if ((tid & 63) == 0) red[tid >> 6] = ss;
    __syncthreads();
    float tot = red[0] + red[1] + red[2] + red[3];
    float sc = 1.f / sqrtf(tot / 1024.f + FEPS);
    for (int c = tid; c < 1024; c += 256) {
      float v = xr[c] * sc * norm1_w[c];
      u16 hi = f2b(v);
      h_hi[(size_t)row * 1024 + c] = hi;
      h_lo[(size_t)row * 1024 + c] = f2b(v - b2f(hi));
    }
    return;
  }

  const float* W; u16* Whi; u16* Wlo = nullptr; int K, N, bx, by;
  if (id < 8192) {                       // ff_in 1024x8192 (heaviest first)
    W = ffi; Whi = ffi_t; K = 1024; N = 8192; bx = id % 256; by = id / 256;
  } else if (id < 8192 + 4096) {         // ff_out 4096x1024
    id -= 8192;
    W = ffo; Whi = ffo_t; K = 4096; N = 1024; bx = id % 32; by = id / 32;
  } else if (id < 12288 + 1024) {        // o_w 1024x1024
    id -= 12288;
    W = ow; Whi = ow_t; K = 1024; N = 1024; bx = id % 32; by = id / 32;
  } else if (id < 13312 + 544) {         // kv_down 1024x544 (split)
    id -= 13312;
    W = kvd; Whi = kvd_h; Wlo = kvd_l; K = 1024; N = 544; bx = id % 17; by = id / 17;
  } else if (id < 13856 + 512) {         // q_down 1024x512 (split)
    id -= 13856;
    W = qd; Whi = qd_h; Wlo = qd_l; K = 1024; N = 512; bx = id % 16; by = id / 16;
  } else if (id < 14368 + 1024) {        // kv_up 512x2048 (split)
    id -= 14368;
    W = kvu; Whi = kvu_h; Wlo = kvu_l; K = 512; N = 2048; bx = id % 64; by = id / 64;
  } else {                               // q_up 512x1536 (split)
    id -= 15392;
    W = qu; Whi = qu_h; Wlo = qu_l; K = 512; N = 1536; bx = id % 48; by = id / 48;
  }

  int n0 = bx * 32, k0 = by * 32;
  int tx = threadIdx.x, ty = threadIdx.y;  // 32 x 8
  for (int i = ty; i < 32; i += 8) {
    int k = k0 + i, n = n0 + tx;
    tile[i][tx] = (k < K && n < N) ? W[(size_t)k * N + n] : 0.f;
  }
  __syncthreads();
  for (int i = ty; i < 32; i += 8) {
    int n = n0 + i, k = k0 + tx;
    if (n < N && k < K) {
      float xv = tile[tx][i];
      u16 hi = f2b(xv);
      Whi[(size_t)n * K + k] = hi;
      if (Wlo) Wlo[(size_t)n * K + k] = f2b(xv - b2f(hi));
    }
  }
}

// ---------------- rmsnorm fp32 in (strided) -> fp32 or bf16 out ----------------
template <int BF16OUT>
__global__ __launch_bounds__(256) void rmsnorm_kernel(
    const float* __restrict__ x, const float* __restrict__ w, void* __restrict__ outv,
    int cols, int in_stride, float eps) {
  const int row = blockIdx.x;
  const float* xr = x + (size_t)row * in_stride;
  float ss = 0.f;
  for (int c = threadIdx.x; c < cols; c += 256) { float v = xr[c]; ss = fmaf(v, v, ss); }
#pragma unroll
  for (int off = 32; off > 0; off >>= 1) ss += __shfl_xor(ss, off);
  __shared__ float red[4];
  if ((threadIdx.x & 63) == 0) red[threadIdx.x >> 6] = ss;
  __syncthreads();
  float tot = red[0] + red[1] + red[2] + red[3];
  float sc = 1.f / sqrtf(tot / (float)cols + eps);
  for (int c = threadIdx.x; c < cols; c += 256) {
    float v = xr[c] * sc * w[c];
    if (BF16OUT) ((u16*)outv)[(size_t)row * cols + c] = f2b(v);
    else ((float*)outv)[(size_t)row * cols + c] = v;
  }
}

// ---- fused pair: rmsnorm_split for ckv (cols 512, stride 544) + cq (512/512) ----
__global__ __launch_bounds__(256) void rmsnorm_split2_kernel(
    const float* __restrict__ in0, const float* __restrict__ w0,
    u16* __restrict__ hi0, u16* __restrict__ lo0, int stride0,
    const float* __restrict__ in1, const float* __restrict__ w1,
    u16* __restrict__ hi1, u16* __restrict__ lo1, int stride1) {
  int row = blockIdx.x;
  const float* xr; const float* w; u16* ho; u16* lo;
  if (row < 2048) {
    xr = in0 + (size_t)row * stride0; w = w0;
    ho = hi0 + (size_t)row * 512; lo = lo0 + (size_t)row * 512;
  } else {
    row -= 2048;
    xr = in1 + (size_t)row * stride1; w = w1;
    ho = hi1 + (size_t)row * 512; lo = lo1 + (size_t)row * 512;
  }
  float ss = 0.f;
  for (int c = threadIdx.x; c < 512; c += 256) { float v = xr[c]; ss = fmaf(v, v, ss); }
#pragma unroll
  for (int off = 32; off > 0; off >>= 1) ss += __shfl_xor(ss, off);
  __shared__ float red[4];
  if ((threadIdx.x & 63) == 0) red[threadIdx.x >> 6] = ss;
  __syncthreads();
  float tot = red[0] + red[1] + red[2] + red[3];
  float sc = 1.f / sqrtf(tot / 512.f + FEPS);
  for (int c = threadIdx.x; c < 512; c += 256) {
    float v = xr[c] * sc * w[c];
    u16 hi = f2b(v);
    ho[c] = hi;
    lo[c] = f2b(v - b2f(hi));
  }
}

// ---- split-precision GEMM (3-term), all-bf16 staging ----
__global__ __launch_bounds__(256) void gemm_split(
    const u16* __restrict__ Ahi, const u16* __restrict__ Alo,
    const u16* __restrict__ Bhi, const u16* __restrict__ Blo,
    float* __restrict__ C, int M, int N, int K) {
  __shared__ u16 Ah[64][72];
  __shared__ u16 Al[64][72];
  __shared__ u16 Bh[64][72];
  __shared__ u16 Bl[64][72];

  const int t = threadIdx.x;
  const int lane = t & 63;
  const int wv = t >> 6;
  const int wr = (wv >> 1) * 32;
  const int wc = (wv & 1) * 32;
  const int bm = blockIdx.y * 64;
  const int bn = blockIdx.x * 64;
  const int lr = t >> 2;
  const int lc = (t & 3) * 16;
  const int rsel = lane & 15;
  const int ksel = 8 * (lane >> 4);

  const u16* Ahrow = Ahi + (size_t)(bm + lr) * K + lc;
  const u16* Alrow = Alo + (size_t)(bm + lr) * K + lc;
  const bool bval = (bn + lr) < N;
  const u16* Bhrow = Bhi + (size_t)(bn + lr) * K + lc;
  const u16* Blrow = Blo + (size_t)(bn + lr) * K + lc;

  f32x4 acc[2][2] = {};

  for (int kt = 0; kt < K; kt += 64) {
    uint4 ah0 = *(const uint4*)(Ahrow + kt);
    uint4 ah1 = *(const uint4*)(Ahrow + kt + 8);
    uint4 al0 = *(const uint4*)(Alrow + kt);
    uint4 al1 = *(const uint4*)(Alrow + kt + 8);
    uint4 bh0 = {0, 0, 0, 0}, bh1 = {0, 0, 0, 0}, bl0 = {0, 0, 0, 0}, bl1 = {0, 0, 0, 0};
    if (bval) {
      bh0 = *(const uint4*)(Bhrow + kt); bh1 = *(const uint4*)(Bhrow + kt + 8);
      bl0 = *(const uint4*)(Blrow + kt); bl1 = *(const uint4*)(Blrow + kt + 8);
    }
    __syncthreads();
    *(uint4*)&Ah[lr][lc] = ah0; *(uint4*)&Ah[lr][lc + 8] = ah1;
    *(uint4*)&Al[lr][lc] = al0; *(uint4*)&Al[lr][lc + 8] = al1;
    *(uint4*)&Bh[lr][lc] = bh0; *(uint4*)&Bh[lr][lc + 8] = bh1;
    *(uint4*)&Bl[lr][lc] = bl0; *(uint4*)&Bl[lr][lc + 8] = bl1;
    __syncthreads();
#pragma unroll
    for (int ks = 0; ks < 2; ++ks) {
      const int ko = ks * 32 + ksel;
      bf16x8 a0h = *(const bf16x8*)&Ah[wr + rsel][ko];
      bf16x8 a1h = *(const bf16x8*)&Ah[wr + 16 + rsel][ko];
      bf16x8 a0l = *(const bf16x8*)&Al[wr + rsel][ko];
      bf16x8 a1l = *(const bf16x8*)&Al[wr + 16 + rsel][ko];
      bf16x8 b0h = *(const bf16x8*)&Bh[wc + rsel][ko];
      bf16x8 b1h = *(const bf16x8*)&Bh[wc + 16 + rsel][ko];
      bf16x8 b0l = *(const bf16x8*)&Bl[wc + rsel][ko];
      bf16x8 b1l = *(const bf16x8*)&Bl[wc + 16 + rsel][ko];
      acc[0][0] = MFMA16(a0h, b0h, acc[0][0]);
      acc[0][0] = MFMA16(a0h, b0l, acc[0][0]);
      acc[0][0] = MFMA16(a0l, b0h, acc[0][0]);
      acc[0][1] = MFMA16(a0h, b1h, acc[0][1]);
      acc[0][1] = MFMA16(a0h, b1l, acc[0][1]);
      acc[0][1] = MFMA16(a0l, b1h, acc[0][1]);
      acc[1][0] = MFMA16(a1h, b0h, acc[1][0]);
      acc[1][0] = MFMA16(a1h, b0l, acc[1][0]);
      acc[1][0] = MFMA16(a1l, b0h, acc[1][0]);
      acc[1][1] = MFMA16(a1h, b1h, acc[1][1]);
      acc[1][1] = MFMA16(a1h, b1l, acc[1][1]);
      acc[1][1] = MFMA16(a1l, b1h, acc[1][1]);
    }
  }
  const int r0 = (lane >> 4) * 4;
#pragma unroll
  for (int fm = 0; fm < 2; ++fm)
#pragma unroll
    for (int fn = 0; fn < 2; ++fn)
#pragma unroll
      for (int j = 0; j < 4; ++j) {
        int row = bm + wr + fm * 16 + r0 + j;
        int col = bn + wc + fn * 16 + rsel;
        if (col < N) C[(size_t)row * N + col] = acc[fm][fn][j];
      }
}

// ---- plain bf16 GEMM (o_w / FFN-out): 64x64 reg-staged. ADDX fuses residual add. ----
template <int GATED, int ADDX>
__global__ __launch_bounds__(256) void gemm_kernel(
    const u16* __restrict__ A, const u16* __restrict__ Bt, const float* __restrict__ X,
    float* __restrict__ C, u16* __restrict__ Cg, int M, int N, int K) {
  __shared__ u16 As[64][72];
  __shared__ u16 Bs[64][72];
  __shared__ u16 Bs2[GATED ? 64 : 1][72];

  const int t = threadIdx.x;
  const int lane = t & 63;
  const int wv = t >> 6;
  const int wr = (wv >> 1) * 32;
  const int wc = (wv & 1) * 32;
  const int bm = blockIdx.y * 64;
  const int bn = blockIdx.x * 64;
  const int lr = t >> 2;
  const int lc = (t & 3) * 16;
  const int rsel = lane & 15;
  const int ksel = 8 * (lane >> 4);

  const u16* Arow = A + (size_t)(bm + lr) * K + lc;
  const u16* Brow = Bt + (size_t)(bn + lr) * K + lc;
  const u16* Brow2 = Bt + (size_t)(4096 + bn + lr) * K + lc;

  f32x4 acc[2][2] = {};
  f32x4 accg[2][2] = {};

  for (int kt = 0; kt < K; kt += 64) {
    uint4 a0 = *(const uint4*)(Arow + kt);
    uint4 a1 = *(const uint4*)(Arow + kt + 8);
    uint4 b0 = *(const uint4*)(Brow + kt);
    uint4 b1 = *(const uint4*)(Brow + kt + 8);
    uint4 c0 = {0, 0, 0, 0}, c1 = {0, 0, 0, 0};
    if (GATED) { c0 = *(const uint4*)(Brow2 + kt); c1 = *(const uint4*)(Brow2 + kt + 8); }
    __syncthreads();
    *(uint4*)&As[lr][lc] = a0; *(uint4*)&As[lr][lc + 8] = a1;
    *(uint4*)&Bs[lr][lc] = b0; *(uint4*)&Bs[lr][lc + 8] = b1;
    if (GATED) { *(uint4*)&Bs2[lr][lc] = c0; *(uint4*)&Bs2[lr][lc + 8] = c1; }
    __syncthreads();
#pragma unroll
    for (int ks = 0; ks < 2; ++ks) {
      const int ko = ks * 32 + ksel;
      bf16x8 af0 = *(const bf16x8*)&As[wr + rsel][ko];
      bf16x8 af1 = *(const bf16x8*)&As[wr + 16 + rsel][ko];
      bf16x8 bf0 = *(const bf16x8*)&Bs[wc + rsel][ko];
      bf16x8 bf1 = *(const bf16x8*)&Bs[wc + 16 + rsel][ko];
      acc[0][0] = MFMA16(af0, bf0, acc[0][0]);
      acc[0][1] = MFMA16(af0, bf1, acc[0][1]);
      acc[1][0] = MFMA16(af1, bf0, acc[1][0]);
      acc[1][1] = MFMA16(af1, bf1, acc[1][1]);
      if (GATED) {
        bf16x8 cf0 = *(const bf16x8*)&Bs2[wc + rsel][ko];
        bf16x8 cf1 = *(const bf16x8*)&Bs2[wc + 16 + rsel][ko];
        accg[0][0] = MFMA16(af0, cf0, accg[0][0]);
        accg[0][1] = MFMA16(af0, cf1, accg[0][1]);
        accg[1][0] = MFMA16(af1, cf0, accg[1][0]);
        accg[1][1] = MFMA16(af1, cf1, accg[1][1]);
      }
    }
  }
  const int r0 = (lane >> 4) * 4;
#pragma unroll
  for (int fm = 0; fm < 2; ++fm)
#pragma unroll
    for (int fn = 0; fn < 2; ++fn)
#pragma unroll
      for (int j = 0; j < 4; ++j) {
        int row = bm + wr + fm * 16 + r0 + j;
        int col = bn + wc + fn * 16 + rsel;
        size_t o = (size_t)row * N + col;
        if (!GATED) {
          float v = acc[fm][fn][j];
          if (ADDX) v += X[o];
          C[o] = v;
        } else {
          float u = acc[fm][fn][j], g = accg[fm][fn][j];
          float sv = g / (1.f + __expf(-g));
          Cg[o] = f2b(u * sv);
        }
      }
}

// ---- gated FFN-in GEMM, M=128 x N=64 tile (1024 blocks: B re-reads halved;
//      o_w/ffn_out keep 64x64 — their grids would starve at M=128). ----
__global__ __launch_bounds__(256) void gemm_m128_gated(
    const u16* __restrict__ A, const u16* __restrict__ Bt,
    u16* __restrict__ Cg, int M, int N, int K) {
  __shared__ u16 As[128][72];
  __shared__ u16 Bs[64][72];
  __shared__ u16 Bs2[64][72];

  const int t = threadIdx.x;
  const int lane = t & 63;
  const int wv = t >> 6;
  const int wr = wv * 32;             // wave row base within 128-row tile
  const int bm = blockIdx.y * 128;
  const int bn = blockIdx.x * 64;
  const int lr = t >> 2;              // staging row 0..63
  const int lc = (t & 3) * 16;        // staging col
  const int rsel = lane & 15;
  const int ksel = 8 * (lane >> 4);

  const u16* Arow0 = A + (size_t)(bm + lr) * K + lc;
  const u16* Arow1 = A + (size_t)(bm + 64 + lr) * K + lc;
  const u16* Brow = Bt + (size_t)(bn + lr) * K + lc;
  const u16* Brow2 = Bt + (size_t)(4096 + bn + lr) * K + lc;

  f32x4 acc[2][4] = {};
  f32x4 accg[2][4] = {};

  for (int kt = 0; kt < K; kt += 64) {
    uint4 a00 = *(const uint4*)(Arow0 + kt);
    uint4 a01 = *(const uint4*)(Arow0 + kt + 8);
    uint4 a10 = *(const uint4*)(Arow1 + kt);
    uint4 a11 = *(const uint4*)(Arow1 + kt + 8);
    uint4 b0 = *(const uint4*)(Brow + kt);
    uint4 b1 = *(const uint4*)(Brow + kt + 8);
    uint4 c0 = *(const uint4*)(Brow2 + kt);
    uint4 c1 = *(const uint4*)(Brow2 + kt + 8);
    __syncthreads();
    *(uint4*)&As[lr][lc] = a00; *(uint4*)&As[lr][lc + 8] = a01;
    *(uint4*)&As[64 + lr][lc] = a10; *(uint4*)&As[64 + lr][lc + 8] = a11;
    *(uint4*)&Bs[lr][lc] = b0; *(uint4*)&Bs[lr][lc + 8] = b1;
    *(uint4*)&Bs2[lr][lc] = c0; *(uint4*)&Bs2[lr][lc + 8] = c1;
    __syncthreads();
#pragma unroll
    for (int ks = 0; ks < 2; ++ks) {
      const int ko = ks * 32 + ksel;
      bf16x8 af0 = *(const bf16x8*)&As[wr + rsel][ko];
      bf16x8 af1 = *(const bf16x8*)&As[wr + 16 + rsel][ko];
      bf16x8 bf[4];
#pragma unroll
      for (int fn = 0; fn < 4; ++fn)
        bf[fn] = *(const bf16x8*)&Bs[fn * 16 + rsel][ko];
#pragma unroll
      for (int fn = 0; fn < 4; ++fn) {
        acc[0][fn] = MFMA16(af0, bf[fn], acc[0][fn]);
        acc[1][fn] = MFMA16(af1, bf[fn], acc[1][fn]);
      }
      bf16x8 cf[4];
#pragma unroll
      for (int fn = 0; fn < 4; ++fn)
        cf[fn] = *(const bf16x8*)&Bs2[fn * 16 + rsel][ko];
#pragma unroll
      for (int fn = 0; fn < 4; ++fn) {
        accg[0][fn] = MFMA16(af0, cf[fn], accg[0][fn]);
        accg[1][fn] = MFMA16(af1, cf[fn], accg[1][fn]);
      }
    }
  }
  const int r0 = (lane >> 4) * 4;
#pragma unroll
  for (int fm = 0; fm < 2; ++fm)
#pragma unroll
    for (int fn = 0; fn < 4; ++fn)
#pragma unroll
      for (int j = 0; j < 4; ++j) {
        int row = bm + wr * 0 + wv * 32 + fm * 16 + r0 + j;
        int col = bn + fn * 16 + rsel;
        size_t o = (size_t)row * N + col;
        float u = acc[fm][fn][j], g = accg[fm][fn][j];
        float sv = g / (1.f + __expf(-g));
        Cg[o] = f2b(u * sv);
      }
}

// ---- fused mid build: build_qh + build_kh + build_vt + lam in one kernel ----
__global__ __launch_bounds__(256) void build_mid_kernel(
    const float* __restrict__ qfull, const float* __restrict__ kv,
    const float* __restrict__ ckv, const float* __restrict__ fr,
    const float* __restrict__ fi, u16* __restrict__ qhi, u16* __restrict__ qlo,
    u16* __restrict__ khi, u16* __restrict__ klo, u16* __restrict__ vt,
    const float* __restrict__ lq1, const float* __restrict__ lk1,
    const float* __restrict__ lq2, const float* __restrict__ lk2,
    float* __restrict__ lamp) {
  __shared__ u16 tile[64][65];
  int id = blockIdx.x;
  if (id < 16384) {
    // ---- build_qh ----
    const int q = id & 2047;
    const int h2 = ((id >> 11) << 2) + (threadIdx.x >> 6);
    const int d = threadIdx.x & 63;
    const int hh = h2 >> 1, s = h2 & 1;
    const float* row = qfull + (size_t)q * 1536 + hh * 96;
    float val;
    if (d < 32) {
      val = row[s * 32 + d];
    } else if (d < 48) {
      int r = d - 32;
      int pos = q & 511;
      const float* rp = row + 64 + s * 16;
      if (pos == 0) val = rp[r];
      else {
        int j = r >> 1;
        float cr = fr[(pos - 1) * 8 + j], ci = fi[(pos - 1) * 8 + j];
        float a = rp[2 * j], b = rp[2 * j + 1];
        val = (r & 1) ? (a * ci + b * cr) : (a * cr - b * ci);
      }
    } else val = 0.f;
    u16 hi = f2b(val);
    qhi[((size_t)h2 * LQ + q) * 64 + d] = hi;
    qlo[((size_t)h2 * LQ + q) * 64 + d] = f2b(val - b2f(hi));
    return;
  }
  id -= 16384;
  if (id < 16384) {
    // ---- build_kh ----
    const int kp = id & 2047;
    const int h2 = ((id >> 11) << 2) + (threadIdx.x >> 6);
    const int d = threadIdx.x & 63;
    const int hh = h2 >> 1, s = h2 & 1;
    float val;
    if (d < 32) {
      val = kv[(size_t)kp * 2048 + hh * 128 + s * 32 + d];
    } else if (d < 48) {
      int r = d - 32;
      int pos = kp & 511;
      const float* rp = ckv + (size_t)kp * 544 + 512 + s * 16;
      if (pos == 0) val = rp[r];
      else {
        int j = r >> 1;
        float cr = fr[(pos - 1) * 8 + j], ci = fi[(pos - 1) * 8 + j];
        float a = rp[2 * j], b = rp[2 * j + 1];
        val = (r & 1) ? (a * ci + b * cr) : (a * cr - b * ci);
      }
    } else val = 0.f;
    u16 hi = f2b(val);
    khi[((size_t)h2 * LQ + kp) * 64 + d] = hi;
    klo[((size_t)h2 * LQ + kp) * 64 + d] = f2b(val - b2f(hi));
    return;
  }
  id -= 16384;
  if (id < 512) {
    // ---- build_vt: vt[h][d][k] = bf16(kv[k][h*128+64+d]) ----
    int h = id >> 5, k0 = (id & 31) * 64;
    int t = threadIdx.x;
    int d = t & 63, kr = t >> 6;
#pragma unroll
    for (int i = 0; i < 16; ++i) {
      int k = kr + i * 4;
      tile[k][d] = f2b(kv[(size_t)(k0 + k) * 2048 + h * 128 + 64 + d]);
    }
    __syncthreads();
    int kk = t & 63, dr = t >> 6;
#pragma unroll
    for (int i = 0; i < 16; ++i) {
      int d2 = dr + i * 4;
      vt[((size_t)h * 64 + d2) * LQ + k0 + kk] = tile[kk][d2];
    }
    return;
  }
  // ---- lam = exp(sum(lk1*lq1)) - exp(sum(lk2*lq2)) + 0.2 ----
  int t = threadIdx.x;
  if (t < 32) {
    float a = lq1[t] * lk1[t], b = lq2[t] * lk2[t];
#pragma unroll
    for (int off = 1; off < 32; off <<= 1) { a += __shfl_xor(a, off); b += __shfl_xor(b, off); }
    if (t == 0) lamp[0] = expf(a) - expf(b) + 0.2f;
  }
}

// 6-MFMA split-precision 16x16 score tile
#define SCORE6(z, a0h, a1h, a0l, a1l, ph, pl)                         \
  {                                                                   \
    bf16x8 bh0 = *(const bf16x8*)(ph), bh1 = *(const bf16x8*)((ph) + 32); \
    bf16x8 bl0 = *(const bf16x8*)(pl), bl1 = *(const bf16x8*)((pl) + 32); \
    z = MFMA16(a0h, bh0, z); z = MFMA16(a1h, bh1, z);                 \
    z = MFMA16(a0h, bl0, z); z = MFMA16(a1h, bl1, z);                 \
    z = MFMA16(a0l, bh0, z); z = MFMA16(a1l, bh1, z);                 \
  }

// ---- attention Z: zp[s][h2][q] = sum over k-segment s of exp|a| (s = 0..3) ----
__global__ __launch_bounds__(256) void attn_z_kernel(
    const u16* __restrict__ qhi, const u16* __restrict__ khi,
    float* __restrict__ zp) {
  __shared__ u16 Kh[2][64][72];

  const int bid = blockIdx.x;
  const int c = 7 - (bid >> 9);                 // heavy-first
  const int r = bid & 511;
  const int h2 = r & 31;
  const int qtIdx = (r >> 5) & 3;
  const int s = r >> 7;                         // 0..3
  const int qt = qtIdx * 8 + c;
  const int qb = qt * 64;
  const int t = threadIdx.x;
  const int lane = t & 63, wv = t >> 6;
  const int rsel = lane & 15, grp = lane >> 4, ksel = 8 * grp;
  const int qrow = qb + wv * 16;

  const size_t qoff = ((size_t)h2 * LQ + qrow + rsel) * 64 + ksel;
  bf16x8 aq0h = *(const bf16x8*)(qhi + qoff), aq1h = *(const bf16x8*)(qhi + qoff + 32);
  const u16* kh = khi + (size_t)h2 * LQ * 64;

  const int srow = t >> 2;
  const int scol = (t & 3) * 16;

  int qm[4];
  float Z[4] = {0.f, 0.f, 0.f, 0.f};
#pragma unroll
  for (int j = 0; j < 4; ++j) qm[j] = (qrow + grp * 4 + j) & 511;

  const int kbeg = s * 512;
  int buf = 0;
  for (int jt = 0; jt <= c; ++jt) {             // computed tiles only
    const int kt = kbeg + jt * 64;
    const size_t kb = (size_t)(kt + srow) * 64 + scol;
    uint4 r0 = *(const uint4*)(kh + kb);
    uint4 r1 = *(const uint4*)(kh + kb + 8);
    *(uint4*)&Kh[buf][srow][scol] = r0;
    *(uint4*)&Kh[buf][srow][scol + 8] = r1;
    __syncthreads();   // K tile ready (dbuf protects against next-tile WAR)
#pragma unroll
    for (int fk = 0; fk < 4; ++fk) {
      const int krow = fk * 16 + rsel;
      const int k = kt + krow;
      bf16x8 b0 = *(const bf16x8*)&Kh[buf][krow][ksel];
      bf16x8 b1 = *(const bf16x8*)&Kh[buf][krow][ksel + 32];
      f32x4 z = {};
      z = MFMA16(aq0h, b0, z);
      z = MFMA16(aq1h, b1, z);
#pragma unroll
      for (int j = 0; j < 4; ++j)
        if ((k & 511) <= qm[j]) Z[j] += __expf(fabsf(z[j] * SCALING));
    }
    buf ^= 1;
  }
#pragma unroll
  for (int j = 0; j < 4; ++j) {
#pragma unroll
    for (int off = 1; off < 16; off <<= 1) Z[j] += __shfl_xor(Z[j], off);
    if (rsel == 0) {
      int q = qrow + grp * 4 + j;
      zp[((size_t)(s * 32 + h2) << 11) + q] = Z[j];
    }
  }
}

// ---- attention PV: 1D grid 2048 heavy-first, one 512-segment per block ----
__global__ __launch_bounds__(256) void attn_pv_kernel(
    const u16* __restrict__ qhi, const u16* __restrict__ qlo,
    const u16* __restrict__ khi, const u16* __restrict__ klo,
    const u16* __restrict__ vt, const float* __restrict__ zp,
    const float* __restrict__ lamp,
    float* __restrict__ O0, float* __restrict__ O123, float* __restrict__ colsum) {
  __shared__ u16 KhA[64][72], KlA[64][72], KhB[64][72], KlB[64][72];
  __shared__ u16 Vs[64][72];
  __shared__ u16 pcLDS[4][16][72];
  __shared__ float csLDS[2][4][64];

  const int bid = blockIdx.x;
  const int c = 7 - (bid >> 8);                 // heavy-first
  const int r = bid & 255;
  const int h = r & 15;
  const int qtIdx = (r >> 4) & 3;
  const int s = r >> 6;                         // 0..3
  const int qt = qtIdx * 8 + c;
  const int qb = qt * 64;
  const int t = threadIdx.x;
  const int lane = t & 63, wv = t >> 6;
  const int rsel = lane & 15, grp = lane >> 4, ksel = 8 * grp;
  const int qrow = qb + wv * 16;
  const float lam = lamp[0];

  const int h2a = 2 * h, h2b = 2 * h + 1;
  const size_t qoffa = ((size_t)h2a * LQ + qrow + rsel) * 64 + ksel;
  const size_t qoffb = ((size_t)h2b * LQ + qrow + rsel) * 64 + ksel;
  bf16x8 aqa0h = *(const bf16x8*)(qhi + qoffa), aqa1h = *(const bf16x8*)(qhi + qoffa + 32);
  bf16x8 aqa0l = *(const bf16x8*)(qlo + qoffa), aqa1l = *(const bf16x8*)(qlo + qoffa + 32);
  bf16x8 aqb0h = *(const bf16x8*)(qhi + qoffb), aqb1h = *(const bf16x8*)(qhi + qoffb + 32);
  bf16x8 aqb0l = *(const bf16x8*)(qlo + qoffb), aqb1l = *(const bf16x8*)(qlo + qoffb + 32);
  const u16* kha = khi + (size_t)h2a * LQ * 64;
  const u16* kla = klo + (size_t)h2a * LQ * 64;
  const u16* khb = khi + (size_t)h2b * LQ * 64;
  const u16* klb = klo + (size_t)h2b * LQ * 64;
  const u16* vb = vt + (size_t)h * 64 * LQ;

  // cooperative staging coords: thread t covers row t>>2, 16 cols at (t&3)*16
  const int srow = t >> 2;
  const int scol = (t & 3) * 16;

  int qm[4];
  float iz1[4], iz2[4];
#pragma unroll
  for (int j = 0; j < 4; ++j) {
    int q = qrow + grp * 4 + j;
    qm[j] = q & 511;
    float z1 = 0.f, z2 = 0.f;
#pragma unroll
    for (int ss = 0; ss < 4; ++ss) {
      z1 += zp[((size_t)(ss * 32 + h2a) << 11) + q];
      z2 += zp[((size_t)(ss * 32 + h2b) << 11) + q];
    }
    iz1[j] = 1.f / z1;
    iz2[j] = 1.f / z2;
  }

  f32x4 accO[4] = {};
  const int kbeg = s * 512;
  int buf = 0;

  // zero colsum for skipped (fully-masked) tiles of this segment
  for (int jt = c + 1; jt < 8; ++jt) {
    if (t < 64) colsum[((size_t)h * 32 + qt) * LQ + kbeg + jt * 64 + t] = 0.f;
  }

  // prologue: load tile 0 into registers
  uint4 rha0, rha1, rla0, rla1, rhb0, rhb1, rlb0, rlb1, rv0, rv1;
  {
    const size_t kb = (size_t)(kbeg + srow) * 64 + scol;
    rha0 = *(const uint4*)(kha + kb);
    rha1 = *(const uint4*)(kha + kb + 8);
    rla0 = *(const uint4*)(kla + kb);
    rla1 = *(const uint4*)(kla + kb + 8);
    rhb0 = *(const uint4*)(khb + kb);
    rhb1 = *(const uint4*)(khb + kb + 8);
    rlb0 = *(const uint4*)(klb + kb);
    rlb1 = *(const uint4*)(klb + kb + 8);
    const u16* vsrc = vb + (size_t)srow * LQ + kbeg + scol;
    rv0 = *(const uint4*)(vsrc);
    rv1 = *(const uint4*)(vsrc + 8);
  }

  for (int jt = 0; jt <= c; ++jt) {
    const int kt = kbeg + jt * 64;

    // write prefetched tile to LDS
    *(uint4*)&KhA[srow][scol] = rha0; *(uint4*)&KhA[srow][scol + 8] = rha1;
    *(uint4*)&KlA[srow][scol] = rla0; *(uint4*)&KlA[srow][scol + 8] = rla1;
    *(uint4*)&KhB[srow][scol] = rhb0; *(uint4*)&KhB[srow][scol + 8] = rhb1;
    *(uint4*)&KlB[srow][scol] = rlb0; *(uint4*)&KlB[srow][scol + 8] = rlb1;
    *(uint4*)&Vs[srow][scol] = rv0;  *(uint4*)&Vs[srow][scol + 8] = rv1;
    __syncthreads();   // K/V tile ready

    // ---- issue NEXT tile's global loads (latency hides under compute) ----
    if (jt < c) {
      const size_t kb = (size_t)(kt + 64 + srow) * 64 + scol;
      rha0 = *(const uint4*)(kha + kb);
      rha1 = *(const uint4*)(kha + kb + 8);
      rla0 = *(const uint4*)(kla + kb);
      rla1 = *(const uint4*)(kla + kb + 8);
      rhb0 = *(const uint4*)(khb + kb);
      rhb1 = *(const uint4*)(khb + kb + 8);
      rlb0 = *(const uint4*)(klb + kb);
      rlb1 = *(const uint4*)(klb + kb + 8);
      const u16* vsrc = vb + (size_t)srow * LQ + kt + 64 + scol;
      rv0 = *(const uint4*)(vsrc);
      rv1 = *(const uint4*)(vsrc + 8);
    }

    __builtin_amdgcn_s_setprio(1);
    float pc[4][4], cs[4];
#pragma unroll
    for (int fk = 0; fk < 4; ++fk) {
      const int krow = fk * 16 + rsel;
      const int k = kt + krow;
      f32x4 z = {};
      SCORE6(z, aqa0h, aqa1h, aqa0l, aqa1l, &KhA[krow][ksel], &KlA[krow][ksel]);
      f32x4 w = {};
      SCORE6(w, aqb0h, aqb1h, aqb0l, aqb1l, &KhB[krow][ksel], &KlB[krow][ksel]);
      float csj = 0.f;
#pragma unroll
      for (int j = 0; j < 4; ++j) {
        bool msk = ((k & 511) > qm[j]);
        float sa = z[j] * SCALING;
        float pa = __builtin_copysignf(__expf(fabsf(sa)) * iz1[j], sa);
        pa = msk ? 0.f : pa;
        csj += pa;
        float sb = w[j] * SCALING;
        float pb = __builtin_copysignf(__expf(fabsf(sb)) * iz2[j], sb);
        pc[fk][j] = pa - (msk ? 0.f : lam * pb);
      }
      cs[fk] = csj;
    }
    // pc relayout through OWN pcLDS slice (intra-wave, lgkmcnt-ordered)
#pragma unroll
    for (int fk = 0; fk < 4; ++fk)
#pragma unroll
      for (int j = 0; j < 4; ++j)
        pcLDS[wv][grp * 4 + j][fk * 16 + rsel] = f2b(pc[fk][j]);
    // PV (intra-wave; V read from LDS)
#pragma unroll
    for (int kc = 0; kc < 2; ++kc) {
      bf16x8 ap = *(const bf16x8*)&pcLDS[wv][rsel][kc * 32 + ksel];
#pragma unroll
      for (int fn = 0; fn < 4; ++fn) {
        bf16x8 bv = *(const bf16x8*)&Vs[fn * 16 + rsel][kc * 32 + ksel];
        accO[fn] = MFMA16(ap, bv, accO[fn]);
      }
    }
    __builtin_amdgcn_s_setprio(0);
    // cross-wave colsum (csLDS dbuf + barrier)
#pragma unroll
    for (int fk = 0; fk < 4; ++fk) {
      float cc = cs[fk];
      cc += __shfl_xor(cc, 16);
      cc += __shfl_xor(cc, 32);
      if (grp == 0) csLDS[buf][wv][fk * 16 + rsel] = cc;
    }
    __syncthreads();
    if (t < 64) {
      float tot = csLDS[buf][0][t] + csLDS[buf][1][t] + csLDS[buf][2][t] + csLDS[buf][3][t];
      colsum[((size_t)h * 32 + qt) * LQ + kt + t] = tot;
    }
    buf ^= 1;
  }
  float* Op = (s == 0) ? O0 : (O123 + (size_t)(s - 1) * 16 * LQ * 64);
#pragma unroll
  for (int fn = 0; fn < 4; ++fn)
#pragma unroll
    for (int j = 0; j < 4; ++j) {
      int q = qrow + grp * 4 + j;
      int d = fn * 16 + rsel;
      Op[((size_t)h * LQ + q) * 64 + d] = accO[fn][j];
    }
}

// g[h][k] = sum_qt colsum[h][qt][k] / 2048
__global__ void g_reduce_kernel(const float* __restrict__ colsum, float* __restrict__ g) {
  int idx = blockIdx.x * 256 + threadIdx.x;
  if (idx >= 16 * LQ) return;
  int h = idx >> 11, k = idx & 2047;
  float s = 0.f;
#pragma unroll
  for (int qt = 0; qt < 32; ++qt) s += colsum[((size_t)h * 32 + qt) * LQ + k];
  g[idx] = s * (1.f / 2048.f);
}

// W[h][r][d] = inclusive prefix over r of Gv[h][r][d], gv fused in
__global__ __launch_bounds__(512) void gv_wscan_kernel(const float* __restrict__ g,
                                                       const u16* __restrict__ vt,
                                                       float* __restrict__ W) {
  __shared__ float s[512];
  int h = blockIdx.x >> 6, d = blockIdx.x & 63;
  int t = threadIdx.x;  // r
  float v = 0.f;
#pragma unroll
  for (int seg = 0; seg < 4; ++seg) {
    int k = seg * 512 + t;
    v += g[h * 2048 + k] * b2f(vt[((size_t)h * 64 + d) * LQ + k]);
  }
  s[t] = v;
  __syncthreads();
  for (int off = 1; off < 512; off <<= 1) {
    float add = (t >= off) ? s[t - off] : 0.f;
    __syncthreads();
    s[t] += add;
    __syncthreads();
  }
  W[((size_t)h * 512 + t) * 64 + d] = s[t];
}

// out_pre = O0 + O1 + O2 + O3 + lam*W[q%512]; head rmsnorm -> bf16 [q][h*64+d]
__global__ __launch_bounds__(256) void combine_norm_kernel(
    const float* __restrict__ O0, const float* __restrict__ O123,
    const float* __restrict__ W, const float* __restrict__ hw,
    const float* __restrict__ lamp, u16* __restrict__ out) {
  const int q = blockIdx.x;
  const int h = blockIdx.y * 4 + (threadIdx.x >> 6);
  const int d = threadIdx.x & 63;
  const float lam = lamp[0];
  const size_t S = (size_t)16 * LQ * 64;
  const size_t idx = ((size_t)h * LQ + q) * 64 + d;
  float v = O0[idx] + O123[idx] + O123[idx + S] + O123[idx + 2 * S] +
            lam * W[((size_t)h * 512 + (q & 511)) * 64 + d];
  float ss = v * v;
#pragma unroll
  for (int off = 1; off < 64; off <<= 1) ss += __shfl_xor(ss, off);
  float sc = 1.f / sqrtf(ss * (1.f / 64.f) + 1e-5f);
  out[(size_t)q * 1024 + h * 64 + d] = f2b(v * sc * hw[d]);
}

// ============================== launch ==============================
extern "C" void kernel_launch(void* const* d_in, const int* in_sizes, int n_in,
                              void* d_out, int out_size, void* d_ws, size_t ws_size,
                              hipStream_t stream) {
  const float* x = (const float*)d_in[0];
  const float* freqs_r = (const float*)d_in[1];
  const float* freqs_i = (const float*)d_in[2];
  // d_in[3] = mask (recomputed analytically)
  const float* kv_down_w = (const float*)d_in[4];
  const float* q_down_w = (const float*)d_in[5];
  const float* kv_up_w = (const float*)d_in[6];
  const float* q_up_w = (const float*)d_in[7];
  const float* kv_norm_w = (const float*)d_in[8];
  const float* q_norm_w = (const float*)d_in[9];
  const float* o_w = (const float*)d_in[10];
  const float* lambda_q1 = (const float*)d_in[11];
  const float* lambda_k1 = (const float*)d_in[12];
  const float* lambda_q2 = (const float*)d_in[13];
  const float* lambda_k2 = (const float*)d_in[14];
  const float* head_norm_w = (const float*)d_in[15];
  const float* norm1_w = (const float*)d_in[16];
  const float* norm2_w = (const float*)d_in[17];
  const float* ff_in_w = (const float*)d_in[18];
  const float* ff_out_w = (const float*)d_in[19];
  float* out = (float*)d_out;
  char* ws = (char*)d_ws;

  // ---- weights region (persistent except down/up: dead after projections) ----
  const size_t WT_KVD_H = 0;                                  // 544x1024 bf16
  const size_t WT_KVD_L = WT_KVD_H + (size_t)544 * 1024 * 2;
  const size_t WT_QD_H  = WT_KVD_L + (size_t)544 * 1024 * 2;  // 512x1024
  const size_t WT_QD_L  = WT_QD_H + (size_t)512 * 1024 * 2;
  const size_t WT_KVU_H = WT_QD_L + (size_t)512 * 1024 * 2;   // 2048x512
  const size_t WT_KVU_L = WT_KVU_H + (size_t)2048 * 512 * 2;
  const size_t WT_QU_H  = WT_KVU_L + (size_t)2048 * 512 * 2;  // 1536x512
  const size_t WT_QU_L  = WT_QU_H + (size_t)1536 * 512 * 2;
  const size_t WT_OW    = WT_QU_L + (size_t)1536 * 512 * 2;   // = 11,714,560
  const size_t WT_FFI   = WT_OW + (size_t)1024 * 1024 * 2;
  const size_t WT_FFO   = WT_FFI + (size_t)8192 * 1024 * 2;
  const size_t A0 = WT_FFO + (size_t)1024 * 4096 * 2;         // = 38,928,384

  // ---- activations (lifetime-aliased) ----
  const size_t H     = A0;                  // h hi/lo bf16 (2x 4,194,304); dead after down-GEMMs
  const size_t CKV   = A0 + 8388608;        // f32 2048x544;  dead after build_kh
  const size_t CKVN  = A0 + 12845056;       // ckvn hi/lo bf16 (2x 2,097,152); dead after kv_up
  const size_t KVB   = A0 + 17039360;       // f32 2048x2048; dead after build_vt
  const size_t CQ    = A0 + 33816576;       // f32 2048x512;  dead after rmsnorm
  const size_t CQN   = A0 + 38010880;       // cqn hi/lo bf16 (2x 2,097,152); dead after q_up
  const size_t QFULL = A0 + 42205184;       // f32 2048x1536; dead after build_qh
  // mid buffers (aliases):
  const size_t QHI = H;                     // bf16 32x2048x64 over dead H
  const size_t KHI = QFULL;                 // bf16 32x2048x64 over dead QFULL[0:8.39M]
  const size_t KLO = A0 + 50593792;         // bf16 32x2048x64 over dead QFULL[8.39M:]+
  const size_t QLO = A0 + 58982400;         // bf16 32x2048x64
  const size_t VT  = CKVN;                  // bf16 16x64x2048 over dead CKVN
  // O partials (4 x 8,388,608 f32):
  const size_t OP0   = 0;                   // over dead down/up weights [0, 8.39M) < WT_OW
  const size_t OP123 = KVB;                 // 3 contiguous partials over dead KVB+CQ+CQN
  const size_t CS  = CKV;                   // f32 16x32x2048 over dead CKV
  const size_t GB  = A0 + 67371008;         // f32 16x2048 (131,072)
  const size_t WB  = A0 + 69599232;         // f32 16x512x64 (2,097,152)
  const size_t LAM = A0 + 71696384;         // scalar
  const size_t ZP  = A0 + 71696640;         // f32 4x32x2048 (1,048,576)
  const size_t WS_END = A0 + 72745216;      // ~111.7 MB (known-safe)
  // late aliases:
  const size_t ATTN  = CKV;                 // bf16 2048x1024 (over consumed CS)
  const size_t X1    = KVB + 8388608;       // f32 2048x1024 (partials consumed by combine)
  const size_t H2N   = H;                   // bf16 2048x1024 over dead QHI
  const size_t FFACT = QFULL;               // bf16 2048x4096 over dead KHI+KLO

  if (ws_size < WS_END) return;

  u16* wt_kvd_h = (u16*)(ws + WT_KVD_H); u16* wt_kvd_l = (u16*)(ws + WT_KVD_L);
  u16* wt_qd_h  = (u16*)(ws + WT_QD_H);  u16* wt_qd_l  = (u16*)(ws + WT_QD_L);
  u16* wt_kvu_h = (u16*)(ws + WT_KVU_H); u16* wt_kvu_l = (u16*)(ws + WT_KVU_L);
  u16* wt_qu_h  = (u16*)(ws + WT_QU_H);  u16* wt_qu_l  = (u16*)(ws + WT_QU_L);
  u16* wt_ow  = (u16*)(ws + WT_OW);
  u16* wt_ffi = (u16*)(ws + WT_FFI);
  u16* wt_ffo = (u16*)(ws + WT_FFO);
  u16* h_hi   = (u16*)(ws + H);
  u16* h_lo   = (u16*)(ws + H + 4194304);
  float* ckv  = (float*)(ws + CKV);
  u16* ckvn_hi = (u16*)(ws + CKVN);
  u16* ckvn_lo = (u16*)(ws + CKVN + 2097152);
  float* kvb  = (float*)(ws + KVB);
  float* cq   = (float*)(ws + CQ);
  u16* cqn_hi = (u16*)(ws + CQN);
  u16* cqn_lo = (u16*)(ws + CQN + 2097152);
  float* qfull = (float*)(ws + QFULL);
  u16* qhib = (u16*)(ws + QHI); u16* qlob = (u16*)(ws + QLO);
  u16* khib = (u16*)(ws + KHI); u16* klob = (u16*)(ws + KLO);
  u16* vtb  = (u16*)(ws + VT);
  float* zpb = (float*)(ws + ZP);
  float* Op0 = (float*)(ws + OP0);
  float* Op123 = (float*)(ws + OP123);
  float* csb = (float*)(ws + CS);
  float* gb  = (float*)(ws + GB);
  float* wbb = (float*)(ws + WB);
  float* lamp = (float*)(ws + LAM);
  u16* attn_n = (u16*)(ws + ATTN);
  float* x1 = (float*)(ws + X1);
  u16* h2n = (u16*)(ws + H2N);
  u16* ffact = (u16*)(ws + FFACT);

  // fused weight prep + rmsnorm(x) (16160 transpose blocks + 2048 rmsnorm rows)
  prep_weights_kernel<<<18208, dim3(32, 8), 0, stream>>>(
      kv_down_w, wt_kvd_h, wt_kvd_l, q_down_w, wt_qd_h, wt_qd_l,
      kv_up_w, wt_kvu_h, wt_kvu_l, q_up_w, wt_qu_h, wt_qu_l,
      o_w, wt_ow, ff_in_w, wt_ffi, ff_out_w, wt_ffo,
      x, norm1_w, h_hi, h_lo);

  // both down-projections (share A = h)
  gemm_split<<<dim3(9, 32), 256, 0, stream>>>(h_hi, h_lo, wt_kvd_h, wt_kvd_l, ckv,
                                              2048, 544, 1024);
  gemm_split<<<dim3(8, 32), 256, 0, stream>>>(h_hi, h_lo, wt_qd_h, wt_qd_l, cq,
                                              2048, 512, 1024);
  // fused rmsnorm of ckv (stride 544) + cq (stride 512)
  rmsnorm_split2_kernel<<<4096, 256, 0, stream>>>(ckv, kv_norm_w, ckvn_hi, ckvn_lo, 544,
                                                  cq, q_norm_w, cqn_hi, cqn_lo, 512);
  gemm_split<<<dim3(32, 32), 256, 0, stream>>>(ckvn_hi, ckvn_lo, wt_kvu_h, wt_kvu_l, kvb,
                                               2048, 2048, 512);
  gemm_split<<<dim3(24, 32), 256, 0, stream>>>(cqn_hi, cqn_lo, wt_qu_h, wt_qu_l, qfull,
                                               2048, 1536, 512);

  // fused mid build (build_qh + build_kh + build_vt + lam -> 1 kernel)
  build_mid_kernel<<<33281, 256, 0, stream>>>(qfull, kvb, ckv, freqs_r, freqs_i,
                                              qhib, qlob, khib, klob, vtb,
                                              lambda_q1, lambda_k1, lambda_q2, lambda_k2,
                                              lamp);

  attn_z_kernel<<<4096, 256, 0, stream>>>(qhib, khib, zpb);
  attn_pv_kernel<<<2048, 256, 0, stream>>>(qhib, qlob, khib, klob, vtb, zpb,
                                           lamp, Op0, Op123, csb);

  g_reduce_kernel<<<128, 256, 0, stream>>>(csb, gb);
  gv_wscan_kernel<<<1024, 512, 0, stream>>>(gb, vtb, wbb);
  combine_norm_kernel<<<dim3(2048, 4), 256, 0, stream>>>(Op0, Op123, wbb, head_norm_w,
                                                         lamp, attn_n);

  // x1 = x + attn_n @ o_w  (residual fused into epilogue)
  gemm_kernel<0, 1><<<dim3(16, 32), 256, 0, stream>>>(attn_n, wt_ow, x, x1, nullptr,
                                                      2048, 1024, 1024);
  rmsnorm_kernel<1><<<2048, 256, 0, stream>>>(x1, norm2_w, h2n, 1024, 1024, FEPS);
  // gated FFN-in: M=128 x N=64 tiles (1024 blocks)
  gemm_m128_gated<<<dim3(64, 16), 256, 0, stream>>>(h2n, wt_ffi, ffact, 2048, 4096, 1024);
  // out = x1 + ffact @ ff_out  (residual fused into epilogue)
  gemm_kernel<0, 1><<<dim3(16, 32), 256, 0, stream>>>(ffact, wt_ffo, x1, out, nullptr,
                                                      2048, 1024, 4096);
}

// Round 27
// 350.078 us; speedup vs baseline: 1.1629x; 1.0053x over previous
//
#include <hip/hip_runtime.h>
#include <math.h>

#define LQ 2048
#define SCALING 0.14433756729740643f   // 48^-0.5
#define FEPS 1.1920928955078125e-07f   // np.finfo(float32).eps

typedef unsigned short u16;
typedef __attribute__((ext_vector_type(8))) short bf16x8;
typedef __attribute__((ext_vector_type(4))) float f32x4;

#define MFMA16(a, b, c) __builtin_amdgcn_mfma_f32_16x16x32_bf16((a), (b), (c), 0, 0, 0)

__device__ __forceinline__ u16 f2b(float x) {
  union { float f; unsigned u; } v; v.f = x;
  return (u16)((v.u + 0x7FFFu + ((v.u >> 16) & 1u)) >> 16);
}
__device__ __forceinline__ float b2f(u16 b) {
  union { unsigned u; float f; } v; v.u = ((unsigned)b) << 16;
  return v.f;
}

// ---- fused weight prep: 7 transposes + rmsnorm_split(x) in one kernel ----
__global__ __launch_bounds__(256) void prep_weights_kernel(
    const float* __restrict__ kvd, u16* __restrict__ kvd_h, u16* __restrict__ kvd_l,
    const float* __restrict__ qd,  u16* __restrict__ qd_h,  u16* __restrict__ qd_l,
    const float* __restrict__ kvu, u16* __restrict__ kvu_h, u16* __restrict__ kvu_l,
    const float* __restrict__ qu,  u16* __restrict__ qu_h,  u16* __restrict__ qu_l,
    const float* __restrict__ ow,  u16* __restrict__ ow_t,
    const float* __restrict__ ffi, u16* __restrict__ ffi_t,
    const float* __restrict__ ffo, u16* __restrict__ ffo_t,
    const float* __restrict__ x, const float* __restrict__ norm1_w,
    u16* __restrict__ h_hi, u16* __restrict__ h_lo) {
  __shared__ float tile[32][33];
  __shared__ float red[4];
  int id = blockIdx.x;

  if (id >= 16160) {
    // ---- rmsnorm_split of x: row = id - 16160, cols 1024 ----
    const int row = id - 16160;
    const int tid = threadIdx.y * 32 + threadIdx.x;  // flat 0..255
    const float* xr = x + (size_t)row * 1024;
    float ss = 0.f;
    for (int c = tid; c < 1024; c += 256) { float v = xr[c]; ss = fmaf(v, v, ss); }
#pragma unroll
    for (int off = 32; off > 0; off >>= 1) ss += __shfl_xor(ss, off);
    if ((tid & 63) == 0) red[tid >> 6] = ss;
    __syncthreads();
    float tot = red[0] + red[1] + red[2] + red[3];
    float sc = 1.f / sqrtf(tot / 1024.f + FEPS);
    for (int c = tid; c < 1024; c += 256) {
      float v = xr[c] * sc * norm1_w[c];
      u16 hi = f2b(v);
      h_hi[(size_t)row * 1024 + c] = hi;
      h_lo[(size_t)row * 1024 + c] = f2b(v - b2f(hi));
    }
    return;
  }

  const float* W; u16* Whi; u16* Wlo = nullptr; int K, N, bx, by;
  if (id < 8192) {                       // ff_in 1024x8192 (heaviest first)
    W = ffi; Whi = ffi_t; K = 1024; N = 8192; bx = id % 256; by = id / 256;
  } else if (id < 8192 + 4096) {         // ff_out 4096x1024
    id -= 8192;
    W = ffo; Whi = ffo_t; K = 4096; N = 1024; bx = id % 32; by = id / 32;
  } else if (id < 12288 + 1024) {        // o_w 1024x1024
    id -= 12288;
    W = ow; Whi = ow_t; K = 1024; N = 1024; bx = id % 32; by = id / 32;
  } else if (id < 13312 + 544) {         // kv_down 1024x544 (split)
    id -= 13312;
    W = kvd; Whi = kvd_h; Wlo = kvd_l; K = 1024; N = 544; bx = id % 17; by = id / 17;
  } else if (id < 13856 + 512) {         // q_down 1024x512 (split)
    id -= 13856;
    W = qd; Whi = qd_h; Wlo = qd_l; K = 1024; N = 512; bx = id % 16; by = id / 16;
  } else if (id < 14368 + 1024) {        // kv_up 512x2048 (split)
    id -= 14368;
    W = kvu; Whi = kvu_h; Wlo = kvu_l; K = 512; N = 2048; bx = id % 64; by = id / 64;
  } else {                               // q_up 512x1536 (split)
    id -= 15392;
    W = qu; Whi = qu_h; Wlo = qu_l; K = 512; N = 1536; bx = id % 48; by = id / 48;
  }

  int n0 = bx * 32, k0 = by * 32;
  int tx = threadIdx.x, ty = threadIdx.y;  // 32 x 8
  for (int i = ty; i < 32; i += 8) {
    int k = k0 + i, n = n0 + tx;
    tile[i][tx] = (k < K && n < N) ? W[(size_t)k * N + n] : 0.f;
  }
  __syncthreads();
  for (int i = ty; i < 32; i += 8) {
    int n = n0 + i, k = k0 + tx;
    if (n < N && k < K) {
      float xv = tile[tx][i];
      u16 hi = f2b(xv);
      Whi[(size_t)n * K + k] = hi;
      if (Wlo) Wlo[(size_t)n * K + k] = f2b(xv - b2f(hi));
    }
  }
}

// ---------------- rmsnorm fp32 in (strided) -> fp32 or bf16 out ----------------
template <int BF16OUT>
__global__ __launch_bounds__(256) void rmsnorm_kernel(
    const float* __restrict__ x, const float* __restrict__ w, void* __restrict__ outv,
    int cols, int in_stride, float eps) {
  const int row = blockIdx.x;
  const float* xr = x + (size_t)row * in_stride;
  float ss = 0.f;
  for (int c = threadIdx.x; c < cols; c += 256) { float v = xr[c]; ss = fmaf(v, v, ss); }
#pragma unroll
  for (int off = 32; off > 0; off >>= 1) ss += __shfl_xor(ss, off);
  __shared__ float red[4];
  if ((threadIdx.x & 63) == 0) red[threadIdx.x >> 6] = ss;
  __syncthreads();
  float tot = red[0] + red[1] + red[2] + red[3];
  float sc = 1.f / sqrtf(tot / (float)cols + eps);
  for (int c = threadIdx.x; c < cols; c += 256) {
    float v = xr[c] * sc * w[c];
    if (BF16OUT) ((u16*)outv)[(size_t)row * cols + c] = f2b(v);
    else ((float*)outv)[(size_t)row * cols + c] = v;
  }
}

// ---- fused pair: rmsnorm_split for ckv (cols 512, stride 544) + cq (512/512) ----
__global__ __launch_bounds__(256) void rmsnorm_split2_kernel(
    const float* __restrict__ in0, const float* __restrict__ w0,
    u16* __restrict__ hi0, u16* __restrict__ lo0, int stride0,
    const float* __restrict__ in1, const float* __restrict__ w1,
    u16* __restrict__ hi1, u16* __restrict__ lo1, int stride1) {
  int row = blockIdx.x;
  const float* xr; const float* w; u16* ho; u16* lo;
  if (row < 2048) {
    xr = in0 + (size_t)row * stride0; w = w0;
    ho = hi0 + (size_t)row * 512; lo = lo0 + (size_t)row * 512;
  } else {
    row -= 2048;
    xr = in1 + (size_t)row * stride1; w = w1;
    ho = hi1 + (size_t)row * 512; lo = lo1 + (size_t)row * 512;
  }
  float ss = 0.f;
  for (int c = threadIdx.x; c < 512; c += 256) { float v = xr[c]; ss = fmaf(v, v, ss); }
#pragma unroll
  for (int off = 32; off > 0; off >>= 1) ss += __shfl_xor(ss, off);
  __shared__ float red[4];
  if ((threadIdx.x & 63) == 0) red[threadIdx.x >> 6] = ss;
  __syncthreads();
  float tot = red[0] + red[1] + red[2] + red[3];
  float sc = 1.f / sqrtf(tot / 512.f + FEPS);
  for (int c = threadIdx.x; c < 512; c += 256) {
    float v = xr[c] * sc * w[c];
    u16 hi = f2b(v);
    ho[c] = hi;
    lo[c] = f2b(v - b2f(hi));
  }
}

// ---- split-precision GEMM (3-term), all-bf16 staging ----
__global__ __launch_bounds__(256) void gemm_split(
    const u16* __restrict__ Ahi, const u16* __restrict__ Alo,
    const u16* __restrict__ Bhi, const u16* __restrict__ Blo,
    float* __restrict__ C, int M, int N, int K) {
  __shared__ u16 Ah[64][72];
  __shared__ u16 Al[64][72];
  __shared__ u16 Bh[64][72];
  __shared__ u16 Bl[64][72];

  const int t = threadIdx.x;
  const int lane = t & 63;
  const int wv = t >> 6;
  const int wr = (wv >> 1) * 32;
  const int wc = (wv & 1) * 32;
  const int bm = blockIdx.y * 64;
  const int bn = blockIdx.x * 64;
  const int lr = t >> 2;
  const int lc = (t & 3) * 16;
  const int rsel = lane & 15;
  const int ksel = 8 * (lane >> 4);

  const u16* Ahrow = Ahi + (size_t)(bm + lr) * K + lc;
  const u16* Alrow = Alo + (size_t)(bm + lr) * K + lc;
  const bool bval = (bn + lr) < N;
  const u16* Bhrow = Bhi + (size_t)(bn + lr) * K + lc;
  const u16* Blrow = Blo + (size_t)(bn + lr) * K + lc;

  f32x4 acc[2][2] = {};

  for (int kt = 0; kt < K; kt += 64) {
    uint4 ah0 = *(const uint4*)(Ahrow + kt);
    uint4 ah1 = *(const uint4*)(Ahrow + kt + 8);
    uint4 al0 = *(const uint4*)(Alrow + kt);
    uint4 al1 = *(const uint4*)(Alrow + kt + 8);
    uint4 bh0 = {0, 0, 0, 0}, bh1 = {0, 0, 0, 0}, bl0 = {0, 0, 0, 0}, bl1 = {0, 0, 0, 0};
    if (bval) {
      bh0 = *(const uint4*)(Bhrow + kt); bh1 = *(const uint4*)(Bhrow + kt + 8);
      bl0 = *(const uint4*)(Blrow + kt); bl1 = *(const uint4*)(Blrow + kt + 8);
    }
    __syncthreads();
    *(uint4*)&Ah[lr][lc] = ah0; *(uint4*)&Ah[lr][lc + 8] = ah1;
    *(uint4*)&Al[lr][lc] = al0; *(uint4*)&Al[lr][lc + 8] = al1;
    *(uint4*)&Bh[lr][lc] = bh0; *(uint4*)&Bh[lr][lc + 8] = bh1;
    *(uint4*)&Bl[lr][lc] = bl0; *(uint4*)&Bl[lr][lc + 8] = bl1;
    __syncthreads();
#pragma unroll
    for (int ks = 0; ks < 2; ++ks) {
      const int ko = ks * 32 + ksel;
      bf16x8 a0h = *(const bf16x8*)&Ah[wr + rsel][ko];
      bf16x8 a1h = *(const bf16x8*)&Ah[wr + 16 + rsel][ko];
      bf16x8 a0l = *(const bf16x8*)&Al[wr + rsel][ko];
      bf16x8 a1l = *(const bf16x8*)&Al[wr + 16 + rsel][ko];
      bf16x8 b0h = *(const bf16x8*)&Bh[wc + rsel][ko];
      bf16x8 b1h = *(const bf16x8*)&Bh[wc + 16 + rsel][ko];
      bf16x8 b0l = *(const bf16x8*)&Bl[wc + rsel][ko];
      bf16x8 b1l = *(const bf16x8*)&Bl[wc + 16 + rsel][ko];
      acc[0][0] = MFMA16(a0h, b0h, acc[0][0]);
      acc[0][0] = MFMA16(a0h, b0l, acc[0][0]);
      acc[0][0] = MFMA16(a0l, b0h, acc[0][0]);
      acc[0][1] = MFMA16(a0h, b1h, acc[0][1]);
      acc[0][1] = MFMA16(a0h, b1l, acc[0][1]);
      acc[0][1] = MFMA16(a0l, b1h, acc[0][1]);
      acc[1][0] = MFMA16(a1h, b0h, acc[1][0]);
      acc[1][0] = MFMA16(a1h, b0l, acc[1][0]);
      acc[1][0] = MFMA16(a1l, b0h, acc[1][0]);
      acc[1][1] = MFMA16(a1h, b1h, acc[1][1]);
      acc[1][1] = MFMA16(a1h, b1l, acc[1][1]);
      acc[1][1] = MFMA16(a1l, b1h, acc[1][1]);
    }
  }
  const int r0 = (lane >> 4) * 4;
#pragma unroll
  for (int fm = 0; fm < 2; ++fm)
#pragma unroll
    for (int fn = 0; fn < 2; ++fn)
#pragma unroll
      for (int j = 0; j < 4; ++j) {
        int row = bm + wr + fm * 16 + r0 + j;
        int col = bn + wc + fn * 16 + rsel;
        if (col < N) C[(size_t)row * N + col] = acc[fm][fn][j];
      }
}

// ---- plain bf16 GEMM (o_w / FFN-out): 64x64 reg-staged. ADDX fuses residual add. ----
template <int GATED, int ADDX>
__global__ __launch_bounds__(256) void gemm_kernel(
    const u16* __restrict__ A, const u16* __restrict__ Bt, const float* __restrict__ X,
    float* __restrict__ C, u16* __restrict__ Cg, int M, int N, int K) {
  __shared__ u16 As[64][72];
  __shared__ u16 Bs[64][72];
  __shared__ u16 Bs2[GATED ? 64 : 1][72];

  const int t = threadIdx.x;
  const int lane = t & 63;
  const int wv = t >> 6;
  const int wr = (wv >> 1) * 32;
  const int wc = (wv & 1) * 32;
  const int bm = blockIdx.y * 64;
  const int bn = blockIdx.x * 64;
  const int lr = t >> 2;
  const int lc = (t & 3) * 16;
  const int rsel = lane & 15;
  const int ksel = 8 * (lane >> 4);

  const u16* Arow = A + (size_t)(bm + lr) * K + lc;
  const u16* Brow = Bt + (size_t)(bn + lr) * K + lc;
  const u16* Brow2 = Bt + (size_t)(4096 + bn + lr) * K + lc;

  f32x4 acc[2][2] = {};
  f32x4 accg[2][2] = {};

  for (int kt = 0; kt < K; kt += 64) {
    uint4 a0 = *(const uint4*)(Arow + kt);
    uint4 a1 = *(const uint4*)(Arow + kt + 8);
    uint4 b0 = *(const uint4*)(Brow + kt);
    uint4 b1 = *(const uint4*)(Brow + kt + 8);
    uint4 c0 = {0, 0, 0, 0}, c1 = {0, 0, 0, 0};
    if (GATED) { c0 = *(const uint4*)(Brow2 + kt); c1 = *(const uint4*)(Brow2 + kt + 8); }
    __syncthreads();
    *(uint4*)&As[lr][lc] = a0; *(uint4*)&As[lr][lc + 8] = a1;
    *(uint4*)&Bs[lr][lc] = b0; *(uint4*)&Bs[lr][lc + 8] = b1;
    if (GATED) { *(uint4*)&Bs2[lr][lc] = c0; *(uint4*)&Bs2[lr][lc + 8] = c1; }
    __syncthreads();
#pragma unroll
    for (int ks = 0; ks < 2; ++ks) {
      const int ko = ks * 32 + ksel;
      bf16x8 af0 = *(const bf16x8*)&As[wr + rsel][ko];
      bf16x8 af1 = *(const bf16x8*)&As[wr + 16 + rsel][ko];
      bf16x8 bf0 = *(const bf16x8*)&Bs[wc + rsel][ko];
      bf16x8 bf1 = *(const bf16x8*)&Bs[wc + 16 + rsel][ko];
      acc[0][0] = MFMA16(af0, bf0, acc[0][0]);
      acc[0][1] = MFMA16(af0, bf1, acc[0][1]);
      acc[1][0] = MFMA16(af1, bf0, acc[1][0]);
      acc[1][1] = MFMA16(af1, bf1, acc[1][1]);
      if (GATED) {
        bf16x8 cf0 = *(const bf16x8*)&Bs2[wc + rsel][ko];
        bf16x8 cf1 = *(const bf16x8*)&Bs2[wc + 16 + rsel][ko];
        accg[0][0] = MFMA16(af0, cf0, accg[0][0]);
        accg[0][1] = MFMA16(af0, cf1, accg[0][1]);
        accg[1][0] = MFMA16(af1, cf0, accg[1][0]);
        accg[1][1] = MFMA16(af1, cf1, accg[1][1]);
      }
    }
  }
  const int r0 = (lane >> 4) * 4;
#pragma unroll
  for (int fm = 0; fm < 2; ++fm)
#pragma unroll
    for (int fn = 0; fn < 2; ++fn)
#pragma unroll
      for (int j = 0; j < 4; ++j) {
        int row = bm + wr + fm * 16 + r0 + j;
        int col = bn + wc + fn * 16 + rsel;
        size_t o = (size_t)row * N + col;
        if (!GATED) {
          float v = acc[fm][fn][j];
          if (ADDX) v += X[o];
          C[o] = v;
        } else {
          float u = acc[fm][fn][j], g = accg[fm][fn][j];
          float sv = g / (1.f + __expf(-g));
          Cg[o] = f2b(u * sv);
        }
      }
}

// ---- gated FFN-in GEMM, M=128 x N=64 tile (1024 blocks) ----
__global__ __launch_bounds__(256) void gemm_m128_gated(
    const u16* __restrict__ A, const u16* __restrict__ Bt,
    u16* __restrict__ Cg, int M, int N, int K) {
  __shared__ u16 As[128][72];
  __shared__ u16 Bs[64][72];
  __shared__ u16 Bs2[64][72];

  const int t = threadIdx.x;
  const int lane = t & 63;
  const int wv = t >> 6;
  const int bm = blockIdx.y * 128;
  const int bn = blockIdx.x * 64;
  const int lr = t >> 2;              // staging row 0..63
  const int lc = (t & 3) * 16;        // staging col
  const int rsel = lane & 15;
  const int ksel = 8 * (lane >> 4);

  const u16* Arow0 = A + (size_t)(bm + lr) * K + lc;
  const u16* Arow1 = A + (size_t)(bm + 64 + lr) * K + lc;
  const u16* Brow = Bt + (size_t)(bn + lr) * K + lc;
  const u16* Brow2 = Bt + (size_t)(4096 + bn + lr) * K + lc;

  f32x4 acc[2][4] = {};
  f32x4 accg[2][4] = {};

  for (int kt = 0; kt < K; kt += 64) {
    uint4 a00 = *(const uint4*)(Arow0 + kt);
    uint4 a01 = *(const uint4*)(Arow0 + kt + 8);
    uint4 a10 = *(const uint4*)(Arow1 + kt);
    uint4 a11 = *(const uint4*)(Arow1 + kt + 8);
    uint4 b0 = *(const uint4*)(Brow + kt);
    uint4 b1 = *(const uint4*)(Brow + kt + 8);
    uint4 c0 = *(const uint4*)(Brow2 + kt);
    uint4 c1 = *(const uint4*)(Brow2 + kt + 8);
    __syncthreads();
    *(uint4*)&As[lr][lc] = a00; *(uint4*)&As[lr][lc + 8] = a01;
    *(uint4*)&As[64 + lr][lc] = a10; *(uint4*)&As[64 + lr][lc + 8] = a11;
    *(uint4*)&Bs[lr][lc] = b0; *(uint4*)&Bs[lr][lc + 8] = b1;
    *(uint4*)&Bs2[lr][lc] = c0; *(uint4*)&Bs2[lr][lc + 8] = c1;
    __syncthreads();
#pragma unroll
    for (int ks = 0; ks < 2; ++ks) {
      const int ko = ks * 32 + ksel;
      bf16x8 af0 = *(const bf16x8*)&As[wv * 32 + rsel][ko];
      bf16x8 af1 = *(const bf16x8*)&As[wv * 32 + 16 + rsel][ko];
      bf16x8 bf[4];
#pragma unroll
      for (int fn = 0; fn < 4; ++fn)
        bf[fn] = *(const bf16x8*)&Bs[fn * 16 + rsel][ko];
#pragma unroll
      for (int fn = 0; fn < 4; ++fn) {
        acc[0][fn] = MFMA16(af0, bf[fn], acc[0][fn]);
        acc[1][fn] = MFMA16(af1, bf[fn], acc[1][fn]);
      }
      bf16x8 cf[4];
#pragma unroll
      for (int fn = 0; fn < 4; ++fn)
        cf[fn] = *(const bf16x8*)&Bs2[fn * 16 + rsel][ko];
#pragma unroll
      for (int fn = 0; fn < 4; ++fn) {
        accg[0][fn] = MFMA16(af0, cf[fn], accg[0][fn]);
        accg[1][fn] = MFMA16(af1, cf[fn], accg[1][fn]);
      }
    }
  }
  const int r0 = (lane >> 4) * 4;
#pragma unroll
  for (int fm = 0; fm < 2; ++fm)
#pragma unroll
    for (int fn = 0; fn < 4; ++fn)
#pragma unroll
      for (int j = 0; j < 4; ++j) {
        int row = bm + wv * 32 + fm * 16 + r0 + j;
        int col = bn + fn * 16 + rsel;
        size_t o = (size_t)row * N + col;
        float u = acc[fm][fn][j], g = accg[fm][fn][j];
        float sv = g / (1.f + __expf(-g));
        Cg[o] = f2b(u * sv);
      }
}

// ---- fused mid build: build_qh + build_kh + build_vt + lam in one kernel ----
__global__ __launch_bounds__(256) void build_mid_kernel(
    const float* __restrict__ qfull, const float* __restrict__ kv,
    const float* __restrict__ ckv, const float* __restrict__ fr,
    const float* __restrict__ fi, u16* __restrict__ qhi, u16* __restrict__ qlo,
    u16* __restrict__ khi, u16* __restrict__ klo, u16* __restrict__ vt,
    const float* __restrict__ lq1, const float* __restrict__ lk1,
    const float* __restrict__ lq2, const float* __restrict__ lk2,
    float* __restrict__ lamp) {
  __shared__ u16 tile[64][65];
  int id = blockIdx.x;
  if (id < 16384) {
    // ---- build_qh ----
    const int q = id & 2047;
    const int h2 = ((id >> 11) << 2) + (threadIdx.x >> 6);
    const int d = threadIdx.x & 63;
    const int hh = h2 >> 1, s = h2 & 1;
    const float* row = qfull + (size_t)q * 1536 + hh * 96;
    float val;
    if (d < 32) {
      val = row[s * 32 + d];
    } else if (d < 48) {
      int r = d - 32;
      int pos = q & 511;
      const float* rp = row + 64 + s * 16;
      if (pos == 0) val = rp[r];
      else {
        int j = r >> 1;
        float cr = fr[(pos - 1) * 8 + j], ci = fi[(pos - 1) * 8 + j];
        float a = rp[2 * j], b = rp[2 * j + 1];
        val = (r & 1) ? (a * ci + b * cr) : (a * cr - b * ci);
      }
    } else val = 0.f;
    u16 hi = f2b(val);
    qhi[((size_t)h2 * LQ + q) * 64 + d] = hi;
    qlo[((size_t)h2 * LQ + q) * 64 + d] = f2b(val - b2f(hi));
    return;
  }
  id -= 16384;
  if (id < 16384) {
    // ---- build_kh ----
    const int kp = id & 2047;
    const int h2 = ((id >> 11) << 2) + (threadIdx.x >> 6);
    const int d = threadIdx.x & 63;
    const int hh = h2 >> 1, s = h2 & 1;
    float val;
    if (d < 32) {
      val = kv[(size_t)kp * 2048 + hh * 128 + s * 32 + d];
    } else if (d < 48) {
      int r = d - 32;
      int pos = kp & 511;
      const float* rp = ckv + (size_t)kp * 544 + 512 + s * 16;
      if (pos == 0) val = rp[r];
      else {
        int j = r >> 1;
        float cr = fr[(pos - 1) * 8 + j], ci = fi[(pos - 1) * 8 + j];
        float a = rp[2 * j], b = rp[2 * j + 1];
        val = (r & 1) ? (a * ci + b * cr) : (a * cr - b * ci);
      }
    } else val = 0.f;
    u16 hi = f2b(val);
    khi[((size_t)h2 * LQ + kp) * 64 + d] = hi;
    klo[((size_t)h2 * LQ + kp) * 64 + d] = f2b(val - b2f(hi));
    return;
  }
  id -= 16384;
  if (id < 512) {
    // ---- build_vt: vt[h][d][k] = bf16(kv[k][h*128+64+d]) ----
    int h = id >> 5, k0 = (id & 31) * 64;
    int t = threadIdx.x;
    int d = t & 63, kr = t >> 6;
#pragma unroll
    for (int i = 0; i < 16; ++i) {
      int k = kr + i * 4;
      tile[k][d] = f2b(kv[(size_t)(k0 + k) * 2048 + h * 128 + 64 + d]);
    }
    __syncthreads();
    int kk = t & 63, dr = t >> 6;
#pragma unroll
    for (int i = 0; i < 16; ++i) {
      int d2 = dr + i * 4;
      vt[((size_t)h * 64 + d2) * LQ + k0 + kk] = tile[kk][d2];
    }
    return;
  }
  // ---- lam = exp(sum(lk1*lq1)) - exp(sum(lk2*lq2)) + 0.2 ----
  int t = threadIdx.x;
  if (t < 32) {
    float a = lq1[t] * lk1[t], b = lq2[t] * lk2[t];
#pragma unroll
    for (int off = 1; off < 32; off <<= 1) { a += __shfl_xor(a, off); b += __shfl_xor(b, off); }
    if (t == 0) lamp[0] = expf(a) - expf(b) + 0.2f;
  }
}

// 6-MFMA split-precision 16x16 score tile
#define SCORE6(z, a0h, a1h, a0l, a1l, ph, pl)                         \
  {                                                                   \
    bf16x8 bh0 = *(const bf16x8*)(ph), bh1 = *(const bf16x8*)((ph) + 32); \
    bf16x8 bl0 = *(const bf16x8*)(pl), bl1 = *(const bf16x8*)((pl) + 32); \
    z = MFMA16(a0h, bh0, z); z = MFMA16(a1h, bh1, z);                 \
    z = MFMA16(a0h, bl0, z); z = MFMA16(a1h, bl1, z);                 \
    z = MFMA16(a0l, bh0, z); z = MFMA16(a1l, bh1, z);                 \
  }

// ---- attention Z: zp[s][h2][q] = sum over k-segment s of exp|a| (s = 0..3) ----
// v2: each block covers TWO qt tiles (128 q rows; qt pair shares c-level since
// qt mod 8 = c) -> K staging + barriers per q halved, 4 MFMA per staged fk.
// Async-stage split: next tile's loads issue right after the barrier.
__global__ __launch_bounds__(256) void attn_z_kernel(
    const u16* __restrict__ qhi, const u16* __restrict__ khi,
    float* __restrict__ zp) {
  __shared__ u16 Kh[2][64][72];

  const int bid = blockIdx.x;
  const int c = 7 - (bid >> 8);                 // heavy-first
  const int r = bid & 255;
  const int h2 = r & 31;
  const int qp = (r >> 5) & 1;                  // qt pair index
  const int s = r >> 6;                         // 0..3
  const int qt0 = (qp * 2) * 8 + c;
  const int qt1 = (qp * 2 + 1) * 8 + c;
  const int t = threadIdx.x;
  const int lane = t & 63, wv = t >> 6;
  const int rsel = lane & 15, grp = lane >> 4, ksel = 8 * grp;
  const int qrow0 = qt0 * 64 + wv * 16;
  const int qrow1 = qt1 * 64 + wv * 16;

  const size_t qoff0 = ((size_t)h2 * LQ + qrow0 + rsel) * 64 + ksel;
  const size_t qoff1 = ((size_t)h2 * LQ + qrow1 + rsel) * 64 + ksel;
  bf16x8 a00 = *(const bf16x8*)(qhi + qoff0), a01 = *(const bf16x8*)(qhi + qoff0 + 32);
  bf16x8 a10 = *(const bf16x8*)(qhi + qoff1), a11 = *(const bf16x8*)(qhi + qoff1 + 32);
  const u16* kh = khi + (size_t)h2 * LQ * 64;

  const int srow = t >> 2;
  const int scol = (t & 3) * 16;

  int qm0[4], qm1[4];
  float Z0[4] = {0.f, 0.f, 0.f, 0.f};
  float Z1[4] = {0.f, 0.f, 0.f, 0.f};
#pragma unroll
  for (int j = 0; j < 4; ++j) {
    qm0[j] = (qrow0 + grp * 4 + j) & 511;
    qm1[j] = (qrow1 + grp * 4 + j) & 511;
  }

  const int kbeg = s * 512;
  int buf = 0;

  // prologue: load tile 0
  uint4 r0, r1;
  {
    const size_t kb = (size_t)(kbeg + srow) * 64 + scol;
    r0 = *(const uint4*)(kh + kb);
    r1 = *(const uint4*)(kh + kb + 8);
  }
  for (int jt = 0; jt <= c; ++jt) {             // computed tiles only
    const int kt = kbeg + jt * 64;
    *(uint4*)&Kh[buf][srow][scol] = r0;
    *(uint4*)&Kh[buf][srow][scol + 8] = r1;
    __syncthreads();   // K tile ready (dbuf protects against next-tile WAR)
    if (jt < c) {
      const size_t kb = (size_t)(kt + 64 + srow) * 64 + scol;
      r0 = *(const uint4*)(kh + kb);
      r1 = *(const uint4*)(kh + kb + 8);
    }
#pragma unroll
    for (int fk = 0; fk < 4; ++fk) {
      const int krow = fk * 16 + rsel;
      const int k = kt + krow;
      bf16x8 b0 = *(const bf16x8*)&Kh[buf][krow][ksel];
      bf16x8 b1 = *(const bf16x8*)&Kh[buf][krow][ksel + 32];
      f32x4 z0 = {};
      z0 = MFMA16(a00, b0, z0);
      z0 = MFMA16(a01, b1, z0);
      f32x4 z1 = {};
      z1 = MFMA16(a10, b0, z1);
      z1 = MFMA16(a11, b1, z1);
#pragma unroll
      for (int j = 0; j < 4; ++j) {
        if ((k & 511) <= qm0[j]) Z0[j] += __expf(fabsf(z0[j] * SCALING));
        if ((k & 511) <= qm1[j]) Z1[j] += __expf(fabsf(z1[j] * SCALING));
      }
    }
    buf ^= 1;
  }
#pragma unroll
  for (int j = 0; j < 4; ++j) {
#pragma unroll
    for (int off = 1; off < 16; off <<= 1) {
      Z0[j] += __shfl_xor(Z0[j], off);
      Z1[j] += __shfl_xor(Z1[j], off);
    }
    if (rsel == 0) {
      int q0 = qrow0 + grp * 4 + j;
      int q1 = qrow1 + grp * 4 + j;
      zp[((size_t)(s * 32 + h2) << 11) + q0] = Z0[j];
      zp[((size_t)(s * 32 + h2) << 11) + q1] = Z1[j];
    }
  }
}

// ---- attention PV: 1D grid 2048 heavy-first, one 512-segment per block ----
__global__ __launch_bounds__(256) void attn_pv_kernel(
    const u16* __restrict__ qhi, const u16* __restrict__ qlo,
    const u16* __restrict__ khi, const u16* __restrict__ klo,
    const u16* __restrict__ vt, const float* __restrict__ zp,
    const float* __restrict__ lamp,
    float* __restrict__ O0, float* __restrict__ O123, float* __restrict__ colsum) {
  __shared__ u16 KhA[64][72], KlA[64][72], KhB[64][72], KlB[64][72];
  __shared__ u16 Vs[64][72];
  __shared__ u16 pcLDS[4][16][72];
  __shared__ float csLDS[2][4][64];

  const int bid = blockIdx.x;
  const int c = 7 - (bid >> 8);                 // heavy-first
  const int r = bid & 255;
  const int h = r & 15;
  const int qtIdx = (r >> 4) & 3;
  const int s = r >> 6;                         // 0..3
  const int qt = qtIdx * 8 + c;
  const int qb = qt * 64;
  const int t = threadIdx.x;
  const int lane = t & 63, wv = t >> 6;
  const int rsel = lane & 15, grp = lane >> 4, ksel = 8 * grp;
  const int qrow = qb + wv * 16;
  const float lam = lamp[0];

  const int h2a = 2 * h, h2b = 2 * h + 1;
  const size_t qoffa = ((size_t)h2a * LQ + qrow + rsel) * 64 + ksel;
  const size_t qoffb = ((size_t)h2b * LQ + qrow + rsel) * 64 + ksel;
  bf16x8 aqa0h = *(const bf16x8*)(qhi + qoffa), aqa1h = *(const bf16x8*)(qhi + qoffa + 32);
  bf16x8 aqa0l = *(const bf16x8*)(qlo + qoffa), aqa1l = *(const bf16x8*)(qlo + qoffa + 32);
  bf16x8 aqb0h = *(const bf16x8*)(qhi + qoffb), aqb1h = *(const bf16x8*)(qhi + qoffb + 32);
  bf16x8 aqb0l = *(const bf16x8*)(qlo + qoffb), aqb1l = *(const bf16x8*)(qlo + qoffb + 32);
  const u16* kha = khi + (size_t)h2a * LQ * 64;
  const u16* kla = klo + (size_t)h2a * LQ * 64;
  const u16* khb = khi + (size_t)h2b * LQ * 64;
  const u16* klb = klo + (size_t)h2b * LQ * 64;
  const u16* vb = vt + (size_t)h * 64 * LQ;

  // cooperative staging coords: thread t covers row t>>2, 16 cols at (t&3)*16
  const int srow = t >> 2;
  const int scol = (t & 3) * 16;

  int qm[4];
  float iz1[4], iz2[4];
#pragma unroll
  for (int j = 0; j < 4; ++j) {
    int q = qrow + grp * 4 + j;
    qm[j] = q & 511;
    float z1 = 0.f, z2 = 0.f;
#pragma unroll
    for (int ss = 0; ss < 4; ++ss) {
      z1 += zp[((size_t)(ss * 32 + h2a) << 11) + q];
      z2 += zp[((size_t)(ss * 32 + h2b) << 11) + q];
    }
    iz1[j] = 1.f / z1;
    iz2[j] = 1.f / z2;
  }

  f32x4 accO[4] = {};
  const int kbeg = s * 512;
  int buf = 0;

  // zero colsum for skipped (fully-masked) tiles of this segment
  for (int jt = c + 1; jt < 8; ++jt) {
    if (t < 64) colsum[((size_t)h * 32 + qt) * LQ + kbeg + jt * 64 + t] = 0.f;
  }

  // prologue: load tile 0 into registers
  uint4 rha0, rha1, rla0, rla1, rhb0, rhb1, rlb0, rlb1, rv0, rv1;
  {
    const size_t kb = (size_t)(kbeg + srow) * 64 + scol;
    rha0 = *(const uint4*)(kha + kb);
    rha1 = *(const uint4*)(kha + kb + 8);
    rla0 = *(const uint4*)(kla + kb);
    rla1 = *(const uint4*)(kla + kb + 8);
    rhb0 = *(const uint4*)(khb + kb);
    rhb1 = *(const uint4*)(khb + kb + 8);
    rlb0 = *(const uint4*)(klb + kb);
    rlb1 = *(const uint4*)(klb + kb + 8);
    const u16* vsrc = vb + (size_t)srow * LQ + kbeg + scol;
    rv0 = *(const uint4*)(vsrc);
    rv1 = *(const uint4*)(vsrc + 8);
  }

  for (int jt = 0; jt <= c; ++jt) {
    const int kt = kbeg + jt * 64;

    // write prefetched tile to LDS
    *(uint4*)&KhA[srow][scol] = rha0; *(uint4*)&KhA[srow][scol + 8] = rha1;
    *(uint4*)&KlA[srow][scol] = rla0; *(uint4*)&KlA[srow][scol + 8] = rla1;
    *(uint4*)&KhB[srow][scol] = rhb0; *(uint4*)&KhB[srow][scol + 8] = rhb1;
    *(uint4*)&KlB[srow][scol] = rlb0; *(uint4*)&KlB[srow][scol + 8] = rlb1;
    *(uint4*)&Vs[srow][scol] = rv0;  *(uint4*)&Vs[srow][scol + 8] = rv1;
    __syncthreads();   // K/V tile ready

    // ---- issue NEXT tile's global loads (latency hides under compute) ----
    if (jt < c) {
      const size_t kb = (size_t)(kt + 64 + srow) * 64 + scol;
      rha0 = *(const uint4*)(kha + kb);
      rha1 = *(const uint4*)(kha + kb + 8);
      rla0 = *(const uint4*)(kla + kb);
      rla1 = *(const uint4*)(kla + kb + 8);
      rhb0 = *(const uint4*)(khb + kb);
      rhb1 = *(const uint4*)(khb + kb + 8);
      rlb0 = *(const uint4*)(klb + kb);
      rlb1 = *(const uint4*)(klb + kb + 8);
      const u16* vsrc = vb + (size_t)srow * LQ + kt + 64 + scol;
      rv0 = *(const uint4*)(vsrc);
      rv1 = *(const uint4*)(vsrc + 8);
    }

    __builtin_amdgcn_s_setprio(1);
    float pc[4][4], cs[4];
#pragma unroll
    for (int fk = 0; fk < 4; ++fk) {
      const int krow = fk * 16 + rsel;
      const int k = kt + krow;
      f32x4 z = {};
      SCORE6(z, aqa0h, aqa1h, aqa0l, aqa1l, &KhA[krow][ksel], &KlA[krow][ksel]);
      f32x4 w = {};
      SCORE6(w, aqb0h, aqb1h, aqb0l, aqb1l, &KhB[krow][ksel], &KlB[krow][ksel]);
      float csj = 0.f;
#pragma unroll
      for (int j = 0; j < 4; ++j) {
        bool msk = ((k & 511) > qm[j]);
        float sa = z[j] * SCALING;
        float pa = __builtin_copysignf(__expf(fabsf(sa)) * iz1[j], sa);
        pa = msk ? 0.f : pa;
        csj += pa;
        float sb = w[j] * SCALING;
        float pb = __builtin_copysignf(__expf(fabsf(sb)) * iz2[j], sb);
        pc[fk][j] = pa - (msk ? 0.f : lam * pb);
      }
      cs[fk] = csj;
    }
    // pc relayout through OWN pcLDS slice (intra-wave, lgkmcnt-ordered)
#pragma unroll
    for (int fk = 0; fk < 4; ++fk)
#pragma unroll
      for (int j = 0; j < 4; ++j)
        pcLDS[wv][grp * 4 + j][fk * 16 + rsel] = f2b(pc[fk][j]);
    // PV (intra-wave; V read from LDS)
#pragma unroll
    for (int kc = 0; kc < 2; ++kc) {
      bf16x8 ap = *(const bf16x8*)&pcLDS[wv][rsel][kc * 32 + ksel];
#pragma unroll
      for (int fn = 0; fn < 4; ++fn) {
        bf16x8 bv = *(const bf16x8*)&Vs[fn * 16 + rsel][kc * 32 + ksel];
        accO[fn] = MFMA16(ap, bv, accO[fn]);
      }
    }
    __builtin_amdgcn_s_setprio(0);
    // cross-wave colsum (csLDS dbuf + barrier)
#pragma unroll
    for (int fk = 0; fk < 4; ++fk) {
      float cc = cs[fk];
      cc += __shfl_xor(cc, 16);
      cc += __shfl_xor(cc, 32);
      if (grp == 0) csLDS[buf][wv][fk * 16 + rsel] = cc;
    }
    __syncthreads();
    if (t < 64) {
      float tot = csLDS[buf][0][t] + csLDS[buf][1][t] + csLDS[buf][2][t] + csLDS[buf][3][t];
      colsum[((size_t)h * 32 + qt) * LQ + kt + t] = tot;
    }
    buf ^= 1;
  }
  float* Op = (s == 0) ? O0 : (O123 + (size_t)(s - 1) * 16 * LQ * 64);
#pragma unroll
  for (int fn = 0; fn < 4; ++fn)
#pragma unroll
    for (int j = 0; j < 4; ++j) {
      int q = qrow + grp * 4 + j;
      int d = fn * 16 + rsel;
      Op[((size_t)h * LQ + q) * 64 + d] = accO[fn][j];
    }
}

// g[h][k] = sum_qt colsum[h][qt][k] / 2048
__global__ void g_reduce_kernel(const float* __restrict__ colsum, float* __restrict__ g) {
  int idx = blockIdx.x * 256 + threadIdx.x;
  if (idx >= 16 * LQ) return;
  int h = idx >> 11, k = idx & 2047;
  float s = 0.f;
#pragma unroll
  for (int qt = 0; qt < 32; ++qt) s += colsum[((size_t)h * 32 + qt) * LQ + k];
  g[idx] = s * (1.f / 2048.f);
}

// W[h][r][d] = inclusive prefix over r of Gv[h][r][d], gv fused in
__global__ __launch_bounds__(512) void gv_wscan_kernel(const float* __restrict__ g,
                                                       const u16* __restrict__ vt,
                                                       float* __restrict__ W) {
  __shared__ float s[512];
  int h = blockIdx.x >> 6, d = blockIdx.x & 63;
  int t = threadIdx.x;  // r
  float v = 0.f;
#pragma unroll
  for (int seg = 0; seg < 4; ++seg) {
    int k = seg * 512 + t;
    v += g[h * 2048 + k] * b2f(vt[((size_t)h * 64 + d) * LQ + k]);
  }
  s[t] = v;
  __syncthreads();
  for (int off = 1; off < 512; off <<= 1) {
    float add = (t >= off) ? s[t - off] : 0.f;
    __syncthreads();
    s[t] += add;
    __syncthreads();
  }
  W[((size_t)h * 512 + t) * 64 + d] = s[t];
}

// out_pre = O0 + O1 + O2 + O3 + lam*W[q%512]; head rmsnorm -> bf16 [q][h*64+d]
__global__ __launch_bounds__(256) void combine_norm_kernel(
    const float* __restrict__ O0, const float* __restrict__ O123,
    const float* __restrict__ W, const float* __restrict__ hw,
    const float* __restrict__ lamp, u16* __restrict__ out) {
  const int q = blockIdx.x;
  const int h = blockIdx.y * 4 + (threadIdx.x >> 6);
  const int d = threadIdx.x & 63;
  const float lam = lamp[0];
  const size_t S = (size_t)16 * LQ * 64;
  const size_t idx = ((size_t)h * LQ + q) * 64 + d;
  float v = O0[idx] + O123[idx] + O123[idx + S] + O123[idx + 2 * S] +
            lam * W[((size_t)h * 512 + (q & 511)) * 64 + d];
  float ss = v * v;
#pragma unroll
  for (int off = 1; off < 64; off <<= 1) ss += __shfl_xor(ss, off);
  float sc = 1.f / sqrtf(ss * (1.f / 64.f) + 1e-5f);
  out[(size_t)q * 1024 + h * 64 + d] = f2b(v * sc * hw[d]);
}

// ============================== launch ==============================
extern "C" void kernel_launch(void* const* d_in, const int* in_sizes, int n_in,
                              void* d_out, int out_size, void* d_ws, size_t ws_size,
                              hipStream_t stream) {
  const float* x = (const float*)d_in[0];
  const float* freqs_r = (const float*)d_in[1];
  const float* freqs_i = (const float*)d_in[2];
  // d_in[3] = mask (recomputed analytically)
  const float* kv_down_w = (const float*)d_in[4];
  const float* q_down_w = (const float*)d_in[5];
  const float* kv_up_w = (const float*)d_in[6];
  const float* q_up_w = (const float*)d_in[7];
  const float* kv_norm_w = (const float*)d_in[8];
  const float* q_norm_w = (const float*)d_in[9];
  const float* o_w = (const float*)d_in[10];
  const float* lambda_q1 = (const float*)d_in[11];
  const float* lambda_k1 = (const float*)d_in[12];
  const float* lambda_q2 = (const float*)d_in[13];
  const float* lambda_k2 = (const float*)d_in[14];
  const float* head_norm_w = (const float*)d_in[15];
  const float* norm1_w = (const float*)d_in[16];
  const float* norm2_w = (const float*)d_in[17];
  const float* ff_in_w = (const float*)d_in[18];
  const float* ff_out_w = (const float*)d_in[19];
  float* out = (float*)d_out;
  char* ws = (char*)d_ws;

  // ---- weights region (persistent except down/up: dead after projections) ----
  const size_t WT_KVD_H = 0;                                  // 544x1024 bf16
  const size_t WT_KVD_L = WT_KVD_H + (size_t)544 * 1024 * 2;
  const size_t WT_QD_H  = WT_KVD_L + (size_t)544 * 1024 * 2;  // 512x1024
  const size_t WT_QD_L  = WT_QD_H + (size_t)512 * 1024 * 2;
  const size_t WT_KVU_H = WT_QD_L + (size_t)512 * 1024 * 2;   // 2048x512
  const size_t WT_KVU_L = WT_KVU_H + (size_t)2048 * 512 * 2;
  const size_t WT_QU_H  = WT_KVU_L + (size_t)2048 * 512 * 2;  // 1536x512
  const size_t WT_QU_L  = WT_QU_H + (size_t)1536 * 512 * 2;
  const size_t WT_OW    = WT_QU_L + (size_t)1536 * 512 * 2;   // = 11,714,560
  const size_t WT_FFI   = WT_OW + (size_t)1024 * 1024 * 2;
  const size_t WT_FFO   = WT_FFI + (size_t)8192 * 1024 * 2;
  const size_t A0 = WT_FFO + (size_t)1024 * 4096 * 2;         // = 38,928,384

  // ---- activations (lifetime-aliased) ----
  const size_t H     = A0;                  // h hi/lo bf16 (2x 4,194,304); dead after down-GEMMs
  const size_t CKV   = A0 + 8388608;        // f32 2048x544;  dead after build_kh
  const size_t CKVN  = A0 + 12845056;       // ckvn hi/lo bf16 (2x 2,097,152); dead after kv_up
  const size_t KVB   = A0 + 17039360;       // f32 2048x2048; dead after build_vt
  const size_t CQ    = A0 + 33816576;       // f32 2048x512;  dead after rmsnorm
  const size_t CQN   = A0 + 38010880;       // cqn hi/lo bf16 (2x 2,097,152); dead after q_up
  const size_t QFULL = A0 + 42205184;       // f32 2048x1536; dead after build_qh
  // mid buffers (aliases):
  const size_t QHI = H;                     // bf16 32x2048x64 over dead H
  const size_t KHI = QFULL;                 // bf16 32x2048x64 over dead QFULL[0:8.39M]
  const size_t KLO = A0 + 50593792;         // bf16 32x2048x64 over dead QFULL[8.39M:]+
  const size_t QLO = A0 + 58982400;         // bf16 32x2048x64
  const size_t VT  = CKVN;                  // bf16 16x64x2048 over dead CKVN
  // O partials (4 x 8,388,608 f32):
  const size_t OP0   = 0;                   // over dead down/up weights [0, 8.39M) < WT_OW
  const size_t OP123 = KVB;                 // 3 contiguous partials over dead KVB+CQ+CQN
  const size_t CS  = CKV;                   // f32 16x32x2048 over dead CKV
  const size_t GB  = A0 + 67371008;         // f32 16x2048 (131,072)
  const size_t WB  = A0 + 69599232;         // f32 16x512x64 (2,097,152)
  const size_t LAM = A0 + 71696384;         // scalar
  const size_t ZP  = A0 + 71696640;         // f32 4x32x2048 (1,048,576)
  const size_t WS_END = A0 + 72745216;      // ~111.7 MB (known-safe)
  // late aliases:
  const size_t ATTN  = CKV;                 // bf16 2048x1024 (over consumed CS)
  const size_t X1    = KVB + 8388608;       // f32 2048x1024 (partials consumed by combine)
  const size_t H2N   = H;                   // bf16 2048x1024 over dead QHI
  const size_t FFACT = QFULL;               // bf16 2048x4096 over dead KHI+KLO

  if (ws_size < WS_END) return;

  u16* wt_kvd_h = (u16*)(ws + WT_KVD_H); u16* wt_kvd_l = (u16*)(ws + WT_KVD_L);
  u16* wt_qd_h  = (u16*)(ws + WT_QD_H);  u16* wt_qd_l  = (u16*)(ws + WT_QD_L);
  u16* wt_kvu_h = (u16*)(ws + WT_KVU_H); u16* wt_kvu_l = (u16*)(ws + WT_KVU_L);
  u16* wt_qu_h  = (u16*)(ws + WT_QU_H);  u16* wt_qu_l  = (u16*)(ws + WT_QU_L);
  u16* wt_ow  = (u16*)(ws + WT_OW);
  u16* wt_ffi = (u16*)(ws + WT_FFI);
  u16* wt_ffo = (u16*)(ws + WT_FFO);
  u16* h_hi   = (u16*)(ws + H);
  u16* h_lo   = (u16*)(ws + H + 4194304);
  float* ckv  = (float*)(ws + CKV);
  u16* ckvn_hi = (u16*)(ws + CKVN);
  u16* ckvn_lo = (u16*)(ws + CKVN + 2097152);
  float* kvb  = (float*)(ws + KVB);
  float* cq   = (float*)(ws + CQ);
  u16* cqn_hi = (u16*)(ws + CQN);
  u16* cqn_lo = (u16*)(ws + CQN + 2097152);
  float* qfull = (float*)(ws + QFULL);
  u16* qhib = (u16*)(ws + QHI); u16* qlob = (u16*)(ws + QLO);
  u16* khib = (u16*)(ws + KHI); u16* klob = (u16*)(ws + KLO);
  u16* vtb  = (u16*)(ws + VT);
  float* zpb = (float*)(ws + ZP);
  float* Op0 = (float*)(ws + OP0);
  float* Op123 = (float*)(ws + OP123);
  float* csb = (float*)(ws + CS);
  float* gb  = (float*)(ws + GB);
  float* wbb = (float*)(ws + WB);
  float* lamp = (float*)(ws + LAM);
  u16* attn_n = (u16*)(ws + ATTN);
  float* x1 = (float*)(ws + X1);
  u16* h2n = (u16*)(ws + H2N);
  u16* ffact = (u16*)(ws + FFACT);

  // fused weight prep + rmsnorm(x) (16160 transpose blocks + 2048 rmsnorm rows)
  prep_weights_kernel<<<18208, dim3(32, 8), 0, stream>>>(
      kv_down_w, wt_kvd_h, wt_kvd_l, q_down_w, wt_qd_h, wt_qd_l,
      kv_up_w, wt_kvu_h, wt_kvu_l, q_up_w, wt_qu_h, wt_qu_l,
      o_w, wt_ow, ff_in_w, wt_ffi, ff_out_w, wt_ffo,
      x, norm1_w, h_hi, h_lo);

  // both down-projections (share A = h)
  gemm_split<<<dim3(9, 32), 256, 0, stream>>>(h_hi, h_lo, wt_kvd_h, wt_kvd_l, ckv,
                                              2048, 544, 1024);
  gemm_split<<<dim3(8, 32), 256, 0, stream>>>(h_hi, h_lo, wt_qd_h, wt_qd_l, cq,
                                              2048, 512, 1024);
  // fused rmsnorm of ckv (stride 544) + cq (stride 512)
  rmsnorm_split2_kernel<<<4096, 256, 0, stream>>>(ckv, kv_norm_w, ckvn_hi, ckvn_lo, 544,
                                                  cq, q_norm_w, cqn_hi, cqn_lo, 512);
  gemm_split<<<dim3(32, 32), 256, 0, stream>>>(ckvn_hi, ckvn_lo, wt_kvu_h, wt_kvu_l, kvb,
                                               2048, 2048, 512);
  gemm_split<<<dim3(24, 32), 256, 0, stream>>>(cqn_hi, cqn_lo, wt_qu_h, wt_qu_l, qfull,
                                               2048, 1536, 512);

  // fused mid build (build_qh + build_kh + build_vt + lam -> 1 kernel)
  build_mid_kernel<<<33281, 256, 0, stream>>>(qfull, kvb, ckv, freqs_r, freqs_i,
                                              qhib, qlob, khib, klob, vtb,
                                              lambda_q1, lambda_k1, lambda_q2, lambda_k2,
                                              lamp);

  attn_z_kernel<<<2048, 256, 0, stream>>>(qhib, khib, zpb);
  attn_pv_kernel<<<2048, 256, 0, stream>>>(qhib, qlob, khib, klob, vtb, zpb,
                                           lamp, Op0, Op123, csb);

  g_reduce_kernel<<<128, 256, 0, stream>>>(csb, gb);
  gv_wscan_kernel<<<1024, 512, 0, stream>>>(gb, vtb, wbb);
  combine_norm_kernel<<<dim3(2048, 4), 256, 0, stream>>>(Op0, Op123, wbb, head_norm_w,
                                                         lamp, attn_n);

  // x1 = x + attn_n @ o_w  (residual fused into epilogue)
  gemm_kernel<0, 1><<<dim3(16, 32), 256, 0, stream>>>(attn_n, wt_ow, x, x1, nullptr,
                                                      2048, 1024, 1024);
  rmsnorm_kernel<1><<<2048, 256, 0, stream>>>(x1, norm2_w, h2n, 1024, 1024, FEPS);
  // gated FFN-in: M=128 x N=64 tiles (1024 blocks)
  gemm_m128_gated<<<dim3(64, 16), 256, 0, stream>>>(h2n, wt_ffi, ffact, 2048, 4096, 1024);
  // out = x1 + ffact @ ff_out  (residual fused into epilogue)
  gemm_kernel<0, 1><<<dim3(16, 32), 256, 0, stream>>>(ffact, wt_ffo, x1, out, nullptr,
                                                      2048, 1024, 4096);
}

// Round 28
// 331.040 us; speedup vs baseline: 1.2298x; 1.0575x over previous
//
#include <hip/hip_runtime.h>
#include <math.h>

#define LQ 2048
#define SCALING 0.14433756729740643f   // 48^-0.5
#define FEPS 1.1920928955078125e-07f   // np.finfo(float32).eps

typedef unsigned short u16;
typedef __attribute__((ext_vector_type(8))) short bf16x8;
typedef __attribute__((ext_vector_type(4))) float f32x4;

#define MFMA16(a, b, c) __builtin_amdgcn_mfma_f32_16x16x32_bf16((a), (b), (c), 0, 0, 0)

__device__ __forceinline__ u16 f2b(float x) {
  union { float f; unsigned u; } v; v.f = x;
  return (u16)((v.u + 0x7FFFu + ((v.u >> 16) & 1u)) >> 16);
}
__device__ __forceinline__ float b2f(u16 b) {
  union { unsigned u; float f; } v; v.u = ((unsigned)b) << 16;
  return v.f;
}

// ---- fused weight prep: 7 transposes + rmsnorm_split(x) in one kernel ----
__global__ __launch_bounds__(256) void prep_weights_kernel(
    const float* __restrict__ kvd, u16* __restrict__ kvd_h, u16* __restrict__ kvd_l,
    const float* __restrict__ qd,  u16* __restrict__ qd_h,  u16* __restrict__ qd_l,
    const float* __restrict__ kvu, u16* __restrict__ kvu_h, u16* __restrict__ kvu_l,
    const float* __restrict__ qu,  u16* __restrict__ qu_h,  u16* __restrict__ qu_l,
    const float* __restrict__ ow,  u16* __restrict__ ow_t,
    const float* __restrict__ ffi, u16* __restrict__ ffi_t,
    const float* __restrict__ ffo, u16* __restrict__ ffo_t,
    const float* __restrict__ x, const float* __restrict__ norm1_w,
    u16* __restrict__ h_hi, u16* __restrict__ h_lo) {
  __shared__ float tile[32][33];
  __shared__ float red[4];
  int id = blockIdx.x;

  if (id >= 16160) {
    // ---- rmsnorm_split of x: row = id - 16160, cols 1024 ----
    const int row = id - 16160;
    const int tid = threadIdx.y * 32 + threadIdx.x;  // flat 0..255
    const float* xr = x + (size_t)row * 1024;
    float ss = 0.f;
    for (int c = tid; c < 1024; c += 256) { float v = xr[c]; ss = fmaf(v, v, ss); }
#pragma unroll
    for (int off = 32; off > 0; off >>= 1) ss += __shfl_xor(ss, off);
    if ((tid & 63) == 0) red[tid >> 6] = ss;
    __syncthreads();
    float tot = red[0] + red[1] + red[2] + red[3];
    float sc = 1.f / sqrtf(tot / 1024.f + FEPS);
    for (int c = tid; c < 1024; c += 256) {
      float v = xr[c] * sc * norm1_w[c];
      u16 hi = f2b(v);
      h_hi[(size_t)row * 1024 + c] = hi;
      h_lo[(size_t)row * 1024 + c] = f2b(v - b2f(hi));
    }
    return;
  }

  const float* W; u16* Whi; u16* Wlo = nullptr; int K, N, bx, by;
  if (id < 8192) {                       // ff_in 1024x8192 (heaviest first)
    W = ffi; Whi = ffi_t; K = 1024; N = 8192; bx = id % 256; by = id / 256;
  } else if (id < 8192 + 4096) {         // ff_out 4096x1024
    id -= 8192;
    W = ffo; Whi = ffo_t; K = 4096; N = 1024; bx = id % 32; by = id / 32;
  } else if (id < 12288 + 1024) {        // o_w 1024x1024
    id -= 12288;
    W = ow; Whi = ow_t; K = 1024; N = 1024; bx = id % 32; by = id / 32;
  } else if (id < 13312 + 544) {         // kv_down 1024x544 (split)
    id -= 13312;
    W = kvd; Whi = kvd_h; Wlo = kvd_l; K = 1024; N = 544; bx = id % 17; by = id / 17;
  } else if (id < 13856 + 512) {         // q_down 1024x512 (split)
    id -= 13856;
    W = qd; Whi = qd_h; Wlo = qd_l; K = 1024; N = 512; bx = id % 16; by = id / 16;
  } else if (id < 14368 + 1024) {        // kv_up 512x2048 (split)
    id -= 14368;
    W = kvu; Whi = kvu_h; Wlo = kvu_l; K = 512; N = 2048; bx = id % 64; by = id / 64;
  } else {                               // q_up 512x1536 (split)
    id -= 15392;
    W = qu; Whi = qu_h; Wlo = qu_l; K = 512; N = 1536; bx = id % 48; by = id / 48;
  }

  int n0 = bx * 32, k0 = by * 32;
  int tx = threadIdx.x, ty = threadIdx.y;  // 32 x 8
  for (int i = ty; i < 32; i += 8) {
    int k = k0 + i, n = n0 + tx;
    tile[i][tx] = (k < K && n < N) ? W[(size_t)k * N + n] : 0.f;
  }
  __syncthreads();
  for (int i = ty; i < 32; i += 8) {
    int n = n0 + i, k = k0 + tx;
    if (n < N && k < K) {
      float xv = tile[tx][i];
      u16 hi = f2b(xv);
      Whi[(size_t)n * K + k] = hi;
      if (Wlo) Wlo[(size_t)n * K + k] = f2b(xv - b2f(hi));
    }
  }
}

// ---------------- rmsnorm fp32 in (strided) -> fp32 or bf16 out ----------------
template <int BF16OUT>
__global__ __launch_bounds__(256) void rmsnorm_kernel(
    const float* __restrict__ x, const float* __restrict__ w, void* __restrict__ outv,
    int cols, int in_stride, float eps) {
  const int row = blockIdx.x;
  const float* xr = x + (size_t)row * in_stride;
  float ss = 0.f;
  for (int c = threadIdx.x; c < cols; c += 256) { float v = xr[c]; ss = fmaf(v, v, ss); }
#pragma unroll
  for (int off = 32; off > 0; off >>= 1) ss += __shfl_xor(ss, off);
  __shared__ float red[4];
  if ((threadIdx.x & 63) == 0) red[threadIdx.x >> 6] = ss;
  __syncthreads();
  float tot = red[0] + red[1] + red[2] + red[3];
  float sc = 1.f / sqrtf(tot / (float)cols + eps);
  for (int c = threadIdx.x; c < cols; c += 256) {
    float v = xr[c] * sc * w[c];
    if (BF16OUT) ((u16*)outv)[(size_t)row * cols + c] = f2b(v);
    else ((float*)outv)[(size_t)row * cols + c] = v;
  }
}

// ---- fused pair: rmsnorm_split for ckv (cols 512, stride 544) + cq (512/512) ----
__global__ __launch_bounds__(256) void rmsnorm_split2_kernel(
    const float* __restrict__ in0, const float* __restrict__ w0,
    u16* __restrict__ hi0, u16* __restrict__ lo0, int stride0,
    const float* __restrict__ in1, const float* __restrict__ w1,
    u16* __restrict__ hi1, u16* __restrict__ lo1, int stride1) {
  int row = blockIdx.x;
  const float* xr; const float* w; u16* ho; u16* lo;
  if (row < 2048) {
    xr = in0 + (size_t)row * stride0; w = w0;
    ho = hi0 + (size_t)row * 512; lo = lo0 + (size_t)row * 512;
  } else {
    row -= 2048;
    xr = in1 + (size_t)row * stride1; w = w1;
    ho = hi1 + (size_t)row * 512; lo = lo1 + (size_t)row * 512;
  }
  float ss = 0.f;
  for (int c = threadIdx.x; c < 512; c += 256) { float v = xr[c]; ss = fmaf(v, v, ss); }
#pragma unroll
  for (int off = 32; off > 0; off >>= 1) ss += __shfl_xor(ss, off);
  __shared__ float red[4];
  if ((threadIdx.x & 63) == 0) red[threadIdx.x >> 6] = ss;
  __syncthreads();
  float tot = red[0] + red[1] + red[2] + red[3];
  float sc = 1.f / sqrtf(tot / 512.f + FEPS);
  for (int c = threadIdx.x; c < 512; c += 256) {
    float v = xr[c] * sc * w[c];
    u16 hi = f2b(v);
    ho[c] = hi;
    lo[c] = f2b(v - b2f(hi));
  }
}

// ---- split-precision GEMM (3-term) over TWO independent problems sharing M,K.
//      Flat grid: first nbx0*rows blocks -> problem 0, rest -> problem 1.
//      Per-tile code identical to the single-problem version (bit-identical). ----
__global__ __launch_bounds__(256) void gemm_split2(
    const u16* __restrict__ Ahi0, const u16* __restrict__ Alo0,
    const u16* __restrict__ Bhi0, const u16* __restrict__ Blo0,
    float* __restrict__ C0, int N0, int nbx0,
    const u16* __restrict__ Ahi1, const u16* __restrict__ Alo1,
    const u16* __restrict__ Bhi1, const u16* __restrict__ Blo1,
    float* __restrict__ C1, int N1, int nbx1,
    int M, int K) {
  __shared__ u16 Ah[64][72];
  __shared__ u16 Al[64][72];
  __shared__ u16 Bh[64][72];
  __shared__ u16 Bl[64][72];

  int id = blockIdx.x;
  const u16* Ahi; const u16* Alo; const u16* Bhi; const u16* Blo;
  float* C; int N, bnx, bmy;
  const int rows = M >> 6;
  if (id < nbx0 * rows) {
    Ahi = Ahi0; Alo = Alo0; Bhi = Bhi0; Blo = Blo0; C = C0; N = N0;
    bnx = id % nbx0; bmy = id / nbx0;
  } else {
    id -= nbx0 * rows;
    Ahi = Ahi1; Alo = Alo1; Bhi = Bhi1; Blo = Blo1; C = C1; N = N1;
    bnx = id % nbx1; bmy = id / nbx1;
  }

  const int t = threadIdx.x;
  const int lane = t & 63;
  const int wv = t >> 6;
  const int wr = (wv >> 1) * 32;
  const int wc = (wv & 1) * 32;
  const int bm = bmy * 64;
  const int bn = bnx * 64;
  const int lr = t >> 2;
  const int lc = (t & 3) * 16;
  const int rsel = lane & 15;
  const int ksel = 8 * (lane >> 4);

  const u16* Ahrow = Ahi + (size_t)(bm + lr) * K + lc;
  const u16* Alrow = Alo + (size_t)(bm + lr) * K + lc;
  const bool bval = (bn + lr) < N;
  const u16* Bhrow = Bhi + (size_t)(bn + lr) * K + lc;
  const u16* Blrow = Blo + (size_t)(bn + lr) * K + lc;

  f32x4 acc[2][2] = {};

  for (int kt = 0; kt < K; kt += 64) {
    uint4 ah0 = *(const uint4*)(Ahrow + kt);
    uint4 ah1 = *(const uint4*)(Ahrow + kt + 8);
    uint4 al0 = *(const uint4*)(Alrow + kt);
    uint4 al1 = *(const uint4*)(Alrow + kt + 8);
    uint4 bh0 = {0, 0, 0, 0}, bh1 = {0, 0, 0, 0}, bl0 = {0, 0, 0, 0}, bl1 = {0, 0, 0, 0};
    if (bval) {
      bh0 = *(const uint4*)(Bhrow + kt); bh1 = *(const uint4*)(Bhrow + kt + 8);
      bl0 = *(const uint4*)(Blrow + kt); bl1 = *(const uint4*)(Blrow + kt + 8);
    }
    __syncthreads();
    *(uint4*)&Ah[lr][lc] = ah0; *(uint4*)&Ah[lr][lc + 8] = ah1;
    *(uint4*)&Al[lr][lc] = al0; *(uint4*)&Al[lr][lc + 8] = al1;
    *(uint4*)&Bh[lr][lc] = bh0; *(uint4*)&Bh[lr][lc + 8] = bh1;
    *(uint4*)&Bl[lr][lc] = bl0; *(uint4*)&Bl[lr][lc + 8] = bl1;
    __syncthreads();
#pragma unroll
    for (int ks = 0; ks < 2; ++ks) {
      const int ko = ks * 32 + ksel;
      bf16x8 a0h = *(const bf16x8*)&Ah[wr + rsel][ko];
      bf16x8 a1h = *(const bf16x8*)&Ah[wr + 16 + rsel][ko];
      bf16x8 a0l = *(const bf16x8*)&Al[wr + rsel][ko];
      bf16x8 a1l = *(const bf16x8*)&Al[wr + 16 + rsel][ko];
      bf16x8 b0h = *(const bf16x8*)&Bh[wc + rsel][ko];
      bf16x8 b1h = *(const bf16x8*)&Bh[wc + 16 + rsel][ko];
      bf16x8 b0l = *(const bf16x8*)&Bl[wc + rsel][ko];
      bf16x8 b1l = *(const bf16x8*)&Bl[wc + 16 + rsel][ko];
      acc[0][0] = MFMA16(a0h, b0h, acc[0][0]);
      acc[0][0] = MFMA16(a0h, b0l, acc[0][0]);
      acc[0][0] = MFMA16(a0l, b0h, acc[0][0]);
      acc[0][1] = MFMA16(a0h, b1h, acc[0][1]);
      acc[0][1] = MFMA16(a0h, b1l, acc[0][1]);
      acc[0][1] = MFMA16(a0l, b1h, acc[0][1]);
      acc[1][0] = MFMA16(a1h, b0h, acc[1][0]);
      acc[1][0] = MFMA16(a1h, b0l, acc[1][0]);
      acc[1][0] = MFMA16(a1l, b0h, acc[1][0]);
      acc[1][1] = MFMA16(a1h, b1h, acc[1][1]);
      acc[1][1] = MFMA16(a1h, b1l, acc[1][1]);
      acc[1][1] = MFMA16(a1l, b1h, acc[1][1]);
    }
  }
  const int r0 = (lane >> 4) * 4;
#pragma unroll
  for (int fm = 0; fm < 2; ++fm)
#pragma unroll
    for (int fn = 0; fn < 2; ++fn)
#pragma unroll
      for (int j = 0; j < 4; ++j) {
        int row = bm + wr + fm * 16 + r0 + j;
        int col = bn + wc + fn * 16 + rsel;
        if (col < N) C[(size_t)row * N + col] = acc[fm][fn][j];
      }
}

// ---- plain bf16 GEMM (o_w / FFN-out): 64x64 reg-staged. ADDX fuses residual add. ----
template <int GATED, int ADDX>
__global__ __launch_bounds__(256) void gemm_kernel(
    const u16* __restrict__ A, const u16* __restrict__ Bt, const float* __restrict__ X,
    float* __restrict__ C, u16* __restrict__ Cg, int M, int N, int K) {
  __shared__ u16 As[64][72];
  __shared__ u16 Bs[64][72];
  __shared__ u16 Bs2[GATED ? 64 : 1][72];

  const int t = threadIdx.x;
  const int lane = t & 63;
  const int wv = t >> 6;
  const int wr = (wv >> 1) * 32;
  const int wc = (wv & 1) * 32;
  const int bm = blockIdx.y * 64;
  const int bn = blockIdx.x * 64;
  const int lr = t >> 2;
  const int lc = (t & 3) * 16;
  const int rsel = lane & 15;
  const int ksel = 8 * (lane >> 4);

  const u16* Arow = A + (size_t)(bm + lr) * K + lc;
  const u16* Brow = Bt + (size_t)(bn + lr) * K + lc;
  const u16* Brow2 = Bt + (size_t)(4096 + bn + lr) * K + lc;

  f32x4 acc[2][2] = {};
  f32x4 accg[2][2] = {};

  for (int kt = 0; kt < K; kt += 64) {
    uint4 a0 = *(const uint4*)(Arow + kt);
    uint4 a1 = *(const uint4*)(Arow + kt + 8);
    uint4 b0 = *(const uint4*)(Brow + kt);
    uint4 b1 = *(const uint4*)(Brow + kt + 8);
    uint4 c0 = {0, 0, 0, 0}, c1 = {0, 0, 0, 0};
    if (GATED) { c0 = *(const uint4*)(Brow2 + kt); c1 = *(const uint4*)(Brow2 + kt + 8); }
    __syncthreads();
    *(uint4*)&As[lr][lc] = a0; *(uint4*)&As[lr][lc + 8] = a1;
    *(uint4*)&Bs[lr][lc] = b0; *(uint4*)&Bs[lr][lc + 8] = b1;
    if (GATED) { *(uint4*)&Bs2[lr][lc] = c0; *(uint4*)&Bs2[lr][lc + 8] = c1; }
    __syncthreads();
#pragma unroll
    for (int ks = 0; ks < 2; ++ks) {
      const int ko = ks * 32 + ksel;
      bf16x8 af0 = *(const bf16x8*)&As[wr + rsel][ko];
      bf16x8 af1 = *(const bf16x8*)&As[wr + 16 + rsel][ko];
      bf16x8 bf0 = *(const bf16x8*)&Bs[wc + rsel][ko];
      bf16x8 bf1 = *(const bf16x8*)&Bs[wc + 16 + rsel][ko];
      acc[0][0] = MFMA16(af0, bf0, acc[0][0]);
      acc[0][1] = MFMA16(af0, bf1, acc[0][1]);
      acc[1][0] = MFMA16(af1, bf0, acc[1][0]);
      acc[1][1] = MFMA16(af1, bf1, acc[1][1]);
      if (GATED) {
        bf16x8 cf0 = *(const bf16x8*)&Bs2[wc + rsel][ko];
        bf16x8 cf1 = *(const bf16x8*)&Bs2[wc + 16 + rsel][ko];
        accg[0][0] = MFMA16(af0, cf0, accg[0][0]);
        accg[0][1] = MFMA16(af0, cf1, accg[0][1]);
        accg[1][0] = MFMA16(af1, cf0, accg[1][0]);
        accg[1][1] = MFMA16(af1, cf1, accg[1][1]);
      }
    }
  }
  const int r0 = (lane >> 4) * 4;
#pragma unroll
  for (int fm = 0; fm < 2; ++fm)
#pragma unroll
    for (int fn = 0; fn < 2; ++fn)
#pragma unroll
      for (int j = 0; j < 4; ++j) {
        int row = bm + wr + fm * 16 + r0 + j;
        int col = bn + wc + fn * 16 + rsel;
        size_t o = (size_t)row * N + col;
        if (!GATED) {
          float v = acc[fm][fn][j];
          if (ADDX) v += X[o];
          C[o] = v;
        } else {
          float u = acc[fm][fn][j], g = accg[fm][fn][j];
          float sv = g / (1.f + __expf(-g));
          Cg[o] = f2b(u * sv);
        }
      }
}

// ---- gated FFN-in GEMM, M=128 x N=64 tile (1024 blocks) ----
__global__ __launch_bounds__(256) void gemm_m128_gated(
    const u16* __restrict__ A, const u16* __restrict__ Bt,
    u16* __restrict__ Cg, int M, int N, int K) {
  __shared__ u16 As[128][72];
  __shared__ u16 Bs[64][72];
  __shared__ u16 Bs2[64][72];

  const int t = threadIdx.x;
  const int lane = t & 63;
  const int wv = t >> 6;
  const int bm = blockIdx.y * 128;
  const int bn = blockIdx.x * 64;
  const int lr = t >> 2;              // staging row 0..63
  const int lc = (t & 3) * 16;        // staging col
  const int rsel = lane & 15;
  const int ksel = 8 * (lane >> 4);

  const u16* Arow0 = A + (size_t)(bm + lr) * K + lc;
  const u16* Arow1 = A + (size_t)(bm + 64 + lr) * K + lc;
  const u16* Brow = Bt + (size_t)(bn + lr) * K + lc;
  const u16* Brow2 = Bt + (size_t)(4096 + bn + lr) * K + lc;

  f32x4 acc[2][4] = {};
  f32x4 accg[2][4] = {};

  for (int kt = 0; kt < K; kt += 64) {
    uint4 a00 = *(const uint4*)(Arow0 + kt);
    uint4 a01 = *(const uint4*)(Arow0 + kt + 8);
    uint4 a10 = *(const uint4*)(Arow1 + kt);
    uint4 a11 = *(const uint4*)(Arow1 + kt + 8);
    uint4 b0 = *(const uint4*)(Brow + kt);
    uint4 b1 = *(const uint4*)(Brow + kt + 8);
    uint4 c0 = *(const uint4*)(Brow2 + kt);
    uint4 c1 = *(const uint4*)(Brow2 + kt + 8);
    __syncthreads();
    *(uint4*)&As[lr][lc] = a00; *(uint4*)&As[lr][lc + 8] = a01;
    *(uint4*)&As[64 + lr][lc] = a10; *(uint4*)&As[64 + lr][lc + 8] = a11;
    *(uint4*)&Bs[lr][lc] = b0; *(uint4*)&Bs[lr][lc + 8] = b1;
    *(uint4*)&Bs2[lr][lc] = c0; *(uint4*)&Bs2[lr][lc + 8] = c1;
    __syncthreads();
#pragma unroll
    for (int ks = 0; ks < 2; ++ks) {
      const int ko = ks * 32 + ksel;
      bf16x8 af0 = *(const bf16x8*)&As[wv * 32 + rsel][ko];
      bf16x8 af1 = *(const bf16x8*)&As[wv * 32 + 16 + rsel][ko];
      bf16x8 bf[4];
#pragma unroll
      for (int fn = 0; fn < 4; ++fn)
        bf[fn] = *(const bf16x8*)&Bs[fn * 16 + rsel][ko];
#pragma unroll
      for (int fn = 0; fn < 4; ++fn) {
        acc[0][fn] = MFMA16(af0, bf[fn], acc[0][fn]);
        acc[1][fn] = MFMA16(af1, bf[fn], acc[1][fn]);
      }
      bf16x8 cf[4];
#pragma unroll
      for (int fn = 0; fn < 4; ++fn)
        cf[fn] = *(const bf16x8*)&Bs2[fn * 16 + rsel][ko];
#pragma unroll
      for (int fn = 0; fn < 4; ++fn) {
        accg[0][fn] = MFMA16(af0, cf[fn], accg[0][fn]);
        accg[1][fn] = MFMA16(af1, cf[fn], accg[1][fn]);
      }
    }
  }
  const int r0 = (lane >> 4) * 4;
#pragma unroll
  for (int fm = 0; fm < 2; ++fm)
#pragma unroll
    for (int fn = 0; fn < 4; ++fn)
#pragma unroll
      for (int j = 0; j < 4; ++j) {
        int row = bm + wv * 32 + fm * 16 + r0 + j;
        int col = bn + fn * 16 + rsel;
        size_t o = (size_t)row * N + col;
        float u = acc[fm][fn][j], g = accg[fm][fn][j];
        float sv = g / (1.f + __expf(-g));
        Cg[o] = f2b(u * sv);
      }
}

// ---- fused mid build: build_qh + build_kh + build_vt + lam in one kernel ----
__global__ __launch_bounds__(256) void build_mid_kernel(
    const float* __restrict__ qfull, const float* __restrict__ kv,
    const float* __restrict__ ckv, const float* __restrict__ fr,
    const float* __restrict__ fi, u16* __restrict__ qhi, u16* __restrict__ qlo,
    u16* __restrict__ khi, u16* __restrict__ klo, u16* __restrict__ vt,
    const float* __restrict__ lq1, const float* __restrict__ lk1,
    const float* __restrict__ lq2, const float* __restrict__ lk2,
    float* __restrict__ lamp) {
  __shared__ u16 tile[64][65];
  int id = blockIdx.x;
  if (id < 16384) {
    // ---- build_qh ----
    const int q = id & 2047;
    const int h2 = ((id >> 11) << 2) + (threadIdx.x >> 6);
    const int d = threadIdx.x & 63;
    const int hh = h2 >> 1, s = h2 & 1;
    const float* row = qfull + (size_t)q * 1536 + hh * 96;
    float val;
    if (d < 32) {
      val = row[s * 32 + d];
    } else if (d < 48) {
      int r = d - 32;
      int pos = q & 511;
      const float* rp = row + 64 + s * 16;
      if (pos == 0) val = rp[r];
      else {
        int j = r >> 1;
        float cr = fr[(pos - 1) * 8 + j], ci = fi[(pos - 1) * 8 + j];
        float a = rp[2 * j], b = rp[2 * j + 1];
        val = (r & 1) ? (a * ci + b * cr) : (a * cr - b * ci);
      }
    } else val = 0.f;
    u16 hi = f2b(val);
    qhi[((size_t)h2 * LQ + q) * 64 + d] = hi;
    qlo[((size_t)h2 * LQ + q) * 64 + d] = f2b(val - b2f(hi));
    return;
  }
  id -= 16384;
  if (id < 16384) {
    // ---- build_kh ----
    const int kp = id & 2047;
    const int h2 = ((id >> 11) << 2) + (threadIdx.x >> 6);
    const int d = threadIdx.x & 63;
    const int hh = h2 >> 1, s = h2 & 1;
    float val;
    if (d < 32) {
      val = kv[(size_t)kp * 2048 + hh * 128 + s * 32 + d];
    } else if (d < 48) {
      int r = d - 32;
      int pos = kp & 511;
      const float* rp = ckv + (size_t)kp * 544 + 512 + s * 16;
      if (pos == 0) val = rp[r];
      else {
        int j = r >> 1;
        float cr = fr[(pos - 1) * 8 + j], ci = fi[(pos - 1) * 8 + j];
        float a = rp[2 * j], b = rp[2 * j + 1];
        val = (r & 1) ? (a * ci + b * cr) : (a * cr - b * ci);
      }
    } else val = 0.f;
    u16 hi = f2b(val);
    khi[((size_t)h2 * LQ + kp) * 64 + d] = hi;
    klo[((size_t)h2 * LQ + kp) * 64 + d] = f2b(val - b2f(hi));
    return;
  }
  id -= 16384;
  if (id < 512) {
    // ---- build_vt: vt[h][d][k] = bf16(kv[k][h*128+64+d]) ----
    int h = id >> 5, k0 = (id & 31) * 64;
    int t = threadIdx.x;
    int d = t & 63, kr = t >> 6;
#pragma unroll
    for (int i = 0; i < 16; ++i) {
      int k = kr + i * 4;
      tile[k][d] = f2b(kv[(size_t)(k0 + k) * 2048 + h * 128 + 64 + d]);
    }
    __syncthreads();
    int kk = t & 63, dr = t >> 6;
#pragma unroll
    for (int i = 0; i < 16; ++i) {
      int d2 = dr + i * 4;
      vt[((size_t)h * 64 + d2) * LQ + k0 + kk] = tile[kk][d2];
    }
    return;
  }
  // ---- lam = exp(sum(lk1*lq1)) - exp(sum(lk2*lq2)) + 0.2 ----
  int t = threadIdx.x;
  if (t < 32) {
    float a = lq1[t] * lk1[t], b = lq2[t] * lk2[t];
#pragma unroll
    for (int off = 1; off < 32; off <<= 1) { a += __shfl_xor(a, off); b += __shfl_xor(b, off); }
    if (t == 0) lamp[0] = expf(a) - expf(b) + 0.2f;
  }
}

// 6-MFMA split-precision 16x16 score tile
#define SCORE6(z, a0h, a1h, a0l, a1l, ph, pl)                         \
  {                                                                   \
    bf16x8 bh0 = *(const bf16x8*)(ph), bh1 = *(const bf16x8*)((ph) + 32); \
    bf16x8 bl0 = *(const bf16x8*)(pl), bl1 = *(const bf16x8*)((pl) + 32); \
    z = MFMA16(a0h, bh0, z); z = MFMA16(a1h, bh1, z);                 \
    z = MFMA16(a0h, bl0, z); z = MFMA16(a1h, bl1, z);                 \
    z = MFMA16(a0l, bh0, z); z = MFMA16(a1l, bh1, z);                 \
  }

// ---- attention Z: zp[s][h2][q] = sum over k-segment s of exp|a| (s = 0..3) ----
// v2: two qt tiles per block + async-stage split.
__global__ __launch_bounds__(256) void attn_z_kernel(
    const u16* __restrict__ qhi, const u16* __restrict__ khi,
    float* __restrict__ zp) {
  __shared__ u16 Kh[2][64][72];

  const int bid = blockIdx.x;
  const int c = 7 - (bid >> 8);                 // heavy-first
  const int r = bid & 255;
  const int h2 = r & 31;
  const int qp = (r >> 5) & 1;                  // qt pair index
  const int s = r >> 6;                         // 0..3
  const int qt0 = (qp * 2) * 8 + c;
  const int qt1 = (qp * 2 + 1) * 8 + c;
  const int t = threadIdx.x;
  const int lane = t & 63, wv = t >> 6;
  const int rsel = lane & 15, grp = lane >> 4, ksel = 8 * grp;
  const int qrow0 = qt0 * 64 + wv * 16;
  const int qrow1 = qt1 * 64 + wv * 16;

  const size_t qoff0 = ((size_t)h2 * LQ + qrow0 + rsel) * 64 + ksel;
  const size_t qoff1 = ((size_t)h2 * LQ + qrow1 + rsel) * 64 + ksel;
  bf16x8 a00 = *(const bf16x8*)(qhi + qoff0), a01 = *(const bf16x8*)(qhi + qoff0 + 32);
  bf16x8 a10 = *(const bf16x8*)(qhi + qoff1), a11 = *(const bf16x8*)(qhi + qoff1 + 32);
  const u16* kh = khi + (size_t)h2 * LQ * 64;

  const int srow = t >> 2;
  const int scol = (t & 3) * 16;

  int qm0[4], qm1[4];
  float Z0[4] = {0.f, 0.f, 0.f, 0.f};
  float Z1[4] = {0.f, 0.f, 0.f, 0.f};
#pragma unroll
  for (int j = 0; j < 4; ++j) {
    qm0[j] = (qrow0 + grp * 4 + j) & 511;
    qm1[j] = (qrow1 + grp * 4 + j) & 511;
  }

  const int kbeg = s * 512;
  int buf = 0;

  // prologue: load tile 0
  uint4 r0, r1;
  {
    const size_t kb = (size_t)(kbeg + srow) * 64 + scol;
    r0 = *(const uint4*)(kh + kb);
    r1 = *(const uint4*)(kh + kb + 8);
  }
  for (int jt = 0; jt <= c; ++jt) {             // computed tiles only
    const int kt = kbeg + jt * 64;
    *(uint4*)&Kh[buf][srow][scol] = r0;
    *(uint4*)&Kh[buf][srow][scol + 8] = r1;
    __syncthreads();   // K tile ready (dbuf protects against next-tile WAR)
    if (jt < c) {
      const size_t kb = (size_t)(kt + 64 + srow) * 64 + scol;
      r0 = *(const uint4*)(kh + kb);
      r1 = *(const uint4*)(kh + kb + 8);
    }
#pragma unroll
    for (int fk = 0; fk < 4; ++fk) {
      const int krow = fk * 16 + rsel;
      const int k = kt + krow;
      bf16x8 b0 = *(const bf16x8*)&Kh[buf][krow][ksel];
      bf16x8 b1 = *(const bf16x8*)&Kh[buf][krow][ksel + 32];
      f32x4 z0 = {};
      z0 = MFMA16(a00, b0, z0);
      z0 = MFMA16(a01, b1, z0);
      f32x4 z1 = {};
      z1 = MFMA16(a10, b0, z1);
      z1 = MFMA16(a11, b1, z1);
#pragma unroll
      for (int j = 0; j < 4; ++j) {
        if ((k & 511) <= qm0[j]) Z0[j] += __expf(fabsf(z0[j] * SCALING));
        if ((k & 511) <= qm1[j]) Z1[j] += __expf(fabsf(z1[j] * SCALING));
      }
    }
    buf ^= 1;
  }
#pragma unroll
  for (int j = 0; j < 4; ++j) {
#pragma unroll
    for (int off = 1; off < 16; off <<= 1) {
      Z0[j] += __shfl_xor(Z0[j], off);
      Z1[j] += __shfl_xor(Z1[j], off);
    }
    if (rsel == 0) {
      int q0 = qrow0 + grp * 4 + j;
      int q1 = qrow1 + grp * 4 + j;
      zp[((size_t)(s * 32 + h2) << 11) + q0] = Z0[j];
      zp[((size_t)(s * 32 + h2) << 11) + q1] = Z1[j];
    }
  }
}

// ---- attention PV: 1D grid 2048 heavy-first, one 512-segment per block ----
__global__ __launch_bounds__(256) void attn_pv_kernel(
    const u16* __restrict__ qhi, const u16* __restrict__ qlo,
    const u16* __restrict__ khi, const u16* __restrict__ klo,
    const u16* __restrict__ vt, const float* __restrict__ zp,
    const float* __restrict__ lamp,
    float* __restrict__ O0, float* __restrict__ O123, float* __restrict__ colsum) {
  __shared__ u16 KhA[64][72], KlA[64][72], KhB[64][72], KlB[64][72];
  __shared__ u16 Vs[64][72];
  __shared__ u16 pcLDS[4][16][72];
  __shared__ float csLDS[2][4][64];

  const int bid = blockIdx.x;
  const int c = 7 - (bid >> 8);                 // heavy-first
  const int r = bid & 255;
  const int h = r & 15;
  const int qtIdx = (r >> 4) & 3;
  const int s = r >> 6;                         // 0..3
  const int qt = qtIdx * 8 + c;
  const int qb = qt * 64;
  const int t = threadIdx.x;
  const int lane = t & 63, wv = t >> 6;
  const int rsel = lane & 15, grp = lane >> 4, ksel = 8 * grp;
  const int qrow = qb + wv * 16;
  const float lam = lamp[0];

  const int h2a = 2 * h, h2b = 2 * h + 1;
  const size_t qoffa = ((size_t)h2a * LQ + qrow + rsel) * 64 + ksel;
  const size_t qoffb = ((size_t)h2b * LQ + qrow + rsel) * 64 + ksel;
  bf16x8 aqa0h = *(const bf16x8*)(qhi + qoffa), aqa1h = *(const bf16x8*)(qhi + qoffa + 32);
  bf16x8 aqa0l = *(const bf16x8*)(qlo + qoffa), aqa1l = *(const bf16x8*)(qlo + qoffa + 32);
  bf16x8 aqb0h = *(const bf16x8*)(qhi + qoffb), aqb1h = *(const bf16x8*)(qhi + qoffb + 32);
  bf16x8 aqb0l = *(const bf16x8*)(qlo + qoffb), aqb1l = *(const bf16x8*)(qlo + qoffb + 32);
  const u16* kha = khi + (size_t)h2a * LQ * 64;
  const u16* kla = klo + (size_t)h2a * LQ * 64;
  const u16* khb = khi + (size_t)h2b * LQ * 64;
  const u16* klb = klo + (size_t)h2b * LQ * 64;
  const u16* vb = vt + (size_t)h * 64 * LQ;

  // cooperative staging coords: thread t covers row t>>2, 16 cols at (t&3)*16
  const int srow = t >> 2;
  const int scol = (t & 3) * 16;

  int qm[4];
  float iz1[4], iz2[4];
#pragma unroll
  for (int j = 0; j < 4; ++j) {
    int q = qrow + grp * 4 + j;
    qm[j] = q & 511;
    float z1 = 0.f, z2 = 0.f;
#pragma unroll
    for (int ss = 0; ss < 4; ++ss) {
      z1 += zp[((size_t)(ss * 32 + h2a) << 11) + q];
      z2 += zp[((size_t)(ss * 32 + h2b) << 11) + q];
    }
    iz1[j] = 1.f / z1;
    iz2[j] = 1.f / z2;
  }

  f32x4 accO[4] = {};
  const int kbeg = s * 512;
  int buf = 0;

  // zero colsum for skipped (fully-masked) tiles of this segment
  for (int jt = c + 1; jt < 8; ++jt) {
    if (t < 64) colsum[((size_t)h * 32 + qt) * LQ + kbeg + jt * 64 + t] = 0.f;
  }

  // prologue: load tile 0 into registers
  uint4 rha0, rha1, rla0, rla1, rhb0, rhb1, rlb0, rlb1, rv0, rv1;
  {
    const size_t kb = (size_t)(kbeg + srow) * 64 + scol;
    rha0 = *(const uint4*)(kha + kb);
    rha1 = *(const uint4*)(kha + kb + 8);
    rla0 = *(const uint4*)(kla + kb);
    rla1 = *(const uint4*)(kla + kb + 8);
    rhb0 = *(const uint4*)(khb + kb);
    rhb1 = *(const uint4*)(khb + kb + 8);
    rlb0 = *(const uint4*)(klb + kb);
    rlb1 = *(const uint4*)(klb + kb + 8);
    const u16* vsrc = vb + (size_t)srow * LQ + kbeg + scol;
    rv0 = *(const uint4*)(vsrc);
    rv1 = *(const uint4*)(vsrc + 8);
  }

  for (int jt = 0; jt <= c; ++jt) {
    const int kt = kbeg + jt * 64;

    // write prefetched tile to LDS
    *(uint4*)&KhA[srow][scol] = rha0; *(uint4*)&KhA[srow][scol + 8] = rha1;
    *(uint4*)&KlA[srow][scol] = rla0; *(uint4*)&KlA[srow][scol + 8] = rla1;
    *(uint4*)&KhB[srow][scol] = rhb0; *(uint4*)&KhB[srow][scol + 8] = rhb1;
    *(uint4*)&KlB[srow][scol] = rlb0; *(uint4*)&KlB[srow][scol + 8] = rlb1;
    *(uint4*)&Vs[srow][scol] = rv0;  *(uint4*)&Vs[srow][scol + 8] = rv1;
    __syncthreads();   // K/V tile ready

    // ---- issue NEXT tile's global loads (latency hides under compute) ----
    if (jt < c) {
      const size_t kb = (size_t)(kt + 64 + srow) * 64 + scol;
      rha0 = *(const uint4*)(kha + kb);
      rha1 = *(const uint4*)(kha + kb + 8);
      rla0 = *(const uint4*)(kla + kb);
      rla1 = *(const uint4*)(kla + kb + 8);
      rhb0 = *(const uint4*)(khb + kb);
      rhb1 = *(const uint4*)(khb + kb + 8);
      rlb0 = *(const uint4*)(klb + kb);
      rlb1 = *(const uint4*)(klb + kb + 8);
      const u16* vsrc = vb + (size_t)srow * LQ + kt + 64 + scol;
      rv0 = *(const uint4*)(vsrc);
      rv1 = *(const uint4*)(vsrc + 8);
    }

    __builtin_amdgcn_s_setprio(1);
    float pc[4][4], cs[4];
#pragma unroll
    for (int fk = 0; fk < 4; ++fk) {
      const int krow = fk * 16 + rsel;
      const int k = kt + krow;
      f32x4 z = {};
      SCORE6(z, aqa0h, aqa1h, aqa0l, aqa1l, &KhA[krow][ksel], &KlA[krow][ksel]);
      f32x4 w = {};
      SCORE6(w, aqb0h, aqb1h, aqb0l, aqb1l, &KhB[krow][ksel], &KlB[krow][ksel]);
      float csj = 0.f;
#pragma unroll
      for (int j = 0; j < 4; ++j) {
        bool msk = ((k & 511) > qm[j]);
        float sa = z[j] * SCALING;
        float pa = __builtin_copysignf(__expf(fabsf(sa)) * iz1[j], sa);
        pa = msk ? 0.f : pa;
        csj += pa;
        float sb = w[j] * SCALING;
        float pb = __builtin_copysignf(__expf(fabsf(sb)) * iz2[j], sb);
        pc[fk][j] = pa - (msk ? 0.f : lam * pb);
      }
      cs[fk] = csj;
    }
    // pc relayout through OWN pcLDS slice (intra-wave, lgkmcnt-ordered)
#pragma unroll
    for (int fk = 0; fk < 4; ++fk)
#pragma unroll
      for (int j = 0; j < 4; ++j)
        pcLDS[wv][grp * 4 + j][fk * 16 + rsel] = f2b(pc[fk][j]);
    // PV (intra-wave; V read from LDS)
#pragma unroll
    for (int kc = 0; kc < 2; ++kc) {
      bf16x8 ap = *(const bf16x8*)&pcLDS[wv][rsel][kc * 32 + ksel];
#pragma unroll
      for (int fn = 0; fn < 4; ++fn) {
        bf16x8 bv = *(const bf16x8*)&Vs[fn * 16 + rsel][kc * 32 + ksel];
        accO[fn] = MFMA16(ap, bv, accO[fn]);
      }
    }
    __builtin_amdgcn_s_setprio(0);
    // cross-wave colsum (csLDS dbuf + barrier)
#pragma unroll
    for (int fk = 0; fk < 4; ++fk) {
      float cc = cs[fk];
      cc += __shfl_xor(cc, 16);
      cc += __shfl_xor(cc, 32);
      if (grp == 0) csLDS[buf][wv][fk * 16 + rsel] = cc;
    }
    __syncthreads();
    if (t < 64) {
      float tot = csLDS[buf][0][t] + csLDS[buf][1][t] + csLDS[buf][2][t] + csLDS[buf][3][t];
      colsum[((size_t)h * 32 + qt) * LQ + kt + t] = tot;
    }
    buf ^= 1;
  }
  float* Op = (s == 0) ? O0 : (O123 + (size_t)(s - 1) * 16 * LQ * 64);
#pragma unroll
  for (int fn = 0; fn < 4; ++fn)
#pragma unroll
    for (int j = 0; j < 4; ++j) {
      int q = qrow + grp * 4 + j;
      int d = fn * 16 + rsel;
      Op[((size_t)h * LQ + q) * 64 + d] = accO[fn][j];
    }
}

// g[h][k] = sum_qt colsum[h][qt][k] / 2048
__global__ void g_reduce_kernel(const float* __restrict__ colsum, float* __restrict__ g) {
  int idx = blockIdx.x * 256 + threadIdx.x;
  if (idx >= 16 * LQ) return;
  int h = idx >> 11, k = idx & 2047;
  float s = 0.f;
#pragma unroll
  for (int qt = 0; qt < 32; ++qt) s += colsum[((size_t)h * 32 + qt) * LQ + k];
  g[idx] = s * (1.f / 2048.f);
}

// W[h][r][d] = inclusive prefix over r of Gv[h][r][d], gv fused in
__global__ __launch_bounds__(512) void gv_wscan_kernel(const float* __restrict__ g,
                                                       const u16* __restrict__ vt,
                                                       float* __restrict__ W) {
  __shared__ float s[512];
  int h = blockIdx.x >> 6, d = blockIdx.x & 63;
  int t = threadIdx.x;  // r
  float v = 0.f;
#pragma unroll
  for (int seg = 0; seg < 4; ++seg) {
    int k = seg * 512 + t;
    v += g[h * 2048 + k] * b2f(vt[((size_t)h * 64 + d) * LQ + k]);
  }
  s[t] = v;
  __syncthreads();
  for (int off = 1; off < 512; off <<= 1) {
    float add = (t >= off) ? s[t - off] : 0.f;
    __syncthreads();
    s[t] += add;
    __syncthreads();
  }
  W[((size_t)h * 512 + t) * 64 + d] = s[t];
}

// out_pre = O0 + O1 + O2 + O3 + lam*W[q%512]; head rmsnorm -> bf16 [q][h*64+d]
__global__ __launch_bounds__(256) void combine_norm_kernel(
    const float* __restrict__ O0, const float* __restrict__ O123,
    const float* __restrict__ W, const float* __restrict__ hw,
    const float* __restrict__ lamp, u16* __restrict__ out) {
  const int q = blockIdx.x;
  const int h = blockIdx.y * 4 + (threadIdx.x >> 6);
  const int d = threadIdx.x & 63;
  const float lam = lamp[0];
  const size_t S = (size_t)16 * LQ * 64;
  const size_t idx = ((size_t)h * LQ + q) * 64 + d;
  float v = O0[idx] + O123[idx] + O123[idx + S] + O123[idx + 2 * S] +
            lam * W[((size_t)h * 512 + (q & 511)) * 64 + d];
  float ss = v * v;
#pragma unroll
  for (int off = 1; off < 64; off <<= 1) ss += __shfl_xor(ss, off);
  float sc = 1.f / sqrtf(ss * (1.f / 64.f) + 1e-5f);
  out[(size_t)q * 1024 + h * 64 + d] = f2b(v * sc * hw[d]);
}

// ============================== launch ==============================
extern "C" void kernel_launch(void* const* d_in, const int* in_sizes, int n_in,
                              void* d_out, int out_size, void* d_ws, size_t ws_size,
                              hipStream_t stream) {
  const float* x = (const float*)d_in[0];
  const float* freqs_r = (const float*)d_in[1];
  const float* freqs_i = (const float*)d_in[2];
  // d_in[3] = mask (recomputed analytically)
  const float* kv_down_w = (const float*)d_in[4];
  const float* q_down_w = (const float*)d_in[5];
  const float* kv_up_w = (const float*)d_in[6];
  const float* q_up_w = (const float*)d_in[7];
  const float* kv_norm_w = (const float*)d_in[8];
  const float* q_norm_w = (const float*)d_in[9];
  const float* o_w = (const float*)d_in[10];
  const float* lambda_q1 = (const float*)d_in[11];
  const float* lambda_k1 = (const float*)d_in[12];
  const float* lambda_q2 = (const float*)d_in[13];
  const float* lambda_k2 = (const float*)d_in[14];
  const float* head_norm_w = (const float*)d_in[15];
  const float* norm1_w = (const float*)d_in[16];
  const float* norm2_w = (const float*)d_in[17];
  const float* ff_in_w = (const float*)d_in[18];
  const float* ff_out_w = (const float*)d_in[19];
  float* out = (float*)d_out;
  char* ws = (char*)d_ws;

  // ---- weights region (persistent except down/up: dead after projections) ----
  const size_t WT_KVD_H = 0;                                  // 544x1024 bf16
  const size_t WT_KVD_L = WT_KVD_H + (size_t)544 * 1024 * 2;
  const size_t WT_QD_H  = WT_KVD_L + (size_t)544 * 1024 * 2;  // 512x1024
  const size_t WT_QD_L  = WT_QD_H + (size_t)512 * 1024 * 2;
  const size_t WT_KVU_H = WT_QD_L + (size_t)512 * 1024 * 2;   // 2048x512
  const size_t WT_KVU_L = WT_KVU_H + (size_t)2048 * 512 * 2;
  const size_t WT_QU_H  = WT_KVU_L + (size_t)2048 * 512 * 2;  // 1536x512
  const size_t WT_QU_L  = WT_QU_H + (size_t)1536 * 512 * 2;
  const size_t WT_OW    = WT_QU_L + (size_t)1536 * 512 * 2;   // = 11,714,560
  const size_t WT_FFI   = WT_OW + (size_t)1024 * 1024 * 2;
  const size_t WT_FFO   = WT_FFI + (size_t)8192 * 1024 * 2;
  const size_t A0 = WT_FFO + (size_t)1024 * 4096 * 2;         // = 38,928,384

  // ---- activations (lifetime-aliased) ----
  const size_t H     = A0;                  // h hi/lo bf16 (2x 4,194,304); dead after down-GEMMs
  const size_t CKV   = A0 + 8388608;        // f32 2048x544;  dead after build_kh
  const size_t CKVN  = A0 + 12845056;       // ckvn hi/lo bf16 (2x 2,097,152); dead after kv_up
  const size_t KVB   = A0 + 17039360;       // f32 2048x2048; dead after build_vt
  const size_t CQ    = A0 + 33816576;       // f32 2048x512;  dead after rmsnorm
  const size_t CQN   = A0 + 38010880;       // cqn hi/lo bf16 (2x 2,097,152); dead after q_up
  const size_t QFULL = A0 + 42205184;       // f32 2048x1536; dead after build_qh
  // mid buffers (aliases):
  const size_t QHI = H;                     // bf16 32x2048x64 over dead H
  const size_t KHI = QFULL;                 // bf16 32x2048x64 over dead QFULL[0:8.39M]
  const size_t KLO = A0 + 50593792;         // bf16 32x2048x64 over dead QFULL[8.39M:]+
  const size_t QLO = A0 + 58982400;         // bf16 32x2048x64
  const size_t VT  = CKVN;                  // bf16 16x64x2048 over dead CKVN
  // O partials (4 x 8,388,608 f32):
  const size_t OP0   = 0;                   // over dead down/up weights [0, 8.39M) < WT_OW
  const size_t OP123 = KVB;                 // 3 contiguous partials over dead KVB+CQ+CQN
  const size_t CS  = CKV;                   // f32 16x32x2048 over dead CKV
  const size_t GB  = A0 + 67371008;         // f32 16x2048 (131,072)
  const size_t WB  = A0 + 69599232;         // f32 16x512x64 (2,097,152)
  const size_t LAM = A0 + 71696384;         // scalar
  const size_t ZP  = A0 + 71696640;         // f32 4x32x2048 (1,048,576)
  const size_t WS_END = A0 + 72745216;      // ~111.7 MB (known-safe)
  // late aliases:
  const size_t ATTN  = CKV;                 // bf16 2048x1024 (over consumed CS)
  const size_t X1    = KVB + 8388608;       // f32 2048x1024 (partials consumed by combine)
  const size_t H2N   = H;                   // bf16 2048x1024 over dead QHI
  const size_t FFACT = QFULL;               // bf16 2048x4096 over dead KHI+KLO

  if (ws_size < WS_END) return;

  u16* wt_kvd_h = (u16*)(ws + WT_KVD_H); u16* wt_kvd_l = (u16*)(ws + WT_KVD_L);
  u16* wt_qd_h  = (u16*)(ws + WT_QD_H);  u16* wt_qd_l  = (u16*)(ws + WT_QD_L);
  u16* wt_kvu_h = (u16*)(ws + WT_KVU_H); u16* wt_kvu_l = (u16*)(ws + WT_KVU_L);
  u16* wt_qu_h  = (u16*)(ws + WT_QU_H);  u16* wt_qu_l  = (u16*)(ws + WT_QU_L);
  u16* wt_ow  = (u16*)(ws + WT_OW);
  u16* wt_ffi = (u16*)(ws + WT_FFI);
  u16* wt_ffo = (u16*)(ws + WT_FFO);
  u16* h_hi   = (u16*)(ws + H);
  u16* h_lo   = (u16*)(ws + H + 4194304);
  float* ckv  = (float*)(ws + CKV);
  u16* ckvn_hi = (u16*)(ws + CKVN);
  u16* ckvn_lo = (u16*)(ws + CKVN + 2097152);
  float* kvb  = (float*)(ws + KVB);
  float* cq   = (float*)(ws + CQ);
  u16* cqn_hi = (u16*)(ws + CQN);
  u16* cqn_lo = (u16*)(ws + CQN + 2097152);
  float* qfull = (float*)(ws + QFULL);
  u16* qhib = (u16*)(ws + QHI); u16* qlob = (u16*)(ws + QLO);
  u16* khib = (u16*)(ws + KHI); u16* klob = (u16*)(ws + KLO);
  u16* vtb  = (u16*)(ws + VT);
  float* zpb = (float*)(ws + ZP);
  float* Op0 = (float*)(ws + OP0);
  float* Op123 = (float*)(ws + OP123);
  float* csb = (float*)(ws + CS);
  float* gb  = (float*)(ws + GB);
  float* wbb = (float*)(ws + WB);
  float* lamp = (float*)(ws + LAM);
  u16* attn_n = (u16*)(ws + ATTN);
  float* x1 = (float*)(ws + X1);
  u16* h2n = (u16*)(ws + H2N);
  u16* ffact = (u16*)(ws + FFACT);

  // fused weight prep + rmsnorm(x) (16160 transpose blocks + 2048 rmsnorm rows)
  prep_weights_kernel<<<18208, dim3(32, 8), 0, stream>>>(
      kv_down_w, wt_kvd_h, wt_kvd_l, q_down_w, wt_qd_h, wt_qd_l,
      kv_up_w, wt_kvu_h, wt_kvu_l, q_up_w, wt_qu_h, wt_qu_l,
      o_w, wt_ow, ff_in_w, wt_ffi, ff_out_w, wt_ffo,
      x, norm1_w, h_hi, h_lo);

  // fused down-projection pair (share A = h): kv_down (9x32) + q_down (8x32)
  gemm_split2<<<544, 256, 0, stream>>>(
      h_hi, h_lo, wt_kvd_h, wt_kvd_l, ckv, 544, 9,
      h_hi, h_lo, wt_qd_h, wt_qd_l, cq, 512, 8,
      2048, 1024);
  // fused rmsnorm of ckv (stride 544) + cq (stride 512)
  rmsnorm_split2_kernel<<<4096, 256, 0, stream>>>(ckv, kv_norm_w, ckvn_hi, ckvn_lo, 544,
                                                  cq, q_norm_w, cqn_hi, cqn_lo, 512);
  // fused up-projection pair: kv_up (32x32) + q_up (24x32)
  gemm_split2<<<1792, 256, 0, stream>>>(
      ckvn_hi, ckvn_lo, wt_kvu_h, wt_kvu_l, kvb, 2048, 32,
      cqn_hi, cqn_lo, wt_qu_h, wt_qu_l, qfull, 1536, 24,
      2048, 512);

  // fused mid build (build_qh + build_kh + build_vt + lam -> 1 kernel)
  build_mid_kernel<<<33281, 256, 0, stream>>>(qfull, kvb, ckv, freqs_r, freqs_i,
                                              qhib, qlob, khib, klob, vtb,
                                              lambda_q1, lambda_k1, lambda_q2, lambda_k2,
                                              lamp);

  attn_z_kernel<<<2048, 256, 0, stream>>>(qhib, khib, zpb);
  attn_pv_kernel<<<2048, 256, 0, stream>>>(qhib, qlob, khib, klob, vtb, zpb,
                                           lamp, Op0, Op123, csb);

  g_reduce_kernel<<<128, 256, 0, stream>>>(csb, gb);
  gv_wscan_kernel<<<1024, 512, 0, stream>>>(gb, vtb, wbb);
  combine_norm_kernel<<<dim3(2048, 4), 256, 0, stream>>>(Op0, Op123, wbb, head_norm_w,
                                                         lamp, attn_n);

  // x1 = x + attn_n @ o_w  (residual fused into epilogue)
  gemm_kernel<0, 1><<<dim3(16, 32), 256, 0, stream>>>(attn_n, wt_ow, x, x1, nullptr,
                                                      2048, 1024, 1024);
  rmsnorm_kernel<1><<<2048, 256, 0, stream>>>(x1, norm2_w, h2n, 1024, 1024, FEPS);
  // gated FFN-in: M=128 x N=64 tiles (1024 blocks)
  gemm_m128_gated<<<dim3(64, 16), 256, 0, stream>>>(h2n, wt_ffi, ffact, 2048, 4096, 1024);
  // out = x1 + ffact @ ff_out  (residual fused into epilogue)
  gemm_kernel<0, 1><<<dim3(16, 32), 256, 0, stream>>>(ffact, wt_ffo, x1, out, nullptr,
                                                      2048, 1024, 4096);
}